// Round 1
// baseline (23192.627 us; speedup 1.0000x reference)
//
#include <hip/hip_runtime.h>
#include <cstddef>

#define DD 64
#define HH 128
#define WW 128
#define HWC (HH * WW)            // 16384 = 2^14
#define NN (DD * HWC)            // 1048576

// ---------------------------------------------------------------------------
// init: t = image, out[0..NN) = image, p=q=s=0
// ---------------------------------------------------------------------------
__global__ __launch_bounds__(256) void init_k(const float* __restrict__ img,
                                              float* __restrict__ t,
                                              float* __restrict__ out0,
                                              float* __restrict__ p,
                                              float* __restrict__ q,
                                              float* __restrict__ s) {
    int i = blockIdx.x * 256 + threadIdx.x;
    float v = img[i];
    t[i] = v;
    out0[i] = v;
    p[i] = 0.f;
    q[i] = 0.f;
    s[i] = 0.f;
}

// ---------------------------------------------------------------------------
// colsum: r[hw] = (sino[hw] - sum_d t[d,hw]) / DD
// ---------------------------------------------------------------------------
__global__ __launch_bounds__(256) void colsum_k(const float* __restrict__ t,
                                                const float* __restrict__ sino,
                                                float* __restrict__ r) {
    int hw = blockIdx.x * 256 + threadIdx.x;
    float sum = 0.f;
#pragma unroll 8
    for (int d = 0; d < DD; ++d) sum += t[d * HWC + hw];
    r[hw] = (sino[hw] - sum) * (1.0f / DD);
}

// ---------------------------------------------------------------------------
// zdiff: z = t + r ; dx = fdiff(z, W) ; dy = fdiff(z, H) ; dz = fdiff(z, D)
// (r cancels along depth)
// ---------------------------------------------------------------------------
__global__ __launch_bounds__(256) void zdiff_k(const float* __restrict__ t,
                                               const float* __restrict__ r,
                                               float* __restrict__ z,
                                               float* __restrict__ dx,
                                               float* __restrict__ dy,
                                               float* __restrict__ dz) {
    int i = blockIdx.x * 256 + threadIdx.x;
    int w = i & (WW - 1);
    int h = (i >> 7) & (HH - 1);
    int d = i >> 14;
    int hw = i & (HWC - 1);
    float tv = t[i];
    float rv = r[hw];
    float zv = tv + rv;
    z[i] = zv;
    dx[i] = (w < WW - 1) ? (t[i + 1] + r[hw + 1]) - zv : 0.f;
    dy[i] = (h < HH - 1) ? (t[i + WW] + r[hw + WW]) - zv : 0.f;
    dz[i] = (d < DD - 1) ? (t[i + HWC] - tv) : 0.f;
}

// ---------------------------------------------------------------------------
// conv1: 1 -> 16 channels, 3x3x3 SAME, relu.  wgt layout [co][kd][kh][kw]
// ---------------------------------------------------------------------------
__global__ __launch_bounds__(256) void conv1_k(const float* __restrict__ x,
                                               const float* __restrict__ wgt,
                                               const float* __restrict__ bias,
                                               float* __restrict__ out) {
    int i = blockIdx.x * 256 + threadIdx.x;
    int w = i & (WW - 1);
    int h = (i >> 7) & (HH - 1);
    int d = i >> 14;
    float acc[16];
#pragma unroll
    for (int co = 0; co < 16; ++co) acc[co] = bias[co];

    for (int kd = 0; kd < 3; ++kd) {
        int zi = d + kd - 1;
        bool okz = (unsigned)zi < (unsigned)DD;
        for (int kh = 0; kh < 3; ++kh) {
            int yi = h + kh - 1;
            bool oky = okz && ((unsigned)yi < (unsigned)HH);
            int kbase = (kd * 3 + kh) * 3;
            int pbase = (zi << 14) + (yi << 7) + w;
#pragma unroll
            for (int kw = 0; kw < 3; ++kw) {
                int xi = w + kw - 1;
                bool ok = oky && ((unsigned)xi < (unsigned)WW);
                float v = ok ? x[pbase + kw - 1] : 0.f;
                int kk = kbase + kw;
#pragma unroll
                for (int co = 0; co < 16; ++co)
                    acc[co] = fmaf(v, wgt[co * 27 + kk], acc[co]);
            }
        }
    }
#pragma unroll
    for (int co = 0; co < 16; ++co) out[co * NN + i] = fmaxf(acc[co], 0.f);
}

// ---------------------------------------------------------------------------
// conv2: 16 -> 16 channels, 3x3x3 SAME, relu.  wgt layout [co][ci][kd][kh][kw]
// ---------------------------------------------------------------------------
__global__ __launch_bounds__(256) void conv2_k(const float* __restrict__ x,
                                               const float* __restrict__ wgt,
                                               const float* __restrict__ bias,
                                               float* __restrict__ out) {
    int i = blockIdx.x * 256 + threadIdx.x;
    int w = i & (WW - 1);
    int h = (i >> 7) & (HH - 1);
    int d = i >> 14;
    float acc[16];
#pragma unroll
    for (int co = 0; co < 16; ++co) acc[co] = bias[co];

    for (int kd = 0; kd < 3; ++kd) {
        int zi = d + kd - 1;
        bool okz = (unsigned)zi < (unsigned)DD;
        for (int kh = 0; kh < 3; ++kh) {
            int yi = h + kh - 1;
            bool oky = okz && ((unsigned)yi < (unsigned)HH);
            int kbase = (kd * 3 + kh) * 3;
            int pbase = (zi << 14) + (yi << 7) + w;
#pragma unroll
            for (int kw = 0; kw < 3; ++kw) {
                int xi = w + kw - 1;
                bool ok = oky && ((unsigned)xi < (unsigned)WW);
                int addr = pbase + kw - 1;
                int kk = kbase + kw;
#pragma unroll
                for (int ci = 0; ci < 16; ++ci) {
                    float v = ok ? x[ci * NN + addr] : 0.f;
#pragma unroll
                    for (int co = 0; co < 16; ++co)
                        acc[co] = fmaf(v, wgt[(co * 16 + ci) * 27 + kk], acc[co]);
                }
            }
        }
    }
#pragma unroll
    for (int co = 0; co < 16; ++co) out[co * NN + i] = fmaxf(acc[co], 0.f);
}

// ---------------------------------------------------------------------------
// conv3: 16 -> 1 channel, 3x3x3 SAME, + residual.  wgt layout [ci][kd][kh][kw]
// ---------------------------------------------------------------------------
__global__ __launch_bounds__(256) void conv3_k(const float* __restrict__ x,
                                               const float* __restrict__ wgt,
                                               const float* __restrict__ bias,
                                               const float* __restrict__ resid,
                                               float* __restrict__ out) {
    int i = blockIdx.x * 256 + threadIdx.x;
    int w = i & (WW - 1);
    int h = (i >> 7) & (HH - 1);
    int d = i >> 14;
    float a[4] = {0.f, 0.f, 0.f, 0.f};

    for (int kd = 0; kd < 3; ++kd) {
        int zi = d + kd - 1;
        bool okz = (unsigned)zi < (unsigned)DD;
        for (int kh = 0; kh < 3; ++kh) {
            int yi = h + kh - 1;
            bool oky = okz && ((unsigned)yi < (unsigned)HH);
            int kbase = (kd * 3 + kh) * 3;
            int pbase = (zi << 14) + (yi << 7) + w;
#pragma unroll
            for (int kw = 0; kw < 3; ++kw) {
                int xi = w + kw - 1;
                bool ok = oky && ((unsigned)xi < (unsigned)WW);
                int addr = pbase + kw - 1;
                int kk = kbase + kw;
#pragma unroll
                for (int ci = 0; ci < 16; ++ci) {
                    float v = ok ? x[ci * NN + addr] : 0.f;
                    a[ci & 3] = fmaf(v, wgt[ci * 27 + kk], a[ci & 3]);
                }
            }
        }
    }
    out[i] = resid[i] + bias[0] + ((a[0] + a[1]) + (a[2] + a[3]));
}

// ---------------------------------------------------------------------------
// update: p' = p + cx*(p-pnew) (same q,s); z_ = t + ct*(t-znew);
// t_new = fdiffT(p',W) + fdiffT(q',H) + fdiffT(s',D) + z_
// fdiffT(u)[i] = (i>0 ? u[i-1] : 0) - (i<n-1 ? u[i] : 0)
// Neighbors of the *updated* p are recomputed from p0/pnew (no race).
// ---------------------------------------------------------------------------
__global__ __launch_bounds__(256) void update_k(const float* __restrict__ p0,
                                                const float* __restrict__ q0,
                                                const float* __restrict__ s0,
                                                const float* __restrict__ pn,
                                                const float* __restrict__ qn,
                                                const float* __restrict__ sn,
                                                const float* __restrict__ zn,
                                                float* __restrict__ t,
                                                float* __restrict__ p1,
                                                float* __restrict__ q1,
                                                float* __restrict__ s1,
                                                float* __restrict__ out,
                                                const float* __restrict__ ntx,
                                                const float* __restrict__ nty,
                                                const float* __restrict__ ntz,
                                                const float* __restrict__ nt,
                                                int c) {
    int i = blockIdx.x * 256 + threadIdx.x;
    int w = i & (WW - 1);
    int h = (i >> 7) & (HH - 1);
    int d = i >> 14;
    float cx = ntx[c], cy = nty[c], cz = ntz[c], ct = nt[c];

    float pu = p0[i] + cx * (p0[i] - pn[i]);
    float qu = q0[i] + cy * (q0[i] - qn[i]);
    float su = s0[i] + cz * (s0[i] - sn[i]);
    p1[i] = pu;
    q1[i] = qu;
    s1[i] = su;

    float tv = t[i];
    float zl = tv + ct * (tv - zn[i]);

    float acc = zl;
    if (w > 0) {
        float a = p0[i - 1];
        acc += a + cx * (a - pn[i - 1]);
    }
    if (w < WW - 1) acc -= pu;
    if (h > 0) {
        float a = q0[i - WW];
        acc += a + cy * (a - qn[i - WW]);
    }
    if (h < HH - 1) acc -= qu;
    if (d > 0) {
        float a = s0[i - HWC];
        acc += a + cz * (a - sn[i - HWC]);
    }
    if (d < DD - 1) acc -= su;

    t[i] = acc;
    out[i] = acc;
}

// ---------------------------------------------------------------------------
extern "C" void kernel_launch(void* const* d_in, const int* in_sizes, int n_in,
                              void* d_out, int out_size, void* d_ws, size_t ws_size,
                              hipStream_t stream) {
    const float* image = (const float*)d_in[0];
    const float* sino  = (const float*)d_in[1];
    const float* w1    = (const float*)d_in[2];
    const float* b1    = (const float*)d_in[3];
    const float* w2    = (const float*)d_in[4];
    const float* b2    = (const float*)d_in[5];
    const float* w3    = (const float*)d_in[6];
    const float* b3    = (const float*)d_in[7];
    const float* ntx   = (const float*)d_in[8];
    const float* nty   = (const float*)d_in[9];
    const float* ntz   = (const float*)d_in[10];
    const float* nt    = (const float*)d_in[11];

    float* out = (float*)d_out;
    float* ws  = (float*)d_ws;

    float* t      = ws;
    float* pbuf[2] = {ws + (size_t)1 * NN, ws + (size_t)4 * NN};
    float* qbuf[2] = {ws + (size_t)2 * NN, ws + (size_t)5 * NN};
    float* sbuf[2] = {ws + (size_t)3 * NN, ws + (size_t)6 * NN};
    float* z   = ws + (size_t)7 * NN;
    float* dx  = ws + (size_t)8 * NN;
    float* dy  = ws + (size_t)9 * NN;
    float* dzb = ws + (size_t)10 * NN;
    float* pn  = ws + (size_t)11 * NN;
    float* qn  = ws + (size_t)12 * NN;
    float* sn  = ws + (size_t)13 * NN;
    float* zn  = ws + (size_t)14 * NN;
    float* r   = ws + (size_t)15 * NN;                 // HWC floats
    float* h1  = ws + (size_t)15 * NN + HWC;           // 16*NN floats
    float* h2  = ws + (size_t)31 * NN + HWC;           // 16*NN floats

    const int NB = NN / 256;   // 4096 blocks
    const int HB = HWC / 256;  // 64 blocks

    init_k<<<NB, 256, 0, stream>>>(image, t, out, pbuf[0], qbuf[0], sbuf[0]);

    int cur = 0;
    for (int c = 0; c < 3; ++c) {
        colsum_k<<<HB, 256, 0, stream>>>(t, sino, r);
        zdiff_k<<<NB, 256, 0, stream>>>(t, r, z, dx, dy, dzb);

        const float* xin[4] = {dx, dy, dzb, z};
        float*       oae[4] = {pn, qn, sn, zn};
        for (int bi = 0; bi < 4; ++bi) {
            conv1_k<<<NB, 256, 0, stream>>>(xin[bi], w1 + (size_t)bi * 432,
                                            b1 + (size_t)bi * 16, h1);
            conv2_k<<<NB, 256, 0, stream>>>(h1, w2 + (size_t)bi * 6912,
                                            b2 + (size_t)bi * 16, h2);
            conv3_k<<<NB, 256, 0, stream>>>(h2, w3 + (size_t)bi * 432,
                                            b3 + (size_t)bi, xin[bi], oae[bi]);
        }

        update_k<<<NB, 256, 0, stream>>>(pbuf[cur], qbuf[cur], sbuf[cur],
                                         pn, qn, sn, zn, t,
                                         pbuf[1 - cur], qbuf[1 - cur], sbuf[1 - cur],
                                         out + (size_t)(c + 1) * NN,
                                         ntx, nty, ntz, nt, c);
        cur ^= 1;
    }
}

// Round 2
// 1984.800 us; speedup vs baseline: 11.6851x; 11.6851x over previous
//
#include <hip/hip_runtime.h>
#include <cstddef>

#define DD 64
#define HH 128
#define WW 128
#define HWC (HH * WW)            // 16384
#define NN (DD * HWC)            // 1048576

// padded spatial dims (+1 halo each side)
#define PD 66
#define PH 130
#define PW 130
#define PHW (PH * PW)            // 16900
#define PN (PD * PHW)            // 1115400

typedef __attribute__((ext_vector_type(8))) _Float16 half8;
typedef __attribute__((ext_vector_type(4))) float f32x4;

__device__ __forceinline__ int pcidx(int d, int h, int w) {
    return (d + 1) * PHW + (h + 1) * PW + (w + 1);
}

// ---------------------------------------------------------------------------
// init: t = image, out[0..NN) = image, p=q=s=0
// ---------------------------------------------------------------------------
__global__ __launch_bounds__(256) void init_k(const float* __restrict__ img,
                                              float* __restrict__ t,
                                              float* __restrict__ out0,
                                              float* __restrict__ p,
                                              float* __restrict__ q,
                                              float* __restrict__ s) {
    int i = blockIdx.x * 256 + threadIdx.x;
    float v = img[i];
    t[i] = v;
    out0[i] = v;
    p[i] = 0.f;
    q[i] = 0.f;
    s[i] = 0.f;
}

// ---------------------------------------------------------------------------
// colsum: r[hw] = (sino[hw] - sum_d t[d,hw]) / DD
// ---------------------------------------------------------------------------
__global__ __launch_bounds__(256) void colsum_k(const float* __restrict__ t,
                                                const float* __restrict__ sino,
                                                float* __restrict__ r) {
    int hw = blockIdx.x * 256 + threadIdx.x;
    float sum = 0.f;
#pragma unroll 8
    for (int d = 0; d < DD; ++d) sum += t[d * HWC + hw];
    r[hw] = (sino[hw] - sum) * (1.0f / DD);
}

// ---------------------------------------------------------------------------
// zdiff: writes PADDED z, dx, dy, dz (fp32). Pads are pre-zeroed.
// ---------------------------------------------------------------------------
__global__ __launch_bounds__(256) void zdiff_k(const float* __restrict__ t,
                                               const float* __restrict__ r,
                                               float* __restrict__ zP,
                                               float* __restrict__ dxP,
                                               float* __restrict__ dyP,
                                               float* __restrict__ dzP) {
    int i = blockIdx.x * 256 + threadIdx.x;
    int w = i & (WW - 1);
    int h = (i >> 7) & (HH - 1);
    int d = i >> 14;
    int hw = i & (HWC - 1);
    int pc = pcidx(d, h, w);
    float tv = t[i];
    float rv = r[hw];
    float zv = tv + rv;
    zP[pc] = zv;
    dxP[pc] = (w < WW - 1) ? (t[i + 1] + r[hw + 1]) - zv : 0.f;
    dyP[pc] = (h < HH - 1) ? (t[i + WW] + r[hw + WW]) - zv : 0.f;
    dzP[pc] = (d < DD - 1) ? (t[i + HWC] - tv) : 0.f;
}

// ---------------------------------------------------------------------------
// prep_w2: repack conv2 weights [bi][co][ci][27] fp32 ->
//          fp16 frag layout [(bi*56 + kc)*16 + co][8], k = tap*16+ci, kc=k>>3
//          tap 27 (K padding) = 0
// ---------------------------------------------------------------------------
__global__ __launch_bounds__(256) void prep_w2(const float* __restrict__ w2,
                                               _Float16* __restrict__ wB) {
    int idx = blockIdx.x * 256 + threadIdx.x;   // 4*56*16 = 3584
    if (idx >= 3584) return;
    int bi = idx / 896;
    int rem = idx - bi * 896;
    int kc = rem >> 4;
    int co = rem & 15;
    int tap = kc >> 1;
    int ci0 = (kc & 1) * 8;
    half8 v;
#pragma unroll
    for (int j = 0; j < 8; ++j) {
        float f = (tap < 27) ? w2[bi * 6912 + (co * 16 + ci0 + j) * 27 + tap] : 0.f;
        v[j] = (_Float16)f;
    }
    *(half8*)(wB + (size_t)idx * 8) = v;
}

// ---------------------------------------------------------------------------
// conv1: 1 -> 16 ch, padded fp32 in, padded interleaved fp16 out (relu)
// ---------------------------------------------------------------------------
__global__ __launch_bounds__(256) void conv1_k(const float* __restrict__ x,
                                               const float* __restrict__ wgt,
                                               const float* __restrict__ bias,
                                               _Float16* __restrict__ out) {
    int i = blockIdx.x * 256 + threadIdx.x;
    int w = i & (WW - 1);
    int h = (i >> 7) & (HH - 1);
    int d = i >> 14;
    int pc = pcidx(d, h, w);
    float acc[16];
#pragma unroll
    for (int co = 0; co < 16; ++co) acc[co] = bias[co];

#pragma unroll
    for (int kd = 0; kd < 3; ++kd)
#pragma unroll
        for (int kh = 0; kh < 3; ++kh)
#pragma unroll
            for (int kw = 0; kw < 3; ++kw) {
                const int off = (kd - 1) * PHW + (kh - 1) * PW + (kw - 1);
                const int tap = (kd * 3 + kh) * 3 + kw;
                float v = x[pc + off];
#pragma unroll
                for (int co = 0; co < 16; ++co)
                    acc[co] = fmaf(v, wgt[co * 27 + tap], acc[co]);
            }
    half8 lo, hi;
#pragma unroll
    for (int co = 0; co < 8; ++co) {
        lo[co] = (_Float16)fmaxf(acc[co], 0.f);
        hi[co] = (_Float16)fmaxf(acc[co + 8], 0.f);
    }
    *(half8*)(out + (size_t)pc * 16) = lo;
    *(half8*)(out + (size_t)pc * 16 + 8) = hi;
}

// ---------------------------------------------------------------------------
// conv2: 16 -> 16 ch via MFMA implicit GEMM.
// x: padded interleaved fp16 [PN][16].  wB: frag-packed weights (7168 halves).
// out: padded interleaved fp16 [PN][16], relu(acc + bias).
// Per wave: M=64 spatial (one W-run), N=16 co, K=448 (14 MFMAs of K=32).
// ---------------------------------------------------------------------------
__global__ __launch_bounds__(256) void conv2_mfma(const _Float16* __restrict__ x,
                                                  const _Float16* __restrict__ wB,
                                                  const float* __restrict__ bias,
                                                  _Float16* __restrict__ out) {
    const int tid = threadIdx.x;
    const int lane = tid & 63;
    const int wid = tid >> 6;
    const int m64 = blockIdx.x * 256 + wid * 64;   // 64 consecutive w in one row
    const int w0 = m64 & (WW - 1);
    const int h0 = (m64 >> 7) & (HH - 1);
    const int d0 = m64 >> 14;
    const int pc64 = pcidx(d0, h0, w0);
    const int l15 = lane & 15;
    const int lg = lane >> 4;          // k-group 0..3
    const int tapSel = lg >> 1;        // tap parity within MFMA
    const int ci0 = (lg & 1) * 8;

    // per-lane padded-offset table for t = 0..13 (tap = 2t + tapSel, clamp 26)
    int offl[14];
#pragma unroll
    for (int t = 0; t < 14; ++t) {
        int tap = 2 * t + tapSel;
        if (tap > 26) tap = 26;        // K-pad: weights are 0 there
        int kd = tap / 9;
        int kh = (tap / 3) % 3;
        int kw = tap % 3;
        offl[t] = (kd - 1) * PHW + (kh - 1) * PW + (kw - 1);
    }

    f32x4 acc0 = {0.f, 0.f, 0.f, 0.f};
    f32x4 acc1 = acc0, acc2 = acc0, acc3 = acc0;
    const int arow = pc64 + l15;

#pragma unroll
    for (int t = 0; t < 14; ++t) {
        half8 b = *(const half8*)(wB + (size_t)((t * 4 + lg) * 16 + l15) * 8);
        int ab = (arow + offl[t]) * 16 + ci0;
        half8 a0 = *(const half8*)(x + ab);
        half8 a1 = *(const half8*)(x + ab + 16 * 16);
        half8 a2 = *(const half8*)(x + ab + 32 * 16);
        half8 a3 = *(const half8*)(x + ab + 48 * 16);
        acc0 = __builtin_amdgcn_mfma_f32_16x16x32_f16(a0, b, acc0, 0, 0, 0);
        acc1 = __builtin_amdgcn_mfma_f32_16x16x32_f16(a1, b, acc1, 0, 0, 0);
        acc2 = __builtin_amdgcn_mfma_f32_16x16x32_f16(a2, b, acc2, 0, 0, 0);
        acc3 = __builtin_amdgcn_mfma_f32_16x16x32_f16(a3, b, acc3, 0, 0, 0);
    }

    float bc = bias[l15];
    // C/D layout: col = lane&15 (co), row = (lane>>4)*4 + reg (spatial)
#pragma unroll
    for (int r = 0; r < 4; ++r) {
        f32x4 a = (r == 0) ? acc0 : (r == 1) ? acc1 : (r == 2) ? acc2 : acc3;
#pragma unroll
        for (int reg = 0; reg < 4; ++reg) {
            int prow = pc64 + r * 16 + lg * 4 + reg;
            float v = fmaxf(a[reg] + bc, 0.f);
            out[(size_t)prow * 16 + l15] = (_Float16)v;
        }
    }
}

// ---------------------------------------------------------------------------
// conv3: 16 -> 1 ch, padded interleaved fp16 in, + residual (padded fp32),
// unpadded fp32 out.
// ---------------------------------------------------------------------------
__global__ __launch_bounds__(256) void conv3_k(const _Float16* __restrict__ x,
                                               const float* __restrict__ wgt,
                                               const float* __restrict__ bias,
                                               const float* __restrict__ residP,
                                               float* __restrict__ out) {
    int i = blockIdx.x * 256 + threadIdx.x;
    int w = i & (WW - 1);
    int h = (i >> 7) & (HH - 1);
    int d = i >> 14;
    int pc = pcidx(d, h, w);
    float a0 = 0.f, a1 = 0.f, a2 = 0.f, a3 = 0.f;

#pragma unroll
    for (int kd = 0; kd < 3; ++kd)
#pragma unroll
        for (int kh = 0; kh < 3; ++kh)
#pragma unroll
            for (int kw = 0; kw < 3; ++kw) {
                const int off = (kd - 1) * PHW + (kh - 1) * PW + (kw - 1);
                const int tap = (kd * 3 + kh) * 3 + kw;
                const _Float16* px = x + (size_t)(pc + off) * 16;
                half8 v0 = *(const half8*)(px);
                half8 v1 = *(const half8*)(px + 8);
#pragma unroll
                for (int ci = 0; ci < 8; ++ci) {
                    a0 = fmaf((float)v0[ci], wgt[ci * 27 + tap], a0);
                    a1 = fmaf((float)v1[ci], wgt[(ci + 8) * 27 + tap], a1);
                }
            }
    (void)a2; (void)a3;
    out[i] = residP[pc] + bias[0] + (a0 + a1);
}

// ---------------------------------------------------------------------------
// update (unchanged from round 1, verified)
// ---------------------------------------------------------------------------
__global__ __launch_bounds__(256) void update_k(const float* __restrict__ p0,
                                                const float* __restrict__ q0,
                                                const float* __restrict__ s0,
                                                const float* __restrict__ pn,
                                                const float* __restrict__ qn,
                                                const float* __restrict__ sn,
                                                const float* __restrict__ zn,
                                                float* __restrict__ t,
                                                float* __restrict__ p1,
                                                float* __restrict__ q1,
                                                float* __restrict__ s1,
                                                float* __restrict__ out,
                                                const float* __restrict__ ntx,
                                                const float* __restrict__ nty,
                                                const float* __restrict__ ntz,
                                                const float* __restrict__ nt,
                                                int c) {
    int i = blockIdx.x * 256 + threadIdx.x;
    int w = i & (WW - 1);
    int h = (i >> 7) & (HH - 1);
    int d = i >> 14;
    float cx = ntx[c], cy = nty[c], cz = ntz[c], ct = nt[c];

    float pu = p0[i] + cx * (p0[i] - pn[i]);
    float qu = q0[i] + cy * (q0[i] - qn[i]);
    float su = s0[i] + cz * (s0[i] - sn[i]);
    p1[i] = pu;
    q1[i] = qu;
    s1[i] = su;

    float tv = t[i];
    float zl = tv + ct * (tv - zn[i]);

    float acc = zl;
    if (w > 0) {
        float a = p0[i - 1];
        acc += a + cx * (a - pn[i - 1]);
    }
    if (w < WW - 1) acc -= pu;
    if (h > 0) {
        float a = q0[i - WW];
        acc += a + cy * (a - qn[i - WW]);
    }
    if (h < HH - 1) acc -= qu;
    if (d > 0) {
        float a = s0[i - HWC];
        acc += a + cz * (a - sn[i - HWC]);
    }
    if (d < DD - 1) acc -= su;

    t[i] = acc;
    out[i] = acc;
}

// ---------------------------------------------------------------------------
extern "C" void kernel_launch(void* const* d_in, const int* in_sizes, int n_in,
                              void* d_out, int out_size, void* d_ws, size_t ws_size,
                              hipStream_t stream) {
    const float* image = (const float*)d_in[0];
    const float* sino  = (const float*)d_in[1];
    const float* w1    = (const float*)d_in[2];
    const float* b1    = (const float*)d_in[3];
    const float* w2    = (const float*)d_in[4];
    const float* b2    = (const float*)d_in[5];
    const float* w3    = (const float*)d_in[6];
    const float* b3    = (const float*)d_in[7];
    const float* ntx   = (const float*)d_in[8];
    const float* nty   = (const float*)d_in[9];
    const float* ntz   = (const float*)d_in[10];
    const float* nt    = (const float*)d_in[11];

    float* out = (float*)d_out;
    float* ws  = (float*)d_ws;

    // unpadded fp32 state
    float* t     = ws;
    float* pbuf[2] = {ws + (size_t)1 * NN, ws + (size_t)4 * NN};
    float* qbuf[2] = {ws + (size_t)2 * NN, ws + (size_t)5 * NN};
    float* sbuf[2] = {ws + (size_t)3 * NN, ws + (size_t)6 * NN};
    float* pn = ws + (size_t)7 * NN;
    float* qn = ws + (size_t)8 * NN;
    float* sn = ws + (size_t)9 * NN;
    float* zn = ws + (size_t)10 * NN;
    float* r  = ws + (size_t)11 * NN;            // HWC floats

    // padded region (zeroed each launch): 4*PN fp32 + 2*(PN*16) fp16
    float* padbase = ws + (size_t)12 * NN;
    float* zP  = padbase;
    float* dxP = padbase + (size_t)1 * PN;
    float* dyP = padbase + (size_t)2 * PN;
    float* dzP = padbase + (size_t)3 * PN;
    _Float16* h1 = (_Float16*)(padbase + (size_t)4 * PN);    // PN*16 halves
    _Float16* h2 = (_Float16*)(padbase + (size_t)12 * PN);   // PN*16 halves
    _Float16* wBp = (_Float16*)(padbase + (size_t)20 * PN);  // 4*7168 halves

    const int NB = NN / 256;   // 4096
    const int HB = HWC / 256;  // 64

    // zero pads (ws is re-poisoned to 0xAA before every call)
    hipMemsetAsync(padbase, 0, (size_t)20 * PN * sizeof(float), stream);
    prep_w2<<<14, 256, 0, stream>>>(w2, wBp);
    init_k<<<NB, 256, 0, stream>>>(image, t, out, pbuf[0], qbuf[0], sbuf[0]);

    int cur = 0;
    for (int c = 0; c < 3; ++c) {
        colsum_k<<<HB, 256, 0, stream>>>(t, sino, r);
        zdiff_k<<<NB, 256, 0, stream>>>(t, r, zP, dxP, dyP, dzP);

        const float* xinP[4] = {dxP, dyP, dzP, zP};
        float*       oae[4]  = {pn, qn, sn, zn};
        for (int bi = 0; bi < 4; ++bi) {
            conv1_k<<<NB, 256, 0, stream>>>(xinP[bi], w1 + (size_t)bi * 432,
                                            b1 + (size_t)bi * 16, h1);
            conv2_mfma<<<NB, 256, 0, stream>>>(h1, wBp + (size_t)bi * 7168,
                                               b2 + (size_t)bi * 16, h2);
            conv3_k<<<NB, 256, 0, stream>>>(h2, w3 + (size_t)bi * 432,
                                            b3 + (size_t)bi, xinP[bi], oae[bi]);
        }

        update_k<<<NB, 256, 0, stream>>>(pbuf[cur], qbuf[cur], sbuf[cur],
                                         pn, qn, sn, zn, t,
                                         pbuf[1 - cur], qbuf[1 - cur], sbuf[1 - cur],
                                         out + (size_t)(c + 1) * NN,
                                         ntx, nty, ntz, nt, c);
        cur ^= 1;
    }
}

// Round 3
// 1560.181 us; speedup vs baseline: 14.8653x; 1.2722x over previous
//
#include <hip/hip_runtime.h>
#include <cstddef>

#define DD 64
#define HH 128
#define WW 128
#define HWC (HH * WW)            // 16384
#define NN (DD * HWC)            // 1048576

// padded spatial dims (+1 halo each side)
#define PD 66
#define PH 130
#define PW 130
#define PHW (PH * PW)            // 16900
#define PN (PD * PHW)            // 1115400

typedef __attribute__((ext_vector_type(8))) _Float16 half8;
typedef __attribute__((ext_vector_type(2))) _Float16 h2;
typedef __attribute__((ext_vector_type(4))) float f32x4;

__device__ __forceinline__ int pcidx(int d, int h, int w) {
    return (d + 1) * PHW + (h + 1) * PW + (w + 1);
}

__device__ __forceinline__ float fdot2f(h2 a, h2 b, float c) {
#if __has_builtin(__builtin_amdgcn_fdot2)
    return __builtin_amdgcn_fdot2(a, b, c, false);
#else
    return fmaf((float)a[0], (float)b[0], fmaf((float)a[1], (float)b[1], c));
#endif
}

// ---------------------------------------------------------------------------
// init: t = image, out[0..NN) = image, p=q=s=0
// ---------------------------------------------------------------------------
__global__ __launch_bounds__(256) void init_k(const float* __restrict__ img,
                                              float* __restrict__ t,
                                              float* __restrict__ out0,
                                              float* __restrict__ p,
                                              float* __restrict__ q,
                                              float* __restrict__ s) {
    int i = blockIdx.x * 256 + threadIdx.x;
    float v = img[i];
    t[i] = v;
    out0[i] = v;
    p[i] = 0.f;
    q[i] = 0.f;
    s[i] = 0.f;
}

// ---------------------------------------------------------------------------
// colsum: r[hw] = (sino[hw] - sum_d t[d,hw]) / DD
// ---------------------------------------------------------------------------
__global__ __launch_bounds__(256) void colsum_k(const float* __restrict__ t,
                                                const float* __restrict__ sino,
                                                float* __restrict__ r) {
    int hw = blockIdx.x * 256 + threadIdx.x;
    float sum = 0.f;
#pragma unroll 8
    for (int d = 0; d < DD; ++d) sum += t[d * HWC + hw];
    r[hw] = (sino[hw] - sum) * (1.0f / DD);
}

// ---------------------------------------------------------------------------
// zdiff: writes PADDED z, dx, dy, dz (fp32). Pads are pre-zeroed.
// ---------------------------------------------------------------------------
__global__ __launch_bounds__(256) void zdiff_k(const float* __restrict__ t,
                                               const float* __restrict__ r,
                                               float* __restrict__ zP,
                                               float* __restrict__ dxP,
                                               float* __restrict__ dyP,
                                               float* __restrict__ dzP) {
    int i = blockIdx.x * 256 + threadIdx.x;
    int w = i & (WW - 1);
    int h = (i >> 7) & (HH - 1);
    int d = i >> 14;
    int hw = i & (HWC - 1);
    int pc = pcidx(d, h, w);
    float tv = t[i];
    float rv = r[hw];
    float zv = tv + rv;
    zP[pc] = zv;
    dxP[pc] = (w < WW - 1) ? (t[i + 1] + r[hw + 1]) - zv : 0.f;
    dyP[pc] = (h < HH - 1) ? (t[i + WW] + r[hw + WW]) - zv : 0.f;
    dzP[pc] = (d < DD - 1) ? (t[i + HWC] - tv) : 0.f;
}

// ---------------------------------------------------------------------------
// prep_w2: repack conv2 weights [bi][co][ci][27] fp32 ->
//          fp16 frag layout [(bi*56 + kc)*16 + co][8], k = tap*16+ci
// ---------------------------------------------------------------------------
__global__ __launch_bounds__(256) void prep_w2(const float* __restrict__ w2,
                                               _Float16* __restrict__ wB) {
    int idx = blockIdx.x * 256 + threadIdx.x;   // 4*56*16 = 3584
    if (idx >= 3584) return;
    int bi = idx / 896;
    int rem = idx - bi * 896;
    int kc = rem >> 4;
    int co = rem & 15;
    int tap = kc >> 1;
    int ci0 = (kc & 1) * 8;
    half8 v;
#pragma unroll
    for (int j = 0; j < 8; ++j) {
        float f = (tap < 27) ? w2[bi * 6912 + (co * 16 + ci0 + j) * 27 + tap] : 0.f;
        v[j] = (_Float16)f;
    }
    *(half8*)(wB + (size_t)idx * 8) = v;
}

// ---------------------------------------------------------------------------
// prep_w3: pack conv3 weights [bi][ci][27] fp32 -> half2 pairs
//          wC[bi][tap][j] = (w3[2j][tap], w3[2j+1][tap]),  j = 0..7
// ---------------------------------------------------------------------------
__global__ __launch_bounds__(256) void prep_w3(const float* __restrict__ w3,
                                               h2* __restrict__ wC) {
    int idx = blockIdx.x * 256 + threadIdx.x;   // 4*27*8 = 864
    if (idx >= 864) return;
    int bi = idx / 216;
    int rem = idx - bi * 216;
    int tap = rem >> 3;
    int j = rem & 7;
    h2 v;
    v[0] = (_Float16)w3[bi * 432 + (2 * j) * 27 + tap];
    v[1] = (_Float16)w3[bi * 432 + (2 * j + 1) * 27 + tap];
    wC[idx] = v;
}

// ---------------------------------------------------------------------------
// conv1: 1 -> 16 ch, padded fp32 in, padded interleaved fp16 out (relu)
// ---------------------------------------------------------------------------
__global__ __launch_bounds__(256) void conv1_k(const float* __restrict__ x,
                                               const float* __restrict__ wgt,
                                               const float* __restrict__ bias,
                                               _Float16* __restrict__ out) {
    int i = blockIdx.x * 256 + threadIdx.x;
    int w = i & (WW - 1);
    int h = (i >> 7) & (HH - 1);
    int d = i >> 14;
    int pc = pcidx(d, h, w);
    float acc[16];
#pragma unroll
    for (int co = 0; co < 16; ++co) acc[co] = bias[co];

#pragma unroll
    for (int kd = 0; kd < 3; ++kd)
#pragma unroll
        for (int kh = 0; kh < 3; ++kh)
#pragma unroll
            for (int kw = 0; kw < 3; ++kw) {
                const int off = (kd - 1) * PHW + (kh - 1) * PW + (kw - 1);
                const int tap = (kd * 3 + kh) * 3 + kw;
                float v = x[pc + off];
#pragma unroll
                for (int co = 0; co < 16; ++co)
                    acc[co] = fmaf(v, wgt[co * 27 + tap], acc[co]);
            }
    half8 lo, hi;
#pragma unroll
    for (int co = 0; co < 8; ++co) {
        lo[co] = (_Float16)fmaxf(acc[co], 0.f);
        hi[co] = (_Float16)fmaxf(acc[co + 8], 0.f);
    }
    *(half8*)(out + (size_t)pc * 16) = lo;
    *(half8*)(out + (size_t)pc * 16 + 8) = hi;
}

// ---------------------------------------------------------------------------
// conv2: 16 -> 16 ch via MFMA implicit GEMM.  (unchanged from round 2)
// ---------------------------------------------------------------------------
__global__ __launch_bounds__(256) void conv2_mfma(const _Float16* __restrict__ x,
                                                  const _Float16* __restrict__ wB,
                                                  const float* __restrict__ bias,
                                                  _Float16* __restrict__ out) {
    const int tid = threadIdx.x;
    const int lane = tid & 63;
    const int wid = tid >> 6;
    const int m64 = blockIdx.x * 256 + wid * 64;
    const int w0 = m64 & (WW - 1);
    const int h0 = (m64 >> 7) & (HH - 1);
    const int d0 = m64 >> 14;
    const int pc64 = pcidx(d0, h0, w0);
    const int l15 = lane & 15;
    const int lg = lane >> 4;
    const int tapSel = lg >> 1;
    const int ci0 = (lg & 1) * 8;

    int offl[14];
#pragma unroll
    for (int t = 0; t < 14; ++t) {
        int tap = 2 * t + tapSel;
        if (tap > 26) tap = 26;
        int kd = tap / 9;
        int kh = (tap / 3) % 3;
        int kw = tap % 3;
        offl[t] = (kd - 1) * PHW + (kh - 1) * PW + (kw - 1);
    }

    f32x4 acc0 = {0.f, 0.f, 0.f, 0.f};
    f32x4 acc1 = acc0, acc2 = acc0, acc3 = acc0;
    const int arow = pc64 + l15;

#pragma unroll
    for (int t = 0; t < 14; ++t) {
        half8 b = *(const half8*)(wB + (size_t)((t * 4 + lg) * 16 + l15) * 8);
        int ab = (arow + offl[t]) * 16 + ci0;
        half8 a0 = *(const half8*)(x + ab);
        half8 a1 = *(const half8*)(x + ab + 16 * 16);
        half8 a2 = *(const half8*)(x + ab + 32 * 16);
        half8 a3 = *(const half8*)(x + ab + 48 * 16);
        acc0 = __builtin_amdgcn_mfma_f32_16x16x32_f16(a0, b, acc0, 0, 0, 0);
        acc1 = __builtin_amdgcn_mfma_f32_16x16x32_f16(a1, b, acc1, 0, 0, 0);
        acc2 = __builtin_amdgcn_mfma_f32_16x16x32_f16(a2, b, acc2, 0, 0, 0);
        acc3 = __builtin_amdgcn_mfma_f32_16x16x32_f16(a3, b, acc3, 0, 0, 0);
    }

    float bc = bias[l15];
#pragma unroll
    for (int r = 0; r < 4; ++r) {
        f32x4 a = (r == 0) ? acc0 : (r == 1) ? acc1 : (r == 2) ? acc2 : acc3;
#pragma unroll
        for (int reg = 0; reg < 4; ++reg) {
            int prow = pc64 + r * 16 + lg * 4 + reg;
            float v = fmaxf(a[reg] + bc, 0.f);
            out[(size_t)prow * 16 + l15] = (_Float16)v;
        }
    }
}

// ---------------------------------------------------------------------------
// conv3: 16 -> 1 ch.  4 outputs per thread along w; v_dot2_f32_f16 math.
// x: padded interleaved fp16 [PN][16].  wC: half2-packed weights [27][8].
// ---------------------------------------------------------------------------
__global__ __launch_bounds__(256) void conv3_k(const _Float16* __restrict__ x,
                                               const h2* __restrict__ wC,
                                               const float* __restrict__ bias,
                                               const float* __restrict__ residP,
                                               float* __restrict__ out) {
    int i = blockIdx.x * 256 + threadIdx.x;    // NN/4 threads
    int w0 = (i & 31) * 4;
    int h = (i >> 5) & (HH - 1);
    int d = i >> 12;
    int pc = pcidx(d, h, w0);

    float accA[4] = {0.f, 0.f, 0.f, 0.f};
    float accB[4] = {0.f, 0.f, 0.f, 0.f};

#pragma unroll
    for (int kd = 0; kd < 3; ++kd)
#pragma unroll
        for (int kh = 0; kh < 3; ++kh) {
            const _Float16* base =
                x + (size_t)(pc + (kd - 1) * PHW + (kh - 1) * PW) * 16;
            // 6 columns: w0-1 .. w0+4, 16 ch each = 8 half2 per column
            h2 col[6][8];
#pragma unroll
            for (int c = 0; c < 6; ++c) {
                half8 v0 = *(const half8*)(base + (c - 1) * 16);
                half8 v1 = *(const half8*)(base + (c - 1) * 16 + 8);
#pragma unroll
                for (int j = 0; j < 4; ++j) {
                    h2 a; a[0] = v0[2 * j]; a[1] = v0[2 * j + 1];
                    col[c][j] = a;
                    h2 b; b[0] = v1[2 * j]; b[1] = v1[2 * j + 1];
                    col[c][j + 4] = b;
                }
            }
#pragma unroll
            for (int kw = 0; kw < 3; ++kw) {
                const int tap = (kd * 3 + kh) * 3 + kw;
                h2 wv[8];
#pragma unroll
                for (int j = 0; j < 8; ++j) wv[j] = wC[tap * 8 + j];
#pragma unroll
                for (int o = 0; o < 4; ++o) {
                    const int c = o + kw;   // 0..5
                    float a = accA[o], b = accB[o];
                    a = fdot2f(col[c][0], wv[0], a);
                    b = fdot2f(col[c][1], wv[1], b);
                    a = fdot2f(col[c][2], wv[2], a);
                    b = fdot2f(col[c][3], wv[3], b);
                    a = fdot2f(col[c][4], wv[4], a);
                    b = fdot2f(col[c][5], wv[5], b);
                    a = fdot2f(col[c][6], wv[6], a);
                    b = fdot2f(col[c][7], wv[7], b);
                    accA[o] = a; accB[o] = b;
                }
            }
        }

    float bc = bias[0];
    f32x4 res;
#pragma unroll
    for (int o = 0; o < 4; ++o)
        res[o] = residP[pc + o] + bc + (accA[o] + accB[o]);
    *(f32x4*)(out + (size_t)i * 4) = res;
}

// ---------------------------------------------------------------------------
// update (unchanged, verified)
// ---------------------------------------------------------------------------
__global__ __launch_bounds__(256) void update_k(const float* __restrict__ p0,
                                                const float* __restrict__ q0,
                                                const float* __restrict__ s0,
                                                const float* __restrict__ pn,
                                                const float* __restrict__ qn,
                                                const float* __restrict__ sn,
                                                const float* __restrict__ zn,
                                                float* __restrict__ t,
                                                float* __restrict__ p1,
                                                float* __restrict__ q1,
                                                float* __restrict__ s1,
                                                float* __restrict__ out,
                                                const float* __restrict__ ntx,
                                                const float* __restrict__ nty,
                                                const float* __restrict__ ntz,
                                                const float* __restrict__ nt,
                                                int c) {
    int i = blockIdx.x * 256 + threadIdx.x;
    int w = i & (WW - 1);
    int h = (i >> 7) & (HH - 1);
    int d = i >> 14;
    float cx = ntx[c], cy = nty[c], cz = ntz[c], ct = nt[c];

    float pu = p0[i] + cx * (p0[i] - pn[i]);
    float qu = q0[i] + cy * (q0[i] - qn[i]);
    float su = s0[i] + cz * (s0[i] - sn[i]);
    p1[i] = pu;
    q1[i] = qu;
    s1[i] = su;

    float tv = t[i];
    float zl = tv + ct * (tv - zn[i]);

    float acc = zl;
    if (w > 0) {
        float a = p0[i - 1];
        acc += a + cx * (a - pn[i - 1]);
    }
    if (w < WW - 1) acc -= pu;
    if (h > 0) {
        float a = q0[i - WW];
        acc += a + cy * (a - qn[i - WW]);
    }
    if (h < HH - 1) acc -= qu;
    if (d > 0) {
        float a = s0[i - HWC];
        acc += a + cz * (a - sn[i - HWC]);
    }
    if (d < DD - 1) acc -= su;

    t[i] = acc;
    out[i] = acc;
}

// ---------------------------------------------------------------------------
extern "C" void kernel_launch(void* const* d_in, const int* in_sizes, int n_in,
                              void* d_out, int out_size, void* d_ws, size_t ws_size,
                              hipStream_t stream) {
    const float* image = (const float*)d_in[0];
    const float* sino  = (const float*)d_in[1];
    const float* w1    = (const float*)d_in[2];
    const float* b1    = (const float*)d_in[3];
    const float* w2    = (const float*)d_in[4];
    const float* b2    = (const float*)d_in[5];
    const float* w3    = (const float*)d_in[6];
    const float* b3    = (const float*)d_in[7];
    const float* ntx   = (const float*)d_in[8];
    const float* nty   = (const float*)d_in[9];
    const float* ntz   = (const float*)d_in[10];
    const float* nt    = (const float*)d_in[11];

    float* out = (float*)d_out;
    float* ws  = (float*)d_ws;

    // unpadded fp32 state
    float* t     = ws;
    float* pbuf[2] = {ws + (size_t)1 * NN, ws + (size_t)4 * NN};
    float* qbuf[2] = {ws + (size_t)2 * NN, ws + (size_t)5 * NN};
    float* sbuf[2] = {ws + (size_t)3 * NN, ws + (size_t)6 * NN};
    float* pn = ws + (size_t)7 * NN;
    float* qn = ws + (size_t)8 * NN;
    float* sn = ws + (size_t)9 * NN;
    float* zn = ws + (size_t)10 * NN;
    float* r  = ws + (size_t)11 * NN;            // HWC floats

    // padded region (zeroed each launch)
    float* padbase = ws + (size_t)12 * NN;
    float* zP  = padbase;
    float* dxP = padbase + (size_t)1 * PN;
    float* dyP = padbase + (size_t)2 * PN;
    float* dzP = padbase + (size_t)3 * PN;
    _Float16* h1 = (_Float16*)(padbase + (size_t)4 * PN);    // PN*16 halves
    _Float16* h2b = (_Float16*)(padbase + (size_t)12 * PN);  // PN*16 halves
    _Float16* wBp = (_Float16*)(padbase + (size_t)20 * PN);  // 4*7168 halves
    h2* wCp = (h2*)(wBp + 4 * 7168);                          // 4*216 half2

    const int NB = NN / 256;   // 4096
    const int HB = HWC / 256;  // 64
    const int QB = NN / 4 / 256; // 1024

    hipMemsetAsync(padbase, 0, (size_t)20 * PN * sizeof(float), stream);
    prep_w2<<<14, 256, 0, stream>>>(w2, wBp);
    prep_w3<<<4, 256, 0, stream>>>(w3, wCp);
    init_k<<<NB, 256, 0, stream>>>(image, t, out, pbuf[0], qbuf[0], sbuf[0]);

    int cur = 0;
    for (int c = 0; c < 3; ++c) {
        colsum_k<<<HB, 256, 0, stream>>>(t, sino, r);
        zdiff_k<<<NB, 256, 0, stream>>>(t, r, zP, dxP, dyP, dzP);

        const float* xinP[4] = {dxP, dyP, dzP, zP};
        float*       oae[4]  = {pn, qn, sn, zn};
        for (int bi = 0; bi < 4; ++bi) {
            conv1_k<<<NB, 256, 0, stream>>>(xinP[bi], w1 + (size_t)bi * 432,
                                            b1 + (size_t)bi * 16, h1);
            conv2_mfma<<<NB, 256, 0, stream>>>(h1, wBp + (size_t)bi * 7168,
                                               b2 + (size_t)bi * 16, h2b);
            conv3_k<<<QB, 256, 0, stream>>>(h2b, wCp + (size_t)bi * 216,
                                            b3 + (size_t)bi, xinP[bi], oae[bi]);
        }

        update_k<<<NB, 256, 0, stream>>>(pbuf[cur], qbuf[cur], sbuf[cur],
                                         pn, qn, sn, zn, t,
                                         pbuf[1 - cur], qbuf[1 - cur], sbuf[1 - cur],
                                         out + (size_t)(c + 1) * NN,
                                         ntx, nty, ntz, nt, c);
        cur ^= 1;
    }
}

// Round 5
// 1299.493 us; speedup vs baseline: 17.8474x; 1.2006x over previous
//
#include <hip/hip_runtime.h>
#include <cstddef>

#define DD 64
#define HH 128
#define WW 128
#define HWC (HH * WW)            // 16384
#define NN (DD * HWC)            // 1048576

// padded spatial dims (+1 halo each side)
#define PD 66
#define PH 130
#define PW 130
#define PHW (PH * PW)            // 16900
#define PN (PD * PHW)            // 1115400

typedef __attribute__((ext_vector_type(8))) _Float16 half8;
typedef __attribute__((ext_vector_type(2))) _Float16 h2;
typedef __attribute__((ext_vector_type(4))) float f32x4;
typedef __attribute__((ext_vector_type(2))) float f32x2;

__device__ __forceinline__ int pcidx(int d, int h, int w) {
    return (d + 1) * PHW + (h + 1) * PW + (w + 1);
}

__device__ __forceinline__ float fdot2f(h2 a, h2 b, float c) {
#if __has_builtin(__builtin_amdgcn_fdot2)
    return __builtin_amdgcn_fdot2(a, b, c, false);
#else
    return fmaf((float)a[0], (float)b[0], fmaf((float)a[1], (float)b[1], c));
#endif
}

// ---------------------------------------------------------------------------
// init: t = image, out[0..NN) = image, p=q=s=0
// ---------------------------------------------------------------------------
__global__ __launch_bounds__(256) void init_k(const float* __restrict__ img,
                                              float* __restrict__ t,
                                              float* __restrict__ out0,
                                              float* __restrict__ p,
                                              float* __restrict__ q,
                                              float* __restrict__ s) {
    int i = blockIdx.x * 256 + threadIdx.x;
    float v = img[i];
    t[i] = v;
    out0[i] = v;
    p[i] = 0.f;
    q[i] = 0.f;
    s[i] = 0.f;
}

// ---------------------------------------------------------------------------
// colsum: r[hw] = (sino[hw] - sum_d t[d,hw]) / DD
// ---------------------------------------------------------------------------
__global__ __launch_bounds__(256) void colsum_k(const float* __restrict__ t,
                                                const float* __restrict__ sino,
                                                float* __restrict__ r) {
    int hw = blockIdx.x * 256 + threadIdx.x;
    float sum = 0.f;
#pragma unroll 8
    for (int d = 0; d < DD; ++d) sum += t[d * HWC + hw];
    r[hw] = (sino[hw] - sum) * (1.0f / DD);
}

// ---------------------------------------------------------------------------
// zdiff: writes PADDED z, dx, dy, dz (fp32). Pads are pre-zeroed.
// ---------------------------------------------------------------------------
__global__ __launch_bounds__(256) void zdiff_k(const float* __restrict__ t,
                                               const float* __restrict__ r,
                                               float* __restrict__ zP,
                                               float* __restrict__ dxP,
                                               float* __restrict__ dyP,
                                               float* __restrict__ dzP) {
    int i = blockIdx.x * 256 + threadIdx.x;
    int w = i & (WW - 1);
    int h = (i >> 7) & (HH - 1);
    int d = i >> 14;
    int hw = i & (HWC - 1);
    int pc = pcidx(d, h, w);
    float tv = t[i];
    float rv = r[hw];
    float zv = tv + rv;
    zP[pc] = zv;
    dxP[pc] = (w < WW - 1) ? (t[i + 1] + r[hw + 1]) - zv : 0.f;
    dyP[pc] = (h < HH - 1) ? (t[i + WW] + r[hw + WW]) - zv : 0.f;
    dzP[pc] = (d < DD - 1) ? (t[i + HWC] - tv) : 0.f;
}

// ---------------------------------------------------------------------------
// prep_w1: pack conv1 weights [bi][co][27] fp32 -> [bi][tap][16co] fp32
// ---------------------------------------------------------------------------
__global__ __launch_bounds__(256) void prep_w1(const float* __restrict__ w1,
                                               float* __restrict__ wA) {
    int idx = blockIdx.x * 256 + threadIdx.x;   // 4*27*16 = 1728
    if (idx >= 1728) return;
    int bi = idx / 432;
    int rem = idx - bi * 432;
    int tap = rem >> 4;
    int co = rem & 15;
    wA[idx] = w1[bi * 432 + co * 27 + tap];
}

// ---------------------------------------------------------------------------
// prep_w2: repack conv2 weights [bi][co][ci][27] fp32 ->
//          fp16 frag layout [(bi*56 + kc)*16 + co][8], k = tap*16+ci
// ---------------------------------------------------------------------------
__global__ __launch_bounds__(256) void prep_w2(const float* __restrict__ w2,
                                               _Float16* __restrict__ wB) {
    int idx = blockIdx.x * 256 + threadIdx.x;   // 4*56*16 = 3584
    if (idx >= 3584) return;
    int bi = idx / 896;
    int rem = idx - bi * 896;
    int kc = rem >> 4;
    int co = rem & 15;
    int tap = kc >> 1;
    int ci0 = (kc & 1) * 8;
    half8 v;
#pragma unroll
    for (int j = 0; j < 8; ++j) {
        float f = (tap < 27) ? w2[bi * 6912 + (co * 16 + ci0 + j) * 27 + tap] : 0.f;
        v[j] = (_Float16)f;
    }
    *(half8*)(wB + (size_t)idx * 8) = v;
}

// ---------------------------------------------------------------------------
// prep_w3: pack conv3 weights [bi][ci][27] fp32 -> half2 pairs
//          wC[bi][tap][j] = (w3[2j][tap], w3[2j+1][tap]),  j = 0..7
// ---------------------------------------------------------------------------
__global__ __launch_bounds__(256) void prep_w3(const float* __restrict__ w3,
                                               h2* __restrict__ wC) {
    int idx = blockIdx.x * 256 + threadIdx.x;   // 4*27*8 = 864
    if (idx >= 864) return;
    int bi = idx / 216;
    int rem = idx - bi * 216;
    int tap = rem >> 3;
    int j = rem & 7;
    h2 v;
    v[0] = (_Float16)w3[bi * 432 + (2 * j) * 27 + tap];
    v[1] = (_Float16)w3[bi * 432 + (2 * j + 1) * 27 + tap];
    wC[idx] = v;
}

// ---------------------------------------------------------------------------
// conv1: 1 -> 16 ch. 4 outputs/thread along w; row-segment reuse.
// x: padded fp32. wA: packed [tap][16co]. out: padded interleaved fp16, relu.
// ---------------------------------------------------------------------------
__global__ __launch_bounds__(256) void conv1_k(const float* __restrict__ x,
                                               const float* __restrict__ wA,
                                               const float* __restrict__ bias,
                                               _Float16* __restrict__ out) {
    int i = blockIdx.x * 256 + threadIdx.x;    // NN/4 threads
    int w0 = (i & 31) * 4;
    int h = (i >> 5) & (HH - 1);
    int d = i >> 12;
    int pc = pcidx(d, h, w0);

    float acc[4][16];
#pragma unroll
    for (int o = 0; o < 4; ++o)
#pragma unroll
        for (int co = 0; co < 16; ++co) acc[o][co] = bias[co];

#pragma unroll
    for (int kd = 0; kd < 3; ++kd)
#pragma unroll
        for (int kh = 0; kh < 3; ++kh) {
            const float* base = x + pc + (kd - 1) * PHW + (kh - 1) * PW;
            // columns w0-1 .. w0+4 (6 floats)
            f32x4 u = *(const f32x4*)(base - 1);
            f32x2 v = *(const f32x2*)(base + 3);
            float c[6] = {u[0], u[1], u[2], u[3], v[0], v[1]};
#pragma unroll
            for (int kw = 0; kw < 3; ++kw) {
                const int tap = (kd * 3 + kh) * 3 + kw;
                const float* wt = wA + tap * 16;
#pragma unroll
                for (int o = 0; o < 4; ++o) {
                    float vv = c[o + kw];
#pragma unroll
                    for (int co = 0; co < 16; ++co)
                        acc[o][co] = fmaf(vv, wt[co], acc[o][co]);
                }
            }
        }

#pragma unroll
    for (int o = 0; o < 4; ++o) {
        half8 lo, hi;
#pragma unroll
        for (int co = 0; co < 8; ++co) {
            lo[co] = (_Float16)fmaxf(acc[o][co], 0.f);
            hi[co] = (_Float16)fmaxf(acc[o][co + 8], 0.f);
        }
        _Float16* po = out + (size_t)(pc + o) * 16;
        *(half8*)po = lo;
        *(half8*)(po + 8) = hi;
    }
}

// ---------------------------------------------------------------------------
// conv2: 16 -> 16 ch via MFMA implicit GEMM.  (unchanged, verified)
// ---------------------------------------------------------------------------
__global__ __launch_bounds__(256) void conv2_mfma(const _Float16* __restrict__ x,
                                                  const _Float16* __restrict__ wB,
                                                  const float* __restrict__ bias,
                                                  _Float16* __restrict__ out) {
    const int tid = threadIdx.x;
    const int lane = tid & 63;
    const int wid = tid >> 6;
    const int m64 = blockIdx.x * 256 + wid * 64;
    const int w0 = m64 & (WW - 1);
    const int h0 = (m64 >> 7) & (HH - 1);
    const int d0 = m64 >> 14;
    const int pc64 = pcidx(d0, h0, w0);
    const int l15 = lane & 15;
    const int lg = lane >> 4;
    const int tapSel = lg >> 1;
    const int ci0 = (lg & 1) * 8;

    int offl[14];
#pragma unroll
    for (int t = 0; t < 14; ++t) {
        int tap = 2 * t + tapSel;
        if (tap > 26) tap = 26;
        int kd = tap / 9;
        int kh = (tap / 3) % 3;
        int kw = tap % 3;
        offl[t] = (kd - 1) * PHW + (kh - 1) * PW + (kw - 1);
    }

    f32x4 acc0 = {0.f, 0.f, 0.f, 0.f};
    f32x4 acc1 = acc0, acc2 = acc0, acc3 = acc0;
    const int arow = pc64 + l15;

#pragma unroll
    for (int t = 0; t < 14; ++t) {
        half8 b = *(const half8*)(wB + (size_t)((t * 4 + lg) * 16 + l15) * 8);
        int ab = (arow + offl[t]) * 16 + ci0;
        half8 a0 = *(const half8*)(x + ab);
        half8 a1 = *(const half8*)(x + ab + 16 * 16);
        half8 a2 = *(const half8*)(x + ab + 32 * 16);
        half8 a3 = *(const half8*)(x + ab + 48 * 16);
        acc0 = __builtin_amdgcn_mfma_f32_16x16x32_f16(a0, b, acc0, 0, 0, 0);
        acc1 = __builtin_amdgcn_mfma_f32_16x16x32_f16(a1, b, acc1, 0, 0, 0);
        acc2 = __builtin_amdgcn_mfma_f32_16x16x32_f16(a2, b, acc2, 0, 0, 0);
        acc3 = __builtin_amdgcn_mfma_f32_16x16x32_f16(a3, b, acc3, 0, 0, 0);
    }

    float bc = bias[l15];
#pragma unroll
    for (int r = 0; r < 4; ++r) {
        f32x4 a = (r == 0) ? acc0 : (r == 1) ? acc1 : (r == 2) ? acc2 : acc3;
#pragma unroll
        for (int reg = 0; reg < 4; ++reg) {
            int prow = pc64 + r * 16 + lg * 4 + reg;
            float v = fmaxf(a[reg] + bc, 0.f);
            out[(size_t)prow * 16 + l15] = (_Float16)v;
        }
    }
}

// ---------------------------------------------------------------------------
// conv3: 16 -> 1 ch.  ONE output/thread (dense 32B/lane loads) + dot2 math.
// x: padded interleaved fp16 [PN][16].  wC: half2-packed weights [27][8].
// ---------------------------------------------------------------------------
__global__ __launch_bounds__(256) void conv3_k(const _Float16* __restrict__ x,
                                               const h2* __restrict__ wC,
                                               const float* __restrict__ bias,
                                               const float* __restrict__ residP,
                                               float* __restrict__ out) {
    int i = blockIdx.x * 256 + threadIdx.x;
    int w = i & (WW - 1);
    int h = (i >> 7) & (HH - 1);
    int d = i >> 14;
    int pc = pcidx(d, h, w);

    float a0 = 0.f, a1 = 0.f, a2 = 0.f, a3 = 0.f;

#pragma unroll
    for (int kd = 0; kd < 3; ++kd)
#pragma unroll
        for (int kh = 0; kh < 3; ++kh)
#pragma unroll
            for (int kw = 0; kw < 3; ++kw) {
                const int off = (kd - 1) * PHW + (kh - 1) * PW + (kw - 1);
                const int tap = (kd * 3 + kh) * 3 + kw;
                const _Float16* px = x + (size_t)(pc + off) * 16;
                half8 v0 = *(const half8*)px;
                half8 v1 = *(const half8*)(px + 8);
                const h2* wv = wC + tap * 8;
                h2 p;
                p[0] = v0[0]; p[1] = v0[1]; a0 = fdot2f(p, wv[0], a0);
                p[0] = v0[2]; p[1] = v0[3]; a1 = fdot2f(p, wv[1], a1);
                p[0] = v0[4]; p[1] = v0[5]; a2 = fdot2f(p, wv[2], a2);
                p[0] = v0[6]; p[1] = v0[7]; a3 = fdot2f(p, wv[3], a3);
                p[0] = v1[0]; p[1] = v1[1]; a0 = fdot2f(p, wv[4], a0);
                p[0] = v1[2]; p[1] = v1[3]; a1 = fdot2f(p, wv[5], a1);
                p[0] = v1[4]; p[1] = v1[5]; a2 = fdot2f(p, wv[6], a2);
                p[0] = v1[6]; p[1] = v1[7]; a3 = fdot2f(p, wv[7], a3);
            }

    out[i] = residP[pc] + bias[0] + ((a0 + a1) + (a2 + a3));
}

// ---------------------------------------------------------------------------
// update (unchanged, verified)
// ---------------------------------------------------------------------------
__global__ __launch_bounds__(256) void update_k(const float* __restrict__ p0,
                                                const float* __restrict__ q0,
                                                const float* __restrict__ s0,
                                                const float* __restrict__ pn,
                                                const float* __restrict__ qn,
                                                const float* __restrict__ sn,
                                                const float* __restrict__ zn,
                                                float* __restrict__ t,
                                                float* __restrict__ p1,
                                                float* __restrict__ q1,
                                                float* __restrict__ s1,
                                                float* __restrict__ out,
                                                const float* __restrict__ ntx,
                                                const float* __restrict__ nty,
                                                const float* __restrict__ ntz,
                                                const float* __restrict__ nt,
                                                int c) {
    int i = blockIdx.x * 256 + threadIdx.x;
    int w = i & (WW - 1);
    int h = (i >> 7) & (HH - 1);
    int d = i >> 14;
    float cx = ntx[c], cy = nty[c], cz = ntz[c], ct = nt[c];

    float pu = p0[i] + cx * (p0[i] - pn[i]);
    float qu = q0[i] + cy * (q0[i] - qn[i]);
    float su = s0[i] + cz * (s0[i] - sn[i]);
    p1[i] = pu;
    q1[i] = qu;
    s1[i] = su;

    float tv = t[i];
    float zl = tv + ct * (tv - zn[i]);

    float acc = zl;
    if (w > 0) {
        float a = p0[i - 1];
        acc += a + cx * (a - pn[i - 1]);
    }
    if (w < WW - 1) acc -= pu;
    if (h > 0) {
        float a = q0[i - WW];
        acc += a + cy * (a - qn[i - WW]);
    }
    if (h < HH - 1) acc -= qu;
    if (d > 0) {
        float a = s0[i - HWC];
        acc += a + cz * (a - sn[i - HWC]);
    }
    if (d < DD - 1) acc -= su;

    t[i] = acc;
    out[i] = acc;
}

// ---------------------------------------------------------------------------
extern "C" void kernel_launch(void* const* d_in, const int* in_sizes, int n_in,
                              void* d_out, int out_size, void* d_ws, size_t ws_size,
                              hipStream_t stream) {
    const float* image = (const float*)d_in[0];
    const float* sino  = (const float*)d_in[1];
    const float* w1    = (const float*)d_in[2];
    const float* b1    = (const float*)d_in[3];
    const float* w2    = (const float*)d_in[4];
    const float* b2    = (const float*)d_in[5];
    const float* w3    = (const float*)d_in[6];
    const float* b3    = (const float*)d_in[7];
    const float* ntx   = (const float*)d_in[8];
    const float* nty   = (const float*)d_in[9];
    const float* ntz   = (const float*)d_in[10];
    const float* nt    = (const float*)d_in[11];

    float* out = (float*)d_out;
    float* ws  = (float*)d_ws;

    // unpadded fp32 state
    float* t     = ws;
    float* pbuf[2] = {ws + (size_t)1 * NN, ws + (size_t)4 * NN};
    float* qbuf[2] = {ws + (size_t)2 * NN, ws + (size_t)5 * NN};
    float* sbuf[2] = {ws + (size_t)3 * NN, ws + (size_t)6 * NN};
    float* pn = ws + (size_t)7 * NN;
    float* qn = ws + (size_t)8 * NN;
    float* sn = ws + (size_t)9 * NN;
    float* zn = ws + (size_t)10 * NN;
    float* r  = ws + (size_t)11 * NN;            // HWC floats

    // padded region (zeroed each launch)
    float* padbase = ws + (size_t)12 * NN;
    float* zP  = padbase;
    float* dxP = padbase + (size_t)1 * PN;
    float* dyP = padbase + (size_t)2 * PN;
    float* dzP = padbase + (size_t)3 * PN;
    _Float16* h1 = (_Float16*)(padbase + (size_t)4 * PN);    // PN*16 halves
    _Float16* h2b = (_Float16*)(padbase + (size_t)12 * PN);  // PN*16 halves
    _Float16* wBp = (_Float16*)(padbase + (size_t)20 * PN);  // 4*7168 halves
    h2* wCp = (h2*)(wBp + 4 * 7168);                          // 4*216 half2
    float* wAp = padbase + (size_t)20 * PN + 16384;           // 4*432 fp32

    const int NB = NN / 256;     // 4096
    const int HB = HWC / 256;    // 64
    const int QB = NN / 4 / 256; // 1024

    hipMemsetAsync(padbase, 0, (size_t)20 * PN * sizeof(float), stream);
    prep_w1<<<7, 256, 0, stream>>>(w1, wAp);
    prep_w2<<<14, 256, 0, stream>>>(w2, wBp);
    prep_w3<<<4, 256, 0, stream>>>(w3, wCp);
    init_k<<<NB, 256, 0, stream>>>(image, t, out, pbuf[0], qbuf[0], sbuf[0]);

    int cur = 0;
    for (int c = 0; c < 3; ++c) {
        colsum_k<<<HB, 256, 0, stream>>>(t, sino, r);
        zdiff_k<<<NB, 256, 0, stream>>>(t, r, zP, dxP, dyP, dzP);

        const float* xinP[4] = {dxP, dyP, dzP, zP};
        float*       oae[4]  = {pn, qn, sn, zn};
        for (int bi = 0; bi < 4; ++bi) {
            conv1_k<<<QB, 256, 0, stream>>>(xinP[bi], wAp + (size_t)bi * 432,
                                            b1 + (size_t)bi * 16, h1);
            conv2_mfma<<<NB, 256, 0, stream>>>(h1, wBp + (size_t)bi * 7168,
                                               b2 + (size_t)bi * 16, h2b);
            conv3_k<<<NB, 256, 0, stream>>>(h2b, wCp + (size_t)bi * 216,
                                            b3 + (size_t)bi, xinP[bi], oae[bi]);
        }

        update_k<<<NB, 256, 0, stream>>>(pbuf[cur], qbuf[cur], sbuf[cur],
                                         pn, qn, sn, zn, t,
                                         pbuf[1 - cur], qbuf[1 - cur], sbuf[1 - cur],
                                         out + (size_t)(c + 1) * NN,
                                         ntx, nty, ntz, nt, c);
        cur ^= 1;
    }
}

// Round 6
// 1228.990 us; speedup vs baseline: 18.8713x; 1.0574x over previous
//
#include <hip/hip_runtime.h>
#include <cstddef>

#define DD 64
#define HH 128
#define WW 128
#define HWC (HH * WW)            // 16384
#define NN (DD * HWC)            // 1048576

// padded spatial dims (+1 halo each side)
#define PD 66
#define PH 130
#define PW 130
#define PHW (PH * PW)            // 16900
#define PN (PD * PHW)            // 1115400

typedef __attribute__((ext_vector_type(8))) _Float16 half8;
typedef __attribute__((ext_vector_type(2))) _Float16 h2;
typedef __attribute__((ext_vector_type(4))) float f32x4;
typedef __attribute__((ext_vector_type(2))) float f32x2;

__device__ __forceinline__ int pcidx(int d, int h, int w) {
    return (d + 1) * PHW + (h + 1) * PW + (w + 1);
}

__device__ __forceinline__ float fdot2f(h2 a, h2 b, float c) {
#if __has_builtin(__builtin_amdgcn_fdot2)
    return __builtin_amdgcn_fdot2(a, b, c, false);
#else
    return fmaf((float)a[0], (float)b[0], fmaf((float)a[1], (float)b[1], c));
#endif
}

// ---------------------------------------------------------------------------
// pad_zero: zero ONLY the halo cells of the padded buffers (replaces the
// 89 MB memset; interior cells are fully rewritten every cascade).
// ---------------------------------------------------------------------------
__global__ __launch_bounds__(256) void pad_zero(float* __restrict__ zP,
                                                float* __restrict__ dxP,
                                                float* __restrict__ dyP,
                                                float* __restrict__ dzP,
                                                _Float16* __restrict__ h1,
                                                _Float16* __restrict__ h2b) {
    int idx = blockIdx.x * 256 + threadIdx.x;
    if (idx >= PN) return;
    int d = idx / PHW;
    int rem = idx - d * PHW;
    int h = rem / PW;
    int w = rem - h * PW;
    bool pad = (d == 0) | (d == PD - 1) | (h == 0) | (h == PH - 1) |
               (w == 0) | (w == PW - 1);
    if (!pad) return;
    zP[idx] = 0.f;
    dxP[idx] = 0.f;
    dyP[idx] = 0.f;
    dzP[idx] = 0.f;
    half8 z = {};
    *(half8*)(h1 + (size_t)idx * 16) = z;
    *(half8*)(h1 + (size_t)idx * 16 + 8) = z;
    *(half8*)(h2b + (size_t)idx * 16) = z;
    *(half8*)(h2b + (size_t)idx * 16 + 8) = z;
}

// ---------------------------------------------------------------------------
// init: t = image, out[0..NN) = image, p=q=s=0
// ---------------------------------------------------------------------------
__global__ __launch_bounds__(256) void init_k(const float* __restrict__ img,
                                              float* __restrict__ t,
                                              float* __restrict__ out0,
                                              float* __restrict__ p,
                                              float* __restrict__ q,
                                              float* __restrict__ s) {
    int i = blockIdx.x * 256 + threadIdx.x;
    float v = img[i];
    t[i] = v;
    out0[i] = v;
    p[i] = 0.f;
    q[i] = 0.f;
    s[i] = 0.f;
}

// ---------------------------------------------------------------------------
// colsum: r[hw] = (sino[hw] - sum_d t[d,hw]) / DD
// ---------------------------------------------------------------------------
__global__ __launch_bounds__(256) void colsum_k(const float* __restrict__ t,
                                                const float* __restrict__ sino,
                                                float* __restrict__ r) {
    int hw = blockIdx.x * 256 + threadIdx.x;
    float sum = 0.f;
#pragma unroll 8
    for (int d = 0; d < DD; ++d) sum += t[d * HWC + hw];
    r[hw] = (sino[hw] - sum) * (1.0f / DD);
}

// ---------------------------------------------------------------------------
// zdiff: writes PADDED z, dx, dy, dz (fp32). Pads are pre-zeroed.
// ---------------------------------------------------------------------------
__global__ __launch_bounds__(256) void zdiff_k(const float* __restrict__ t,
                                               const float* __restrict__ r,
                                               float* __restrict__ zP,
                                               float* __restrict__ dxP,
                                               float* __restrict__ dyP,
                                               float* __restrict__ dzP) {
    int i = blockIdx.x * 256 + threadIdx.x;
    int w = i & (WW - 1);
    int h = (i >> 7) & (HH - 1);
    int d = i >> 14;
    int hw = i & (HWC - 1);
    int pc = pcidx(d, h, w);
    float tv = t[i];
    float rv = r[hw];
    float zv = tv + rv;
    zP[pc] = zv;
    dxP[pc] = (w < WW - 1) ? (t[i + 1] + r[hw + 1]) - zv : 0.f;
    dyP[pc] = (h < HH - 1) ? (t[i + WW] + r[hw + WW]) - zv : 0.f;
    dzP[pc] = (d < DD - 1) ? (t[i + HWC] - tv) : 0.f;
}

// ---------------------------------------------------------------------------
// prep_w1: pack conv1 weights [bi][co][27] fp32 -> [bi][tap][16co] fp32
// ---------------------------------------------------------------------------
__global__ __launch_bounds__(256) void prep_w1(const float* __restrict__ w1,
                                               float* __restrict__ wA) {
    int idx = blockIdx.x * 256 + threadIdx.x;   // 4*27*16 = 1728
    if (idx >= 1728) return;
    int bi = idx / 432;
    int rem = idx - bi * 432;
    int tap = rem >> 4;
    int co = rem & 15;
    wA[idx] = w1[bi * 432 + co * 27 + tap];
}

// ---------------------------------------------------------------------------
// prep_w2: repack conv2 weights [bi][co][ci][27] fp32 ->
//          fp16 frag layout [(bi*56 + kc)*16 + co][8], k = tap*16+ci
// ---------------------------------------------------------------------------
__global__ __launch_bounds__(256) void prep_w2(const float* __restrict__ w2,
                                               _Float16* __restrict__ wB) {
    int idx = blockIdx.x * 256 + threadIdx.x;   // 4*56*16 = 3584
    if (idx >= 3584) return;
    int bi = idx / 896;
    int rem = idx - bi * 896;
    int kc = rem >> 4;
    int co = rem & 15;
    int tap = kc >> 1;
    int ci0 = (kc & 1) * 8;
    half8 v;
#pragma unroll
    for (int j = 0; j < 8; ++j) {
        float f = (tap < 27) ? w2[bi * 6912 + (co * 16 + ci0 + j) * 27 + tap] : 0.f;
        v[j] = (_Float16)f;
    }
    *(half8*)(wB + (size_t)idx * 8) = v;
}

// ---------------------------------------------------------------------------
// prep_w3: pack conv3 weights [bi][ci][27] fp32 -> half2 pairs
//          wC[bi][tap][j] = (w3[2j][tap], w3[2j+1][tap]),  j = 0..7
// ---------------------------------------------------------------------------
__global__ __launch_bounds__(256) void prep_w3(const float* __restrict__ w3,
                                               h2* __restrict__ wC) {
    int idx = blockIdx.x * 256 + threadIdx.x;   // 4*27*8 = 864
    if (idx >= 864) return;
    int bi = idx / 216;
    int rem = idx - bi * 216;
    int tap = rem >> 3;
    int j = rem & 7;
    h2 v;
    v[0] = (_Float16)w3[bi * 432 + (2 * j) * 27 + tap];
    v[1] = (_Float16)w3[bi * 432 + (2 * j + 1) * 27 + tap];
    wC[idx] = v;
}

// ---------------------------------------------------------------------------
// conv1: 1 -> 16 ch. 4 outputs/thread along w; row-segment reuse.
// ---------------------------------------------------------------------------
__global__ __launch_bounds__(256) void conv1_k(const float* __restrict__ x,
                                               const float* __restrict__ wA,
                                               const float* __restrict__ bias,
                                               _Float16* __restrict__ out) {
    int i = blockIdx.x * 256 + threadIdx.x;    // NN/4 threads
    int w0 = (i & 31) * 4;
    int h = (i >> 5) & (HH - 1);
    int d = i >> 12;
    int pc = pcidx(d, h, w0);

    float acc[4][16];
#pragma unroll
    for (int o = 0; o < 4; ++o)
#pragma unroll
        for (int co = 0; co < 16; ++co) acc[o][co] = bias[co];

#pragma unroll
    for (int kd = 0; kd < 3; ++kd)
#pragma unroll
        for (int kh = 0; kh < 3; ++kh) {
            const float* base = x + pc + (kd - 1) * PHW + (kh - 1) * PW;
            f32x4 u = *(const f32x4*)(base - 1);
            f32x2 v = *(const f32x2*)(base + 3);
            float c[6] = {u[0], u[1], u[2], u[3], v[0], v[1]};
#pragma unroll
            for (int kw = 0; kw < 3; ++kw) {
                const int tap = (kd * 3 + kh) * 3 + kw;
                const float* wt = wA + tap * 16;
#pragma unroll
                for (int o = 0; o < 4; ++o) {
                    float vv = c[o + kw];
#pragma unroll
                    for (int co = 0; co < 16; ++co)
                        acc[o][co] = fmaf(vv, wt[co], acc[o][co]);
                }
            }
        }

#pragma unroll
    for (int o = 0; o < 4; ++o) {
        half8 lo, hi;
#pragma unroll
        for (int co = 0; co < 8; ++co) {
            lo[co] = (_Float16)fmaxf(acc[o][co], 0.f);
            hi[co] = (_Float16)fmaxf(acc[o][co + 8], 0.f);
        }
        _Float16* po = out + (size_t)(pc + o) * 16;
        *(half8*)po = lo;
        *(half8*)(po + 8) = hi;
    }
}

// ---------------------------------------------------------------------------
// conv2: 16 -> 16 ch via MFMA implicit GEMM.  (unchanged, verified)
// ---------------------------------------------------------------------------
__global__ __launch_bounds__(256) void conv2_mfma(const _Float16* __restrict__ x,
                                                  const _Float16* __restrict__ wB,
                                                  const float* __restrict__ bias,
                                                  _Float16* __restrict__ out) {
    const int tid = threadIdx.x;
    const int lane = tid & 63;
    const int wid = tid >> 6;
    const int m64 = blockIdx.x * 256 + wid * 64;
    const int w0 = m64 & (WW - 1);
    const int h0 = (m64 >> 7) & (HH - 1);
    const int d0 = m64 >> 14;
    const int pc64 = pcidx(d0, h0, w0);
    const int l15 = lane & 15;
    const int lg = lane >> 4;
    const int tapSel = lg >> 1;
    const int ci0 = (lg & 1) * 8;

    int offl[14];
#pragma unroll
    for (int t = 0; t < 14; ++t) {
        int tap = 2 * t + tapSel;
        if (tap > 26) tap = 26;
        int kd = tap / 9;
        int kh = (tap / 3) % 3;
        int kw = tap % 3;
        offl[t] = (kd - 1) * PHW + (kh - 1) * PW + (kw - 1);
    }

    f32x4 acc0 = {0.f, 0.f, 0.f, 0.f};
    f32x4 acc1 = acc0, acc2 = acc0, acc3 = acc0;
    const int arow = pc64 + l15;

#pragma unroll
    for (int t = 0; t < 14; ++t) {
        half8 b = *(const half8*)(wB + (size_t)((t * 4 + lg) * 16 + l15) * 8);
        int ab = (arow + offl[t]) * 16 + ci0;
        half8 a0 = *(const half8*)(x + ab);
        half8 a1 = *(const half8*)(x + ab + 16 * 16);
        half8 a2 = *(const half8*)(x + ab + 32 * 16);
        half8 a3 = *(const half8*)(x + ab + 48 * 16);
        acc0 = __builtin_amdgcn_mfma_f32_16x16x32_f16(a0, b, acc0, 0, 0, 0);
        acc1 = __builtin_amdgcn_mfma_f32_16x16x32_f16(a1, b, acc1, 0, 0, 0);
        acc2 = __builtin_amdgcn_mfma_f32_16x16x32_f16(a2, b, acc2, 0, 0, 0);
        acc3 = __builtin_amdgcn_mfma_f32_16x16x32_f16(a3, b, acc3, 0, 0, 0);
    }

    float bc = bias[l15];
#pragma unroll
    for (int r = 0; r < 4; ++r) {
        f32x4 a = (r == 0) ? acc0 : (r == 1) ? acc1 : (r == 2) ? acc2 : acc3;
#pragma unroll
        for (int reg = 0; reg < 4; ++reg) {
            int prow = pc64 + r * 16 + lg * 4 + reg;
            float v = fmaxf(a[reg] + bc, 0.f);
            out[(size_t)prow * 16 + l15] = (_Float16)v;
        }
    }
}

// ---------------------------------------------------------------------------
// conv3: 16 -> 1 ch.  4 outputs/thread along DEPTH (lanes stay dense in w);
// 6 shared planes per (kh,kw) serve the 3 kd taps of all 4 outputs -> 2x
// fewer loads. dot2 math, fp32 accum.
// ---------------------------------------------------------------------------
__global__ __launch_bounds__(256) void conv3_k(const _Float16* __restrict__ x,
                                               const h2* __restrict__ wC,
                                               const float* __restrict__ bias,
                                               const float* __restrict__ residP,
                                               float* __restrict__ out) {
    int i = blockIdx.x * 256 + threadIdx.x;    // NN/4 threads
    int w = i & (WW - 1);
    int h = (i >> 7) & (HH - 1);
    int dq = i >> 14;                          // 0..15
    int d0 = dq * 4;
    int pc = pcidx(d0, h, w);

    float accA[4] = {0.f, 0.f, 0.f, 0.f};
    float accB[4] = {0.f, 0.f, 0.f, 0.f};

#pragma unroll
    for (int kh = 0; kh < 3; ++kh)
#pragma unroll
        for (int kw = 0; kw < 3; ++kw) {
            const _Float16* base =
                x + (size_t)(pc - PHW + (kh - 1) * PW + (kw - 1)) * 16;
#pragma unroll
            for (int p = 0; p < 6; ++p) {     // depth planes d0-1 .. d0+4
                const _Float16* px = base + (size_t)p * PHW * 16;
                half8 v0 = *(const half8*)px;
                half8 v1 = *(const half8*)(px + 8);
#pragma unroll
                for (int kd = 0; kd < 3; ++kd) {
                    const int o = p - kd;
                    if (o < 0 || o > 3) continue;
                    const h2* wv = wC + (size_t)(kd * 9 + kh * 3 + kw) * 8;
                    h2 t2;
                    float a = accA[o], b = accB[o];
                    t2[0] = v0[0]; t2[1] = v0[1]; a = fdot2f(t2, wv[0], a);
                    t2[0] = v0[2]; t2[1] = v0[3]; b = fdot2f(t2, wv[1], b);
                    t2[0] = v0[4]; t2[1] = v0[5]; a = fdot2f(t2, wv[2], a);
                    t2[0] = v0[6]; t2[1] = v0[7]; b = fdot2f(t2, wv[3], b);
                    t2[0] = v1[0]; t2[1] = v1[1]; a = fdot2f(t2, wv[4], a);
                    t2[0] = v1[2]; t2[1] = v1[3]; b = fdot2f(t2, wv[5], b);
                    t2[0] = v1[4]; t2[1] = v1[5]; a = fdot2f(t2, wv[6], a);
                    t2[0] = v1[6]; t2[1] = v1[7]; b = fdot2f(t2, wv[7], b);
                    accA[o] = a; accB[o] = b;
                }
            }
        }

    float bc = bias[0];
    int ob = (d0 << 14) + (h << 7) + w;
#pragma unroll
    for (int o = 0; o < 4; ++o)
        out[ob + o * HWC] = residP[pc + o * PHW] + bc + (accA[o] + accB[o]);
}

// ---------------------------------------------------------------------------
// update (unchanged, verified)
// ---------------------------------------------------------------------------
__global__ __launch_bounds__(256) void update_k(const float* __restrict__ p0,
                                                const float* __restrict__ q0,
                                                const float* __restrict__ s0,
                                                const float* __restrict__ pn,
                                                const float* __restrict__ qn,
                                                const float* __restrict__ sn,
                                                const float* __restrict__ zn,
                                                float* __restrict__ t,
                                                float* __restrict__ p1,
                                                float* __restrict__ q1,
                                                float* __restrict__ s1,
                                                float* __restrict__ out,
                                                const float* __restrict__ ntx,
                                                const float* __restrict__ nty,
                                                const float* __restrict__ ntz,
                                                const float* __restrict__ nt,
                                                int c) {
    int i = blockIdx.x * 256 + threadIdx.x;
    int w = i & (WW - 1);
    int h = (i >> 7) & (HH - 1);
    int d = i >> 14;
    float cx = ntx[c], cy = nty[c], cz = ntz[c], ct = nt[c];

    float pu = p0[i] + cx * (p0[i] - pn[i]);
    float qu = q0[i] + cy * (q0[i] - qn[i]);
    float su = s0[i] + cz * (s0[i] - sn[i]);
    p1[i] = pu;
    q1[i] = qu;
    s1[i] = su;

    float tv = t[i];
    float zl = tv + ct * (tv - zn[i]);

    float acc = zl;
    if (w > 0) {
        float a = p0[i - 1];
        acc += a + cx * (a - pn[i - 1]);
    }
    if (w < WW - 1) acc -= pu;
    if (h > 0) {
        float a = q0[i - WW];
        acc += a + cy * (a - qn[i - WW]);
    }
    if (h < HH - 1) acc -= qu;
    if (d > 0) {
        float a = s0[i - HWC];
        acc += a + cz * (a - sn[i - HWC]);
    }
    if (d < DD - 1) acc -= su;

    t[i] = acc;
    out[i] = acc;
}

// ---------------------------------------------------------------------------
extern "C" void kernel_launch(void* const* d_in, const int* in_sizes, int n_in,
                              void* d_out, int out_size, void* d_ws, size_t ws_size,
                              hipStream_t stream) {
    const float* image = (const float*)d_in[0];
    const float* sino  = (const float*)d_in[1];
    const float* w1    = (const float*)d_in[2];
    const float* b1    = (const float*)d_in[3];
    const float* w2    = (const float*)d_in[4];
    const float* b2    = (const float*)d_in[5];
    const float* w3    = (const float*)d_in[6];
    const float* b3    = (const float*)d_in[7];
    const float* ntx   = (const float*)d_in[8];
    const float* nty   = (const float*)d_in[9];
    const float* ntz   = (const float*)d_in[10];
    const float* nt    = (const float*)d_in[11];

    float* out = (float*)d_out;
    float* ws  = (float*)d_ws;

    // unpadded fp32 state
    float* t     = ws;
    float* pbuf[2] = {ws + (size_t)1 * NN, ws + (size_t)4 * NN};
    float* qbuf[2] = {ws + (size_t)2 * NN, ws + (size_t)5 * NN};
    float* sbuf[2] = {ws + (size_t)3 * NN, ws + (size_t)6 * NN};
    float* pn = ws + (size_t)7 * NN;
    float* qn = ws + (size_t)8 * NN;
    float* sn = ws + (size_t)9 * NN;
    float* zn = ws + (size_t)10 * NN;
    float* r  = ws + (size_t)11 * NN;            // HWC floats

    // padded region (pads zeroed by pad_zero each launch)
    float* padbase = ws + (size_t)12 * NN;
    float* zP  = padbase;
    float* dxP = padbase + (size_t)1 * PN;
    float* dyP = padbase + (size_t)2 * PN;
    float* dzP = padbase + (size_t)3 * PN;
    _Float16* h1 = (_Float16*)(padbase + (size_t)4 * PN);    // PN*16 halves
    _Float16* h2b = (_Float16*)(padbase + (size_t)12 * PN);  // PN*16 halves
    _Float16* wBp = (_Float16*)(padbase + (size_t)20 * PN);  // 4*7168 halves
    h2* wCp = (h2*)(wBp + 4 * 7168);                          // 4*216 half2
    float* wAp = padbase + (size_t)20 * PN + 16384;           // 4*432 fp32

    const int NB = NN / 256;     // 4096
    const int HB = HWC / 256;    // 64
    const int QB = NN / 4 / 256; // 1024
    const int PB = (PN + 255) / 256;

    pad_zero<<<PB, 256, 0, stream>>>(zP, dxP, dyP, dzP, h1, h2b);
    prep_w1<<<7, 256, 0, stream>>>(w1, wAp);
    prep_w2<<<14, 256, 0, stream>>>(w2, wBp);
    prep_w3<<<4, 256, 0, stream>>>(w3, wCp);
    init_k<<<NB, 256, 0, stream>>>(image, t, out, pbuf[0], qbuf[0], sbuf[0]);

    int cur = 0;
    for (int c = 0; c < 3; ++c) {
        colsum_k<<<HB, 256, 0, stream>>>(t, sino, r);
        zdiff_k<<<NB, 256, 0, stream>>>(t, r, zP, dxP, dyP, dzP);

        const float* xinP[4] = {dxP, dyP, dzP, zP};
        float*       oae[4]  = {pn, qn, sn, zn};
        for (int bi = 0; bi < 4; ++bi) {
            conv1_k<<<QB, 256, 0, stream>>>(xinP[bi], wAp + (size_t)bi * 432,
                                            b1 + (size_t)bi * 16, h1);
            conv2_mfma<<<NB, 256, 0, stream>>>(h1, wBp + (size_t)bi * 7168,
                                               b2 + (size_t)bi * 16, h2b);
            conv3_k<<<QB, 256, 0, stream>>>(h2b, wCp + (size_t)bi * 216,
                                            b3 + (size_t)bi, xinP[bi], oae[bi]);
        }

        update_k<<<NB, 256, 0, stream>>>(pbuf[cur], qbuf[cur], sbuf[cur],
                                         pn, qn, sn, zn, t,
                                         pbuf[1 - cur], qbuf[1 - cur], sbuf[1 - cur],
                                         out + (size_t)(c + 1) * NN,
                                         ntx, nty, ntz, nt, c);
        cur ^= 1;
    }
}

// Round 9
// 1223.483 us; speedup vs baseline: 18.9562x; 1.0045x over previous
//
#include <hip/hip_runtime.h>
#include <cstddef>

#define DD 64
#define HH 128
#define WW 128
#define HWC (HH * WW)            // 16384
#define NN (DD * HWC)            // 1048576

// padded spatial dims (+1 halo each side)
#define PD 66
#define PH 130
#define PW 130
#define PHW (PH * PW)            // 16900
#define PN (PD * PHW)            // 1115400

typedef __attribute__((ext_vector_type(8))) _Float16 half8;
typedef __attribute__((ext_vector_type(2))) _Float16 h2;
typedef __attribute__((ext_vector_type(4))) float f32x4;
typedef __attribute__((ext_vector_type(2))) float f32x2;

__device__ __forceinline__ int pcidx(int d, int h, int w) {
    return (d + 1) * PHW + (h + 1) * PW + (w + 1);
}

__device__ __forceinline__ float fdot2f(h2 a, h2 b, float c) {
#if __has_builtin(__builtin_amdgcn_fdot2)
    return __builtin_amdgcn_fdot2(a, b, c, false);
#else
    return fmaf((float)a[0], (float)b[0], fmaf((float)a[1], (float)b[1], c));
#endif
}

// ---------------------------------------------------------------------------
// pad_zero: zero ONLY halo cells of padded buffers. nb h-buffer pairs with
// stride hstride (halves).
// ---------------------------------------------------------------------------
__global__ __launch_bounds__(256) void pad_zero(float* __restrict__ zP,
                                                float* __restrict__ dxP,
                                                float* __restrict__ dyP,
                                                float* __restrict__ dzP,
                                                _Float16* __restrict__ h1all,
                                                _Float16* __restrict__ h2all,
                                                int nb, size_t hstride) {
    int idx = blockIdx.x * 256 + threadIdx.x;
    if (idx >= PN) return;
    int d = idx / PHW;
    int rem = idx - d * PHW;
    int h = rem / PW;
    int w = rem - h * PW;
    bool pad = (d == 0) | (d == PD - 1) | (h == 0) | (h == PH - 1) |
               (w == 0) | (w == PW - 1);
    if (!pad) return;
    zP[idx] = 0.f;
    dxP[idx] = 0.f;
    dyP[idx] = 0.f;
    dzP[idx] = 0.f;
    half8 z = {};
    for (int k = 0; k < nb; ++k) {
        _Float16* p1 = h1all + (size_t)k * hstride + (size_t)idx * 16;
        _Float16* p2 = h2all + (size_t)k * hstride + (size_t)idx * 16;
        *(half8*)p1 = z;
        *(half8*)(p1 + 8) = z;
        *(half8*)p2 = z;
        *(half8*)(p2 + 8) = z;
    }
}

// ---------------------------------------------------------------------------
// init: t = image, out[0..NN) = image, p=q=s=0
// ---------------------------------------------------------------------------
__global__ __launch_bounds__(256) void init_k(const float* __restrict__ img,
                                              float* __restrict__ t,
                                              float* __restrict__ out0,
                                              float* __restrict__ p,
                                              float* __restrict__ q,
                                              float* __restrict__ s) {
    int i = blockIdx.x * 256 + threadIdx.x;
    float v = img[i];
    t[i] = v;
    out0[i] = v;
    p[i] = 0.f;
    q[i] = 0.f;
    s[i] = 0.f;
}

// ---------------------------------------------------------------------------
// colsum: r[hw] = (sino[hw] - sum_d t[d,hw]) / DD
// ---------------------------------------------------------------------------
__global__ __launch_bounds__(256) void colsum_k(const float* __restrict__ t,
                                                const float* __restrict__ sino,
                                                float* __restrict__ r) {
    int hw = blockIdx.x * 256 + threadIdx.x;
    float sum = 0.f;
#pragma unroll 8
    for (int d = 0; d < DD; ++d) sum += t[d * HWC + hw];
    r[hw] = (sino[hw] - sum) * (1.0f / DD);
}

// ---------------------------------------------------------------------------
// zdiff: writes PADDED z, dx, dy, dz (fp32). Pads are pre-zeroed.
// ---------------------------------------------------------------------------
__global__ __launch_bounds__(256) void zdiff_k(const float* __restrict__ t,
                                               const float* __restrict__ r,
                                               float* __restrict__ zP,
                                               float* __restrict__ dxP,
                                               float* __restrict__ dyP,
                                               float* __restrict__ dzP) {
    int i = blockIdx.x * 256 + threadIdx.x;
    int w = i & (WW - 1);
    int h = (i >> 7) & (HH - 1);
    int d = i >> 14;
    int hw = i & (HWC - 1);
    int pc = pcidx(d, h, w);
    float tv = t[i];
    float rv = r[hw];
    float zv = tv + rv;
    zP[pc] = zv;
    dxP[pc] = (w < WW - 1) ? (t[i + 1] + r[hw + 1]) - zv : 0.f;
    dyP[pc] = (h < HH - 1) ? (t[i + WW] + r[hw + WW]) - zv : 0.f;
    dzP[pc] = (d < DD - 1) ? (t[i + HWC] - tv) : 0.f;
}

// ---------------------------------------------------------------------------
// prep_all: pack w1 -> [bi][tap][16co] fp32 (idx 0..1727)
//           w2 -> fp16 frag layout (idx 1728..5311)
//           w3 -> half2 pairs (idx 5312..6175)
// ---------------------------------------------------------------------------
__global__ __launch_bounds__(256) void prep_all(const float* __restrict__ w1,
                                                const float* __restrict__ w2,
                                                const float* __restrict__ w3,
                                                float* __restrict__ wA,
                                                _Float16* __restrict__ wB,
                                                h2* __restrict__ wC) {
    int idx = blockIdx.x * 256 + threadIdx.x;
    if (idx < 1728) {
        int bi = idx / 432;
        int rem = idx - bi * 432;
        int tap = rem >> 4;
        int co = rem & 15;
        wA[idx] = w1[bi * 432 + co * 27 + tap];
    } else if (idx < 5312) {
        int k = idx - 1728;
        int bi = k / 896;
        int rem = k - bi * 896;
        int kc = rem >> 4;
        int co = rem & 15;
        int tap = kc >> 1;
        int ci0 = (kc & 1) * 8;
        half8 v;
#pragma unroll
        for (int j = 0; j < 8; ++j) {
            float f = (tap < 27) ? w2[bi * 6912 + (co * 16 + ci0 + j) * 27 + tap]
                                 : 0.f;
            v[j] = (_Float16)f;
        }
        *(half8*)(wB + (size_t)k * 8) = v;
    } else if (idx < 6176) {
        int k = idx - 5312;
        int bi = k / 216;
        int rem = k - bi * 216;
        int tap = rem >> 3;
        int j = rem & 7;
        h2 v;
        v[0] = (_Float16)w3[bi * 432 + (2 * j) * 27 + tap];
        v[1] = (_Float16)w3[bi * 432 + (2 * j + 1) * 27 + tap];
        wC[k] = v;
    }
}

// ---------------------------------------------------------------------------
// conv1_b: 1 -> 16 ch. 4 outputs/thread along w; row-segment reuse.
// bi = bi_base + blockIdx.y. input = padbase + PN*((bi+1)&3).
// ---------------------------------------------------------------------------
__global__ __launch_bounds__(256) void conv1_b(const float* __restrict__ padbase,
                                               const float* __restrict__ wA,
                                               const float* __restrict__ b1,
                                               _Float16* __restrict__ h1all,
                                               size_t hstride, int bi_base) {
    const int bi = bi_base + blockIdx.y;
    const float* x = padbase + (size_t)PN * ((bi + 1) & 3);
    const float* wAb = wA + bi * 432;
    const float* bias = b1 + bi * 16;
    _Float16* out = h1all + (size_t)bi * hstride;

    int i = blockIdx.x * 256 + threadIdx.x;    // NN/4 threads
    int w0 = (i & 31) * 4;
    int h = (i >> 5) & (HH - 1);
    int d = i >> 12;
    int pc = pcidx(d, h, w0);

    float acc[4][16];
#pragma unroll
    for (int o = 0; o < 4; ++o)
#pragma unroll
        for (int co = 0; co < 16; ++co) acc[o][co] = bias[co];

#pragma unroll
    for (int kd = 0; kd < 3; ++kd)
#pragma unroll
        for (int kh = 0; kh < 3; ++kh) {
            const float* base = x + pc + (kd - 1) * PHW + (kh - 1) * PW;
            f32x4 u = *(const f32x4*)(base - 1);
            f32x2 v = *(const f32x2*)(base + 3);
            float c[6] = {u[0], u[1], u[2], u[3], v[0], v[1]};
#pragma unroll
            for (int kw = 0; kw < 3; ++kw) {
                const int tap = (kd * 3 + kh) * 3 + kw;
                const float* wt = wAb + tap * 16;
#pragma unroll
                for (int o = 0; o < 4; ++o) {
                    float vv = c[o + kw];
#pragma unroll
                    for (int co = 0; co < 16; ++co)
                        acc[o][co] = fmaf(vv, wt[co], acc[o][co]);
                }
            }
        }

#pragma unroll
    for (int o = 0; o < 4; ++o) {
        half8 lo, hi;
#pragma unroll
        for (int co = 0; co < 8; ++co) {
            lo[co] = (_Float16)fmaxf(acc[o][co], 0.f);
            hi[co] = (_Float16)fmaxf(acc[o][co + 8], 0.f);
        }
        _Float16* po = out + (size_t)(pc + o) * 16;
        *(half8*)po = lo;
        *(half8*)(po + 8) = hi;
    }
}

// ---------------------------------------------------------------------------
// conv2_b: 16 -> 16 ch via MFMA implicit GEMM, batched over bi.
// ---------------------------------------------------------------------------
__global__ __launch_bounds__(256) void conv2_b(const _Float16* __restrict__ h1all,
                                               const _Float16* __restrict__ wB,
                                               const float* __restrict__ b2,
                                               _Float16* __restrict__ h2all,
                                               size_t hstride, int bi_base) {
    const int bi = bi_base + blockIdx.y;
    const _Float16* x = h1all + (size_t)bi * hstride;
    const _Float16* wBb = wB + (size_t)bi * 7168;
    const float* bias = b2 + bi * 16;
    _Float16* out = h2all + (size_t)bi * hstride;

    const int tid = threadIdx.x;
    const int lane = tid & 63;
    const int wid = tid >> 6;
    const int m64 = blockIdx.x * 256 + wid * 64;
    const int w0 = m64 & (WW - 1);
    const int h0 = (m64 >> 7) & (HH - 1);
    const int d0 = m64 >> 14;
    const int pc64 = pcidx(d0, h0, w0);
    const int l15 = lane & 15;
    const int lg = lane >> 4;
    const int tapSel = lg >> 1;
    const int ci0 = (lg & 1) * 8;

    int offl[14];
#pragma unroll
    for (int t = 0; t < 14; ++t) {
        int tap = 2 * t + tapSel;
        if (tap > 26) tap = 26;
        int kd = tap / 9;
        int kh = (tap / 3) % 3;
        int kw = tap % 3;
        offl[t] = (kd - 1) * PHW + (kh - 1) * PW + (kw - 1);
    }

    f32x4 acc0 = {0.f, 0.f, 0.f, 0.f};
    f32x4 acc1 = acc0, acc2 = acc0, acc3 = acc0;
    const int arow = pc64 + l15;

#pragma unroll
    for (int t = 0; t < 14; ++t) {
        half8 b = *(const half8*)(wBb + (size_t)((t * 4 + lg) * 16 + l15) * 8);
        int ab = (arow + offl[t]) * 16 + ci0;
        half8 a0 = *(const half8*)(x + ab);
        half8 a1 = *(const half8*)(x + ab + 16 * 16);
        half8 a2 = *(const half8*)(x + ab + 32 * 16);
        half8 a3 = *(const half8*)(x + ab + 48 * 16);
        acc0 = __builtin_amdgcn_mfma_f32_16x16x32_f16(a0, b, acc0, 0, 0, 0);
        acc1 = __builtin_amdgcn_mfma_f32_16x16x32_f16(a1, b, acc1, 0, 0, 0);
        acc2 = __builtin_amdgcn_mfma_f32_16x16x32_f16(a2, b, acc2, 0, 0, 0);
        acc3 = __builtin_amdgcn_mfma_f32_16x16x32_f16(a3, b, acc3, 0, 0, 0);
    }

    float bc = bias[l15];
#pragma unroll
    for (int r = 0; r < 4; ++r) {
        f32x4 a = (r == 0) ? acc0 : (r == 1) ? acc1 : (r == 2) ? acc2 : acc3;
#pragma unroll
        for (int reg = 0; reg < 4; ++reg) {
            int prow = pc64 + r * 16 + lg * 4 + reg;
            float v = fmaxf(a[reg] + bc, 0.f);
            out[(size_t)prow * 16 + l15] = (_Float16)v;
        }
    }
}

// ---------------------------------------------------------------------------
// conv3_b: 16 -> 1 ch, 4 outputs/thread along depth, dot2 math; batched.
// out = pnBase + bi*NN; resid = padbase + PN*((bi+1)&3).
// ---------------------------------------------------------------------------
__global__ __launch_bounds__(256) void conv3_b(const _Float16* __restrict__ h2all,
                                               const h2* __restrict__ wC,
                                               const float* __restrict__ b3,
                                               const float* __restrict__ padbase,
                                               float* __restrict__ pnBase,
                                               size_t hstride, int bi_base) {
    const int bi = bi_base + blockIdx.y;
    const _Float16* x = h2all + (size_t)bi * hstride;
    const h2* wCb = wC + (size_t)bi * 216;
    const float* residP = padbase + (size_t)PN * ((bi + 1) & 3);
    float* out = pnBase + (size_t)bi * NN;
    const float bc = b3[bi];

    int i = blockIdx.x * 256 + threadIdx.x;    // NN/4 threads
    int w = i & (WW - 1);
    int h = (i >> 7) & (HH - 1);
    int dq = i >> 14;                          // 0..15
    int d0 = dq * 4;
    int pc = pcidx(d0, h, w);

    float accA[4] = {0.f, 0.f, 0.f, 0.f};
    float accB[4] = {0.f, 0.f, 0.f, 0.f};

#pragma unroll
    for (int kh = 0; kh < 3; ++kh)
#pragma unroll
        for (int kw = 0; kw < 3; ++kw) {
            const _Float16* base =
                x + (size_t)(pc - PHW + (kh - 1) * PW + (kw - 1)) * 16;
#pragma unroll
            for (int p = 0; p < 6; ++p) {     // depth planes d0-1 .. d0+4
                const _Float16* px = base + (size_t)p * PHW * 16;
                half8 v0 = *(const half8*)px;
                half8 v1 = *(const half8*)(px + 8);
#pragma unroll
                for (int kd = 0; kd < 3; ++kd) {
                    const int o = p - kd;
                    if (o < 0 || o > 3) continue;
                    const h2* wv = wCb + (size_t)(kd * 9 + kh * 3 + kw) * 8;
                    h2 t2;
                    float a = accA[o], b = accB[o];
                    t2[0] = v0[0]; t2[1] = v0[1]; a = fdot2f(t2, wv[0], a);
                    t2[0] = v0[2]; t2[1] = v0[3]; b = fdot2f(t2, wv[1], b);
                    t2[0] = v0[4]; t2[1] = v0[5]; a = fdot2f(t2, wv[2], a);
                    t2[0] = v0[6]; t2[1] = v0[7]; b = fdot2f(t2, wv[3], b);
                    t2[0] = v1[0]; t2[1] = v1[1]; a = fdot2f(t2, wv[4], a);
                    t2[0] = v1[2]; t2[1] = v1[3]; b = fdot2f(t2, wv[5], b);
                    t2[0] = v1[4]; t2[1] = v1[5]; a = fdot2f(t2, wv[6], a);
                    t2[0] = v1[6]; t2[1] = v1[7]; b = fdot2f(t2, wv[7], b);
                    accA[o] = a; accB[o] = b;
                }
            }
        }

    int ob = (d0 << 14) + (h << 7) + w;
#pragma unroll
    for (int o = 0; o < 4; ++o)
        out[ob + o * HWC] = residP[pc + o * PHW] + bc + (accA[o] + accB[o]);
}

// ---------------------------------------------------------------------------
// update (unchanged, verified)
// ---------------------------------------------------------------------------
__global__ __launch_bounds__(256) void update_k(const float* __restrict__ p0,
                                                const float* __restrict__ q0,
                                                const float* __restrict__ s0,
                                                const float* __restrict__ pn,
                                                const float* __restrict__ qn,
                                                const float* __restrict__ sn,
                                                const float* __restrict__ zn,
                                                float* __restrict__ t,
                                                float* __restrict__ p1,
                                                float* __restrict__ q1,
                                                float* __restrict__ s1,
                                                float* __restrict__ out,
                                                const float* __restrict__ ntx,
                                                const float* __restrict__ nty,
                                                const float* __restrict__ ntz,
                                                const float* __restrict__ nt,
                                                int c) {
    int i = blockIdx.x * 256 + threadIdx.x;
    int w = i & (WW - 1);
    int h = (i >> 7) & (HH - 1);
    int d = i >> 14;
    float cx = ntx[c], cy = nty[c], cz = ntz[c], ct = nt[c];

    float pu = p0[i] + cx * (p0[i] - pn[i]);
    float qu = q0[i] + cy * (q0[i] - qn[i]);
    float su = s0[i] + cz * (s0[i] - sn[i]);
    p1[i] = pu;
    q1[i] = qu;
    s1[i] = su;

    float tv = t[i];
    float zl = tv + ct * (tv - zn[i]);

    float acc = zl;
    if (w > 0) {
        float a = p0[i - 1];
        acc += a + cx * (a - pn[i - 1]);
    }
    if (w < WW - 1) acc -= pu;
    if (h > 0) {
        float a = q0[i - WW];
        acc += a + cy * (a - qn[i - WW]);
    }
    if (h < HH - 1) acc -= qu;
    if (d > 0) {
        float a = s0[i - HWC];
        acc += a + cz * (a - sn[i - HWC]);
    }
    if (d < DD - 1) acc -= su;

    t[i] = acc;
    out[i] = acc;
}

// ---------------------------------------------------------------------------
extern "C" void kernel_launch(void* const* d_in, const int* in_sizes, int n_in,
                              void* d_out, int out_size, void* d_ws, size_t ws_size,
                              hipStream_t stream) {
    const float* image = (const float*)d_in[0];
    const float* sino  = (const float*)d_in[1];
    const float* w1    = (const float*)d_in[2];
    const float* b1    = (const float*)d_in[3];
    const float* w2    = (const float*)d_in[4];
    const float* b2    = (const float*)d_in[5];
    const float* w3    = (const float*)d_in[6];
    const float* b3    = (const float*)d_in[7];
    const float* ntx   = (const float*)d_in[8];
    const float* nty   = (const float*)d_in[9];
    const float* ntz   = (const float*)d_in[10];
    const float* nt    = (const float*)d_in[11];

    float* out = (float*)d_out;
    float* ws  = (float*)d_ws;

    // unpadded fp32 state
    float* t     = ws;
    float* pbuf[2] = {ws + (size_t)1 * NN, ws + (size_t)4 * NN};
    float* qbuf[2] = {ws + (size_t)2 * NN, ws + (size_t)5 * NN};
    float* sbuf[2] = {ws + (size_t)3 * NN, ws + (size_t)6 * NN};
    float* pn = ws + (size_t)7 * NN;   // pn,qn,sn,zn contiguous (bi*NN)
    float* r  = ws + (size_t)11 * NN;  // HWC floats

    // padded region
    float* padbase = ws + (size_t)12 * NN;
    float* zP  = padbase;                          // bi=3 input
    float* dxP = padbase + (size_t)1 * PN;         // bi=0
    float* dyP = padbase + (size_t)2 * PN;         // bi=1
    float* dzP = padbase + (size_t)3 * PN;         // bi=2

    // batched layout: 4 h1 + 4 h2 buffers
    const size_t HS = (size_t)PN * 16;             // halves per h-buffer
    _Float16* h1all = (_Float16*)(padbase + (size_t)4 * PN);
    // batched: h2all after 4 h1 buffers; sequential: right after 1 h1 buffer
    size_t needed_batched =
        ((size_t)12 * NN + (size_t)4 * PN + 17000) * 4 + 2 * 4 * HS * 2;
    bool batched = ws_size >= needed_batched;
    int nb = batched ? 4 : 1;
    size_t hstride = batched ? HS : 0;

    _Float16* h2all = h1all + (size_t)nb * HS;
    float* wtail = (float*)(h2all + (size_t)nb * HS);
    _Float16* wBp = (_Float16*)wtail;              // 4*7168 halves
    h2* wCp = (h2*)(wBp + 4 * 7168);               // 4*216 h2
    float* wAp = (float*)(wCp + 4 * 216);          // 4*432 fp32

    const int NB = NN / 256;     // 4096
    const int HB = HWC / 256;    // 64
    const int QB = NN / 4 / 256; // 1024
    const int PB = (PN + 255) / 256;

    pad_zero<<<PB, 256, 0, stream>>>(zP, dxP, dyP, dzP, h1all, h2all, nb, HS);
    prep_all<<<25, 256, 0, stream>>>(w1, w2, w3, wAp, wBp, wCp);
    init_k<<<NB, 256, 0, stream>>>(image, t, out, pbuf[0], qbuf[0], sbuf[0]);

    int cur = 0;
    for (int c = 0; c < 3; ++c) {
        colsum_k<<<HB, 256, 0, stream>>>(t, sino, r);
        zdiff_k<<<NB, 256, 0, stream>>>(t, r, zP, dxP, dyP, dzP);

        if (batched) {
            conv1_b<<<dim3(QB, 4), 256, 0, stream>>>(padbase, wAp, b1, h1all,
                                                     hstride, 0);
            conv2_b<<<dim3(NB, 4), 256, 0, stream>>>(h1all, wBp, b2, h2all,
                                                     hstride, 0);
            conv3_b<<<dim3(QB, 4), 256, 0, stream>>>(h2all, wCp, b3, padbase,
                                                     pn, hstride, 0);
        } else {
            for (int bi = 0; bi < 4; ++bi) {
                conv1_b<<<dim3(QB, 1), 256, 0, stream>>>(padbase, wAp, b1,
                                                         h1all, 0, bi);
                conv2_b<<<dim3(NB, 1), 256, 0, stream>>>(h1all, wBp, b2,
                                                         h2all, 0, bi);
                conv3_b<<<dim3(QB, 1), 256, 0, stream>>>(h2all, wCp, b3,
                                                         padbase, pn, 0, bi);
            }
        }

        update_k<<<NB, 256, 0, stream>>>(pbuf[cur], qbuf[cur], sbuf[cur],
                                         pn, pn + NN, pn + 2 * (size_t)NN,
                                         pn + 3 * (size_t)NN, t,
                                         pbuf[1 - cur], qbuf[1 - cur], sbuf[1 - cur],
                                         out + (size_t)(c + 1) * NN,
                                         ntx, nty, ntz, nt, c);
        cur ^= 1;
    }
}

// Round 10
// 1069.195 us; speedup vs baseline: 21.6917x; 1.1443x over previous
//
#include <hip/hip_runtime.h>
#include <cstddef>

#define DD 64
#define HH 128
#define WW 128
#define HWC (HH * WW)            // 16384
#define NN (DD * HWC)            // 1048576

// padded spatial dims (+1 halo each side)
#define PD 66
#define PH 130
#define PW 130
#define PHW (PH * PW)            // 16900
#define PN (PD * PHW)            // 1115400

typedef __attribute__((ext_vector_type(8))) _Float16 half8;
typedef __attribute__((ext_vector_type(2))) _Float16 h2;
typedef __attribute__((ext_vector_type(4))) float f32x4;
typedef __attribute__((ext_vector_type(2))) float f32x2;

__device__ __forceinline__ int pcidx(int d, int h, int w) {
    return (d + 1) * PHW + (h + 1) * PW + (w + 1);
}

__device__ __forceinline__ float fdot2f(h2 a, h2 b, float c) {
#if __has_builtin(__builtin_amdgcn_fdot2)
    return __builtin_amdgcn_fdot2(a, b, c, false);
#else
    return fmaf((float)a[0], (float)b[0], fmaf((float)a[1], (float)b[1], c));
#endif
}

// ---------------------------------------------------------------------------
// pad_zero: zero ONLY halo cells of the padded buffers.
// ---------------------------------------------------------------------------
__global__ __launch_bounds__(256) void pad_zero(float* __restrict__ zP,
                                                float* __restrict__ dxP,
                                                float* __restrict__ dyP,
                                                float* __restrict__ dzP,
                                                _Float16* __restrict__ h1,
                                                _Float16* __restrict__ h2b) {
    int idx = blockIdx.x * 256 + threadIdx.x;
    if (idx >= PN) return;
    int d = idx / PHW;
    int rem = idx - d * PHW;
    int h = rem / PW;
    int w = rem - h * PW;
    bool pad = (d == 0) | (d == PD - 1) | (h == 0) | (h == PH - 1) |
               (w == 0) | (w == PW - 1);
    if (!pad) return;
    zP[idx] = 0.f;
    dxP[idx] = 0.f;
    dyP[idx] = 0.f;
    dzP[idx] = 0.f;
    half8 z = {};
    *(half8*)(h1 + (size_t)idx * 16) = z;
    *(half8*)(h1 + (size_t)idx * 16 + 8) = z;
    *(half8*)(h2b + (size_t)idx * 16) = z;
    *(half8*)(h2b + (size_t)idx * 16 + 8) = z;
}

// ---------------------------------------------------------------------------
// init: t = image, out[0..NN) = image, p=q=s=0
// ---------------------------------------------------------------------------
__global__ __launch_bounds__(256) void init_k(const float* __restrict__ img,
                                              float* __restrict__ t,
                                              float* __restrict__ out0,
                                              float* __restrict__ p,
                                              float* __restrict__ q,
                                              float* __restrict__ s) {
    int i = blockIdx.x * 256 + threadIdx.x;
    float v = img[i];
    t[i] = v;
    out0[i] = v;
    p[i] = 0.f;
    q[i] = 0.f;
    s[i] = 0.f;
}

// ---------------------------------------------------------------------------
// colsum: r[hw] = (sino[hw] - sum_d t[d,hw]) / DD
// ---------------------------------------------------------------------------
__global__ __launch_bounds__(256) void colsum_k(const float* __restrict__ t,
                                                const float* __restrict__ sino,
                                                float* __restrict__ r) {
    int hw = blockIdx.x * 256 + threadIdx.x;
    float sum = 0.f;
#pragma unroll 8
    for (int d = 0; d < DD; ++d) sum += t[d * HWC + hw];
    r[hw] = (sino[hw] - sum) * (1.0f / DD);
}

// ---------------------------------------------------------------------------
// zdiff: writes PADDED z, dx, dy, dz (fp32). Pads are pre-zeroed.
// ---------------------------------------------------------------------------
__global__ __launch_bounds__(256) void zdiff_k(const float* __restrict__ t,
                                               const float* __restrict__ r,
                                               float* __restrict__ zP,
                                               float* __restrict__ dxP,
                                               float* __restrict__ dyP,
                                               float* __restrict__ dzP) {
    int i = blockIdx.x * 256 + threadIdx.x;
    int w = i & (WW - 1);
    int h = (i >> 7) & (HH - 1);
    int d = i >> 14;
    int hw = i & (HWC - 1);
    int pc = pcidx(d, h, w);
    float tv = t[i];
    float rv = r[hw];
    float zv = tv + rv;
    zP[pc] = zv;
    dxP[pc] = (w < WW - 1) ? (t[i + 1] + r[hw + 1]) - zv : 0.f;
    dyP[pc] = (h < HH - 1) ? (t[i + WW] + r[hw + WW]) - zv : 0.f;
    dzP[pc] = (d < DD - 1) ? (t[i + HWC] - tv) : 0.f;
}

// ---------------------------------------------------------------------------
// prep_all: pack w1 -> [bi][tap][16co] fp32 (idx 0..1727)
//           w2 -> fp16 frag layout (idx 1728..5311)
//           w3 -> half2 pairs (idx 5312..6175)
// ---------------------------------------------------------------------------
__global__ __launch_bounds__(256) void prep_all(const float* __restrict__ w1,
                                                const float* __restrict__ w2,
                                                const float* __restrict__ w3,
                                                float* __restrict__ wA,
                                                _Float16* __restrict__ wB,
                                                h2* __restrict__ wC) {
    int idx = blockIdx.x * 256 + threadIdx.x;
    if (idx < 1728) {
        int bi = idx / 432;
        int rem = idx - bi * 432;
        int tap = rem >> 4;
        int co = rem & 15;
        wA[idx] = w1[bi * 432 + co * 27 + tap];
    } else if (idx < 5312) {
        int k = idx - 1728;
        int bi = k / 896;
        int rem = k - bi * 896;
        int kc = rem >> 4;
        int co = rem & 15;
        int tap = kc >> 1;
        int ci0 = (kc & 1) * 8;
        half8 v;
#pragma unroll
        for (int j = 0; j < 8; ++j) {
            float f = (tap < 27) ? w2[bi * 6912 + (co * 16 + ci0 + j) * 27 + tap]
                                 : 0.f;
            v[j] = (_Float16)f;
        }
        *(half8*)(wB + (size_t)k * 8) = v;
    } else if (idx < 6176) {
        int k = idx - 5312;
        int bi = k / 216;
        int rem = k - bi * 216;
        int tap = rem >> 3;
        int j = rem & 7;
        h2 v;
        v[0] = (_Float16)w3[bi * 432 + (2 * j) * 27 + tap];
        v[1] = (_Float16)w3[bi * 432 + (2 * j + 1) * 27 + tap];
        wC[k] = v;
    }
}

// ---------------------------------------------------------------------------
// conv1: 1 -> 16 ch. 4 outputs/thread along w; row-segment reuse.
// ---------------------------------------------------------------------------
__global__ __launch_bounds__(256) void conv1_k(const float* __restrict__ x,
                                               const float* __restrict__ wA,
                                               const float* __restrict__ bias,
                                               _Float16* __restrict__ out) {
    int i = blockIdx.x * 256 + threadIdx.x;    // NN/4 threads
    int w0 = (i & 31) * 4;
    int h = (i >> 5) & (HH - 1);
    int d = i >> 12;
    int pc = pcidx(d, h, w0);

    float acc[4][16];
#pragma unroll
    for (int o = 0; o < 4; ++o)
#pragma unroll
        for (int co = 0; co < 16; ++co) acc[o][co] = bias[co];

#pragma unroll
    for (int kd = 0; kd < 3; ++kd)
#pragma unroll
        for (int kh = 0; kh < 3; ++kh) {
            const float* base = x + pc + (kd - 1) * PHW + (kh - 1) * PW;
            f32x4 u = *(const f32x4*)(base - 1);
            f32x2 v = *(const f32x2*)(base + 3);
            float c[6] = {u[0], u[1], u[2], u[3], v[0], v[1]};
#pragma unroll
            for (int kw = 0; kw < 3; ++kw) {
                const int tap = (kd * 3 + kh) * 3 + kw;
                const float* wt = wA + tap * 16;
#pragma unroll
                for (int o = 0; o < 4; ++o) {
                    float vv = c[o + kw];
#pragma unroll
                    for (int co = 0; co < 16; ++co)
                        acc[o][co] = fmaf(vv, wt[co], acc[o][co]);
                }
            }
        }

#pragma unroll
    for (int o = 0; o < 4; ++o) {
        half8 lo, hi;
#pragma unroll
        for (int co = 0; co < 8; ++co) {
            lo[co] = (_Float16)fmaxf(acc[o][co], 0.f);
            hi[co] = (_Float16)fmaxf(acc[o][co + 8], 0.f);
        }
        _Float16* po = out + (size_t)(pc + o) * 16;
        *(half8*)po = lo;
        *(half8*)(po + 8) = hi;
    }
}

// ---------------------------------------------------------------------------
// conv2_lds: 16 -> 16 ch MFMA implicit GEMM with LDS-staged A-tile.
// Block = 256 thr = 4 waves = 2 h-rows x 128 w outputs (one d-plane).
// Staged region: 3d x 4h x 130w rows of 32B = 3120 granules (pad to 3328).
// Granule swizzle G' = G ^ ((G>>3)&1) applied to BOTH the staging source
// and the read address (linear LDS dest required by global_load_lds).
// ---------------------------------------------------------------------------
__global__ __launch_bounds__(256) void conv2_lds(const _Float16* __restrict__ x,
                                                 const _Float16* __restrict__ wB,
                                                 const float* __restrict__ bias,
                                                 _Float16* __restrict__ out) {
    __shared__ __align__(16) _Float16 lds[3328 * 8];   // 53,248 B

    const int tid = threadIdx.x;
    const int lane = tid & 63;
    const int wid = tid >> 6;
    const int m256 = blockIdx.x * 256;
    const int h0 = (m256 >> 7) & (HH - 1);
    const int d0 = m256 >> 14;
    const int origin = d0 * PHW + h0 * PW;   // element idx of region (0,0,0)

    // ---- stage: 13 x global_load_lds(16B) per thread, inverse-swizzled src
    for (int it = 0; it < 13; ++it) {
        int P = it * 256 + tid;               // physical granule (linear dest)
        int G = P ^ ((P >> 3) & 1);           // logical granule
        int lin = G >> 1;                     // region row (32B each)
        int hf = G & 1;                       // 16B half within row
        unsigned seg = (unsigned)lin / 130u;  // 0..12 (12 = overstage tail)
        int wx = lin - (int)seg * 130;
        int dz = (int)seg >> 2, hy = (int)seg & 3;
        const _Float16* src =
            x + ((size_t)(origin + dz * PHW + hy * PW + wx) * 16 + hf * 8);
        _Float16* dst = lds + ((size_t)(it * 256 + wid * 64) * 8);
        __builtin_amdgcn_global_load_lds(
            (const __attribute__((address_space(1))) void*)src,
            (__attribute__((address_space(3))) void*)dst, 16, 0, 0);
    }
    __syncthreads();

    const int l15 = lane & 15;
    const int lg = lane >> 4;
    const int tapSel = lg >> 1;
    const int hf0 = lg & 1;

    // per-lane region row for each packed K-chunk t (j=0; +16 per a-index)
    int rowt[14];
#pragma unroll
    for (int t = 0; t < 14; ++t) {
        int tap = 2 * t + tapSel;
        if (tap > 26) tap = 26;               // K-pad: weights are 0 there
        int kd = tap / 9;
        int kh = (tap / 3) % 3;
        int kw = tap % 3;
        rowt[t] = (kd * 4 + (wid >> 1) + kh) * 130 + (wid & 1) * 64 + l15 + kw;
    }

    f32x4 acc0 = {0.f, 0.f, 0.f, 0.f};
    f32x4 acc1 = acc0, acc2 = acc0, acc3 = acc0;

#pragma unroll
    for (int t = 0; t < 14; ++t) {
        half8 b = *(const half8*)(wB + (size_t)((t * 4 + lg) * 16 + l15) * 8);
        int r = rowt[t];
        int g = r * 2 + (hf0 ^ ((r >> 2) & 1));   // swizzled granule
        const _Float16* pa = lds + (size_t)g * 8;
        half8 a0 = *(const half8*)(pa);            // row r
        half8 a1 = *(const half8*)(pa + 32 * 8);   // row r+16
        half8 a2 = *(const half8*)(pa + 64 * 8);   // row r+32
        half8 a3 = *(const half8*)(pa + 96 * 8);   // row r+48
        acc0 = __builtin_amdgcn_mfma_f32_16x16x32_f16(a0, b, acc0, 0, 0, 0);
        acc1 = __builtin_amdgcn_mfma_f32_16x16x32_f16(a1, b, acc1, 0, 0, 0);
        acc2 = __builtin_amdgcn_mfma_f32_16x16x32_f16(a2, b, acc2, 0, 0, 0);
        acc3 = __builtin_amdgcn_mfma_f32_16x16x32_f16(a3, b, acc3, 0, 0, 0);
    }

    const int pc64 = pcidx(d0, h0 + (wid >> 1), (wid & 1) * 64);
    float bc = bias[l15];
#pragma unroll
    for (int r = 0; r < 4; ++r) {
        f32x4 a = (r == 0) ? acc0 : (r == 1) ? acc1 : (r == 2) ? acc2 : acc3;
#pragma unroll
        for (int reg = 0; reg < 4; ++reg) {
            int prow = pc64 + r * 16 + lg * 4 + reg;
            float v = fmaxf(a[reg] + bc, 0.f);
            out[(size_t)prow * 16 + l15] = (_Float16)v;
        }
    }
}

// ---------------------------------------------------------------------------
// conv3: 16 -> 1 ch, 4 outputs/thread along depth, dot2 math.
// ---------------------------------------------------------------------------
__global__ __launch_bounds__(256) void conv3_k(const _Float16* __restrict__ x,
                                               const h2* __restrict__ wC,
                                               const float* __restrict__ bias,
                                               const float* __restrict__ residP,
                                               float* __restrict__ out) {
    int i = blockIdx.x * 256 + threadIdx.x;    // NN/4 threads
    int w = i & (WW - 1);
    int h = (i >> 7) & (HH - 1);
    int dq = i >> 14;                          // 0..15
    int d0 = dq * 4;
    int pc = pcidx(d0, h, w);

    float accA[4] = {0.f, 0.f, 0.f, 0.f};
    float accB[4] = {0.f, 0.f, 0.f, 0.f};

#pragma unroll
    for (int kh = 0; kh < 3; ++kh)
#pragma unroll
        for (int kw = 0; kw < 3; ++kw) {
            const _Float16* base =
                x + (size_t)(pc - PHW + (kh - 1) * PW + (kw - 1)) * 16;
#pragma unroll
            for (int p = 0; p < 6; ++p) {     // depth planes d0-1 .. d0+4
                const _Float16* px = base + (size_t)p * PHW * 16;
                half8 v0 = *(const half8*)px;
                half8 v1 = *(const half8*)(px + 8);
#pragma unroll
                for (int kd = 0; kd < 3; ++kd) {
                    const int o = p - kd;
                    if (o < 0 || o > 3) continue;
                    const h2* wv = wC + (size_t)(kd * 9 + kh * 3 + kw) * 8;
                    h2 t2;
                    float a = accA[o], b = accB[o];
                    t2[0] = v0[0]; t2[1] = v0[1]; a = fdot2f(t2, wv[0], a);
                    t2[0] = v0[2]; t2[1] = v0[3]; b = fdot2f(t2, wv[1], b);
                    t2[0] = v0[4]; t2[1] = v0[5]; a = fdot2f(t2, wv[2], a);
                    t2[0] = v0[6]; t2[1] = v0[7]; b = fdot2f(t2, wv[3], b);
                    t2[0] = v1[0]; t2[1] = v1[1]; a = fdot2f(t2, wv[4], a);
                    t2[0] = v1[2]; t2[1] = v1[3]; b = fdot2f(t2, wv[5], b);
                    t2[0] = v1[4]; t2[1] = v1[5]; a = fdot2f(t2, wv[6], a);
                    t2[0] = v1[6]; t2[1] = v1[7]; b = fdot2f(t2, wv[7], b);
                    accA[o] = a; accB[o] = b;
                }
            }
        }

    float bc = bias[0];
    int ob = (d0 << 14) + (h << 7) + w;
#pragma unroll
    for (int o = 0; o < 4; ++o)
        out[ob + o * HWC] = residP[pc + o * PHW] + bc + (accA[o] + accB[o]);
}

// ---------------------------------------------------------------------------
// update (unchanged, verified)
// ---------------------------------------------------------------------------
__global__ __launch_bounds__(256) void update_k(const float* __restrict__ p0,
                                                const float* __restrict__ q0,
                                                const float* __restrict__ s0,
                                                const float* __restrict__ pn,
                                                const float* __restrict__ qn,
                                                const float* __restrict__ sn,
                                                const float* __restrict__ zn,
                                                float* __restrict__ t,
                                                float* __restrict__ p1,
                                                float* __restrict__ q1,
                                                float* __restrict__ s1,
                                                float* __restrict__ out,
                                                const float* __restrict__ ntx,
                                                const float* __restrict__ nty,
                                                const float* __restrict__ ntz,
                                                const float* __restrict__ nt,
                                                int c) {
    int i = blockIdx.x * 256 + threadIdx.x;
    int w = i & (WW - 1);
    int h = (i >> 7) & (HH - 1);
    int d = i >> 14;
    float cx = ntx[c], cy = nty[c], cz = ntz[c], ct = nt[c];

    float pu = p0[i] + cx * (p0[i] - pn[i]);
    float qu = q0[i] + cy * (q0[i] - qn[i]);
    float su = s0[i] + cz * (s0[i] - sn[i]);
    p1[i] = pu;
    q1[i] = qu;
    s1[i] = su;

    float tv = t[i];
    float zl = tv + ct * (tv - zn[i]);

    float acc = zl;
    if (w > 0) {
        float a = p0[i - 1];
        acc += a + cx * (a - pn[i - 1]);
    }
    if (w < WW - 1) acc -= pu;
    if (h > 0) {
        float a = q0[i - WW];
        acc += a + cy * (a - qn[i - WW]);
    }
    if (h < HH - 1) acc -= qu;
    if (d > 0) {
        float a = s0[i - HWC];
        acc += a + cz * (a - sn[i - HWC]);
    }
    if (d < DD - 1) acc -= su;

    t[i] = acc;
    out[i] = acc;
}

// ---------------------------------------------------------------------------
extern "C" void kernel_launch(void* const* d_in, const int* in_sizes, int n_in,
                              void* d_out, int out_size, void* d_ws, size_t ws_size,
                              hipStream_t stream) {
    const float* image = (const float*)d_in[0];
    const float* sino  = (const float*)d_in[1];
    const float* w1    = (const float*)d_in[2];
    const float* b1    = (const float*)d_in[3];
    const float* w2    = (const float*)d_in[4];
    const float* b2    = (const float*)d_in[5];
    const float* w3    = (const float*)d_in[6];
    const float* b3    = (const float*)d_in[7];
    const float* ntx   = (const float*)d_in[8];
    const float* nty   = (const float*)d_in[9];
    const float* ntz   = (const float*)d_in[10];
    const float* nt    = (const float*)d_in[11];

    float* out = (float*)d_out;
    float* ws  = (float*)d_ws;

    // unpadded fp32 state
    float* t     = ws;
    float* pbuf[2] = {ws + (size_t)1 * NN, ws + (size_t)4 * NN};
    float* qbuf[2] = {ws + (size_t)2 * NN, ws + (size_t)5 * NN};
    float* sbuf[2] = {ws + (size_t)3 * NN, ws + (size_t)6 * NN};
    float* pn = ws + (size_t)7 * NN;   // pn,qn,sn,zn contiguous (bi*NN)
    float* r  = ws + (size_t)11 * NN;  // HWC floats

    // padded region (halos zeroed by pad_zero each launch)
    float* padbase = ws + (size_t)12 * NN;
    float* zP  = padbase;                          // bi=3 input
    float* dxP = padbase + (size_t)1 * PN;         // bi=0
    float* dyP = padbase + (size_t)2 * PN;         // bi=1
    float* dzP = padbase + (size_t)3 * PN;         // bi=2

    const size_t HS = (size_t)PN * 16;             // halves per h-buffer
    _Float16* h1  = (_Float16*)(padbase + (size_t)4 * PN);
    _Float16* h2b = h1 + HS;
    _Float16* wBp = h2b + HS;                      // 4*7168 halves
    h2* wCp = (h2*)(wBp + 4 * 7168);               // 4*216 h2
    float* wAp = (float*)(wCp + 4 * 216);          // 4*432 fp32

    const int NB = NN / 256;     // 4096
    const int HB = HWC / 256;    // 64
    const int QB = NN / 4 / 256; // 1024
    const int PB = (PN + 255) / 256;

    pad_zero<<<PB, 256, 0, stream>>>(zP, dxP, dyP, dzP, h1, h2b);
    prep_all<<<25, 256, 0, stream>>>(w1, w2, w3, wAp, wBp, wCp);
    init_k<<<NB, 256, 0, stream>>>(image, t, out, pbuf[0], qbuf[0], sbuf[0]);

    int cur = 0;
    for (int c = 0; c < 3; ++c) {
        colsum_k<<<HB, 256, 0, stream>>>(t, sino, r);
        zdiff_k<<<NB, 256, 0, stream>>>(t, r, zP, dxP, dyP, dzP);

        const float* xinP[4] = {dxP, dyP, dzP, zP};
        for (int bi = 0; bi < 4; ++bi) {
            conv1_k<<<QB, 256, 0, stream>>>(xinP[bi], wAp + (size_t)bi * 432,
                                            b1 + (size_t)bi * 16, h1);
            conv2_lds<<<NB, 256, 0, stream>>>(h1, wBp + (size_t)bi * 7168,
                                              b2 + (size_t)bi * 16, h2b);
            conv3_k<<<QB, 256, 0, stream>>>(h2b, wCp + (size_t)bi * 216,
                                            b3 + (size_t)bi, xinP[bi],
                                            pn + (size_t)bi * NN);
        }

        update_k<<<NB, 256, 0, stream>>>(pbuf[cur], qbuf[cur], sbuf[cur],
                                         pn, pn + NN, pn + 2 * (size_t)NN,
                                         pn + 3 * (size_t)NN, t,
                                         pbuf[1 - cur], qbuf[1 - cur], sbuf[1 - cur],
                                         out + (size_t)(c + 1) * NN,
                                         ntx, nty, ntz, nt, c);
        cur ^= 1;
    }
}

// Round 11
// 1069.019 us; speedup vs baseline: 21.6952x; 1.0002x over previous
//
#include <hip/hip_runtime.h>
#include <cstddef>

#define DD 64
#define HH 128
#define WW 128
#define HWC (HH * WW)            // 16384
#define NN (DD * HWC)            // 1048576

// padded spatial dims (+1 halo each side)
#define PD 66
#define PH 130
#define PW 130
#define PHW (PH * PW)            // 16900
#define PN (PD * PHW)            // 1115400

typedef __attribute__((ext_vector_type(8))) _Float16 half8;
typedef __attribute__((ext_vector_type(2))) _Float16 h2;
typedef __attribute__((ext_vector_type(4))) float f32x4;
typedef __attribute__((ext_vector_type(2))) float f32x2;

__device__ __forceinline__ int pcidx(int d, int h, int w) {
    return (d + 1) * PHW + (h + 1) * PW + (w + 1);
}

__device__ __forceinline__ float fdot2f(h2 a, h2 b, float c) {
#if __has_builtin(__builtin_amdgcn_fdot2)
    return __builtin_amdgcn_fdot2(a, b, c, false);
#else
    return fmaf((float)a[0], (float)b[0], fmaf((float)a[1], (float)b[1], c));
#endif
}

// ---------------------------------------------------------------------------
// pad_zero: zero ONLY halo cells of the padded buffers.
// ---------------------------------------------------------------------------
__global__ __launch_bounds__(256) void pad_zero(float* __restrict__ zP,
                                                float* __restrict__ dxP,
                                                float* __restrict__ dyP,
                                                float* __restrict__ dzP,
                                                _Float16* __restrict__ h1,
                                                _Float16* __restrict__ h2b) {
    int idx = blockIdx.x * 256 + threadIdx.x;
    if (idx >= PN) return;
    int d = idx / PHW;
    int rem = idx - d * PHW;
    int h = rem / PW;
    int w = rem - h * PW;
    bool pad = (d == 0) | (d == PD - 1) | (h == 0) | (h == PH - 1) |
               (w == 0) | (w == PW - 1);
    if (!pad) return;
    zP[idx] = 0.f;
    dxP[idx] = 0.f;
    dyP[idx] = 0.f;
    dzP[idx] = 0.f;
    half8 z = {};
    *(half8*)(h1 + (size_t)idx * 16) = z;
    *(half8*)(h1 + (size_t)idx * 16 + 8) = z;
    *(half8*)(h2b + (size_t)idx * 16) = z;
    *(half8*)(h2b + (size_t)idx * 16 + 8) = z;
}

// ---------------------------------------------------------------------------
// init: t = image, out[0..NN) = image, p=q=s=0
// ---------------------------------------------------------------------------
__global__ __launch_bounds__(256) void init_k(const float* __restrict__ img,
                                              float* __restrict__ t,
                                              float* __restrict__ out0,
                                              float* __restrict__ p,
                                              float* __restrict__ q,
                                              float* __restrict__ s) {
    int i = blockIdx.x * 256 + threadIdx.x;
    float v = img[i];
    t[i] = v;
    out0[i] = v;
    p[i] = 0.f;
    q[i] = 0.f;
    s[i] = 0.f;
}

// ---------------------------------------------------------------------------
// colsum: r[hw] = (sino[hw] - sum_d t[d,hw]) / DD
// ---------------------------------------------------------------------------
__global__ __launch_bounds__(256) void colsum_k(const float* __restrict__ t,
                                                const float* __restrict__ sino,
                                                float* __restrict__ r) {
    int hw = blockIdx.x * 256 + threadIdx.x;
    float sum = 0.f;
#pragma unroll 8
    for (int d = 0; d < DD; ++d) sum += t[d * HWC + hw];
    r[hw] = (sino[hw] - sum) * (1.0f / DD);
}

// ---------------------------------------------------------------------------
// zdiff: writes PADDED z, dx, dy, dz (fp32). Pads are pre-zeroed.
// ---------------------------------------------------------------------------
__global__ __launch_bounds__(256) void zdiff_k(const float* __restrict__ t,
                                               const float* __restrict__ r,
                                               float* __restrict__ zP,
                                               float* __restrict__ dxP,
                                               float* __restrict__ dyP,
                                               float* __restrict__ dzP) {
    int i = blockIdx.x * 256 + threadIdx.x;
    int w = i & (WW - 1);
    int h = (i >> 7) & (HH - 1);
    int d = i >> 14;
    int hw = i & (HWC - 1);
    int pc = pcidx(d, h, w);
    float tv = t[i];
    float rv = r[hw];
    float zv = tv + rv;
    zP[pc] = zv;
    dxP[pc] = (w < WW - 1) ? (t[i + 1] + r[hw + 1]) - zv : 0.f;
    dyP[pc] = (h < HH - 1) ? (t[i + WW] + r[hw + WW]) - zv : 0.f;
    dzP[pc] = (d < DD - 1) ? (t[i + HWC] - tv) : 0.f;
}

// ---------------------------------------------------------------------------
// prep_all: pack w1 -> [bi][tap][16co] fp32 (idx 0..1727)
//           w2 -> fp16 frag layout (idx 1728..5311)
//           w3 -> half2 pairs (idx 5312..6175)
// ---------------------------------------------------------------------------
__global__ __launch_bounds__(256) void prep_all(const float* __restrict__ w1,
                                                const float* __restrict__ w2,
                                                const float* __restrict__ w3,
                                                float* __restrict__ wA,
                                                _Float16* __restrict__ wB,
                                                h2* __restrict__ wC) {
    int idx = blockIdx.x * 256 + threadIdx.x;
    if (idx < 1728) {
        int bi = idx / 432;
        int rem = idx - bi * 432;
        int tap = rem >> 4;
        int co = rem & 15;
        wA[idx] = w1[bi * 432 + co * 27 + tap];
    } else if (idx < 5312) {
        int k = idx - 1728;
        int bi = k / 896;
        int rem = k - bi * 896;
        int kc = rem >> 4;
        int co = rem & 15;
        int tap = kc >> 1;
        int ci0 = (kc & 1) * 8;
        half8 v;
#pragma unroll
        for (int j = 0; j < 8; ++j) {
            float f = (tap < 27) ? w2[bi * 6912 + (co * 16 + ci0 + j) * 27 + tap]
                                 : 0.f;
            v[j] = (_Float16)f;
        }
        *(half8*)(wB + (size_t)k * 8) = v;
    } else if (idx < 6176) {
        int k = idx - 5312;
        int bi = k / 216;
        int rem = k - bi * 216;
        int tap = rem >> 3;
        int j = rem & 7;
        h2 v;
        v[0] = (_Float16)w3[bi * 432 + (2 * j) * 27 + tap];
        v[1] = (_Float16)w3[bi * 432 + (2 * j + 1) * 27 + tap];
        wC[k] = v;
    }
}

// ---------------------------------------------------------------------------
// conv1: 1 -> 16 ch. 4 outputs/thread along w; row-segment reuse.
// ---------------------------------------------------------------------------
__global__ __launch_bounds__(256) void conv1_k(const float* __restrict__ x,
                                               const float* __restrict__ wA,
                                               const float* __restrict__ bias,
                                               _Float16* __restrict__ out) {
    int i = blockIdx.x * 256 + threadIdx.x;    // NN/4 threads
    int w0 = (i & 31) * 4;
    int h = (i >> 5) & (HH - 1);
    int d = i >> 12;
    int pc = pcidx(d, h, w0);

    float acc[4][16];
#pragma unroll
    for (int o = 0; o < 4; ++o)
#pragma unroll
        for (int co = 0; co < 16; ++co) acc[o][co] = bias[co];

#pragma unroll
    for (int kd = 0; kd < 3; ++kd)
#pragma unroll
        for (int kh = 0; kh < 3; ++kh) {
            const float* base = x + pc + (kd - 1) * PHW + (kh - 1) * PW;
            f32x4 u = *(const f32x4*)(base - 1);
            f32x2 v = *(const f32x2*)(base + 3);
            float c[6] = {u[0], u[1], u[2], u[3], v[0], v[1]};
#pragma unroll
            for (int kw = 0; kw < 3; ++kw) {
                const int tap = (kd * 3 + kh) * 3 + kw;
                const float* wt = wA + tap * 16;
#pragma unroll
                for (int o = 0; o < 4; ++o) {
                    float vv = c[o + kw];
#pragma unroll
                    for (int co = 0; co < 16; ++co)
                        acc[o][co] = fmaf(vv, wt[co], acc[o][co]);
                }
            }
        }

#pragma unroll
    for (int o = 0; o < 4; ++o) {
        half8 lo, hi;
#pragma unroll
        for (int co = 0; co < 8; ++co) {
            lo[co] = (_Float16)fmaxf(acc[o][co], 0.f);
            hi[co] = (_Float16)fmaxf(acc[o][co + 8], 0.f);
        }
        _Float16* po = out + (size_t)(pc + o) * 16;
        *(half8*)po = lo;
        *(half8*)(po + 8) = hi;
    }
}

// ---------------------------------------------------------------------------
// conv2_lds: 16 -> 16 ch MFMA implicit GEMM with LDS-staged A-tile.
// B-fragments preloaded into registers BEFORE the staging wait.
// ---------------------------------------------------------------------------
__global__ __launch_bounds__(256) void conv2_lds(const _Float16* __restrict__ x,
                                                 const _Float16* __restrict__ wB,
                                                 const float* __restrict__ bias,
                                                 _Float16* __restrict__ out) {
    __shared__ __align__(16) _Float16 lds[3328 * 8];   // 53,248 B

    const int tid = threadIdx.x;
    const int lane = tid & 63;
    const int wid = tid >> 6;
    const int m256 = blockIdx.x * 256;
    const int h0 = (m256 >> 7) & (HH - 1);
    const int d0 = m256 >> 14;
    const int origin = d0 * PHW + h0 * PW;   // element idx of region (0,0,0)

    const int l15 = lane & 15;
    const int lg = lane >> 4;
    const int tapSel = lg >> 1;
    const int hf0 = lg & 1;

    // ---- B-preload: all 14 fragments into registers (independent of LDS)
    half8 bfr[14];
#pragma unroll
    for (int t = 0; t < 14; ++t)
        bfr[t] = *(const half8*)(wB + (size_t)((t * 4 + lg) * 16 + l15) * 8);

    // ---- stage: 13 x global_load_lds(16B) per thread, inverse-swizzled src
    for (int it = 0; it < 13; ++it) {
        int P = it * 256 + tid;               // physical granule (linear dest)
        int G = P ^ ((P >> 3) & 1);           // logical granule
        int lin = G >> 1;                     // region row (32B each)
        int hf = G & 1;                       // 16B half within row
        unsigned seg = (unsigned)lin / 130u;  // 0..12 (12 = overstage tail)
        int wx = lin - (int)seg * 130;
        int dz = (int)seg >> 2, hy = (int)seg & 3;
        const _Float16* src =
            x + ((size_t)(origin + dz * PHW + hy * PW + wx) * 16 + hf * 8);
        _Float16* dst = lds + ((size_t)(it * 256 + wid * 64) * 8);
        __builtin_amdgcn_global_load_lds(
            (const __attribute__((address_space(1))) void*)src,
            (__attribute__((address_space(3))) void*)dst, 16, 0, 0);
    }
    __syncthreads();

    // per-lane region row for each packed K-chunk t
    int rowt[14];
#pragma unroll
    for (int t = 0; t < 14; ++t) {
        int tap = 2 * t + tapSel;
        if (tap > 26) tap = 26;               // K-pad: weights are 0 there
        int kd = tap / 9;
        int kh = (tap / 3) % 3;
        int kw = tap % 3;
        rowt[t] = (kd * 4 + (wid >> 1) + kh) * 130 + (wid & 1) * 64 + l15 + kw;
    }

    f32x4 acc0 = {0.f, 0.f, 0.f, 0.f};
    f32x4 acc1 = acc0, acc2 = acc0, acc3 = acc0;

#pragma unroll
    for (int t = 0; t < 14; ++t) {
        int r = rowt[t];
        int g = r * 2 + (hf0 ^ ((r >> 2) & 1));   // swizzled granule
        const _Float16* pa = lds + (size_t)g * 8;
        half8 a0 = *(const half8*)(pa);            // row r
        half8 a1 = *(const half8*)(pa + 32 * 8);   // row r+16
        half8 a2 = *(const half8*)(pa + 64 * 8);   // row r+32
        half8 a3 = *(const half8*)(pa + 96 * 8);   // row r+48
        acc0 = __builtin_amdgcn_mfma_f32_16x16x32_f16(a0, bfr[t], acc0, 0, 0, 0);
        acc1 = __builtin_amdgcn_mfma_f32_16x16x32_f16(a1, bfr[t], acc1, 0, 0, 0);
        acc2 = __builtin_amdgcn_mfma_f32_16x16x32_f16(a2, bfr[t], acc2, 0, 0, 0);
        acc3 = __builtin_amdgcn_mfma_f32_16x16x32_f16(a3, bfr[t], acc3, 0, 0, 0);
    }

    const int pc64 = pcidx(d0, h0 + (wid >> 1), (wid & 1) * 64);
    float bc = bias[l15];
#pragma unroll
    for (int r = 0; r < 4; ++r) {
        f32x4 a = (r == 0) ? acc0 : (r == 1) ? acc1 : (r == 2) ? acc2 : acc3;
#pragma unroll
        for (int reg = 0; reg < 4; ++reg) {
            int prow = pc64 + r * 16 + lg * 4 + reg;
            float v = fmaxf(a[reg] + bc, 0.f);
            out[(size_t)prow * 16 + l15] = (_Float16)v;
        }
    }
}

// ---------------------------------------------------------------------------
// conv3: 16 -> 1 ch.  8 outputs/thread (4 depth x 2 w); 4-column window
// shared across kw taps and the w-pair; dot2 math, fp32 accum.
// ---------------------------------------------------------------------------
__global__ __launch_bounds__(256) void conv3_k(const _Float16* __restrict__ x,
                                               const h2* __restrict__ wC,
                                               const float* __restrict__ bias,
                                               const float* __restrict__ residP,
                                               float* __restrict__ out) {
    int i = blockIdx.x * 256 + threadIdx.x;    // NN/8 threads
    int w0 = (i & 63) * 2;
    int h = (i >> 6) & (HH - 1);
    int d0 = (i >> 13) * 4;
    int pc = pcidx(d0, h, w0);

    float accA[4][2] = {};
    float accB[4][2] = {};

#pragma unroll
    for (int kh = 0; kh < 3; ++kh) {
#pragma unroll
        for (int p = 0; p < 6; ++p) {         // depth planes d0-1 .. d0+4
            const _Float16* rowp =
                x + (size_t)(pc + (p - 1) * PHW + (kh - 1) * PW - 1) * 16;
            half8 v0[4], v1[4];
#pragma unroll
            for (int c2 = 0; c2 < 4; ++c2) {  // columns w0-1 .. w0+2
                v0[c2] = *(const half8*)(rowp + c2 * 16);
                v1[c2] = *(const half8*)(rowp + c2 * 16 + 8);
            }
#pragma unroll
            for (int kd = 0; kd < 3; ++kd) {
                const int o = p - kd;
                if (o < 0 || o > 3) continue;
#pragma unroll
                for (int kw = 0; kw < 3; ++kw) {
                    const h2* wv = wC + (size_t)(kd * 9 + kh * 3 + kw) * 8;
#pragma unroll
                    for (int ow = 0; ow < 2; ++ow) {
                        const int c2 = kw + ow;
                        float a = accA[o][ow], b = accB[o][ow];
                        h2 t2;
                        t2[0] = v0[c2][0]; t2[1] = v0[c2][1]; a = fdot2f(t2, wv[0], a);
                        t2[0] = v0[c2][2]; t2[1] = v0[c2][3]; b = fdot2f(t2, wv[1], b);
                        t2[0] = v0[c2][4]; t2[1] = v0[c2][5]; a = fdot2f(t2, wv[2], a);
                        t2[0] = v0[c2][6]; t2[1] = v0[c2][7]; b = fdot2f(t2, wv[3], b);
                        t2[0] = v1[c2][0]; t2[1] = v1[c2][1]; a = fdot2f(t2, wv[4], a);
                        t2[0] = v1[c2][2]; t2[1] = v1[c2][3]; b = fdot2f(t2, wv[5], b);
                        t2[0] = v1[c2][4]; t2[1] = v1[c2][5]; a = fdot2f(t2, wv[6], a);
                        t2[0] = v1[c2][6]; t2[1] = v1[c2][7]; b = fdot2f(t2, wv[7], b);
                        accA[o][ow] = a; accB[o][ow] = b;
                    }
                }
            }
        }
    }

    float bc = bias[0];
    int ob = (d0 << 14) + (h << 7) + w0;
#pragma unroll
    for (int o = 0; o < 4; ++o) {
        f32x2 res;
#pragma unroll
        for (int ow = 0; ow < 2; ++ow)
            res[ow] = residP[pc + o * PHW + ow] + bc +
                      (accA[o][ow] + accB[o][ow]);
        *(f32x2*)(out + ob + o * HWC) = res;
    }
}

// ---------------------------------------------------------------------------
// update (unchanged, verified)
// ---------------------------------------------------------------------------
__global__ __launch_bounds__(256) void update_k(const float* __restrict__ p0,
                                                const float* __restrict__ q0,
                                                const float* __restrict__ s0,
                                                const float* __restrict__ pn,
                                                const float* __restrict__ qn,
                                                const float* __restrict__ sn,
                                                const float* __restrict__ zn,
                                                float* __restrict__ t,
                                                float* __restrict__ p1,
                                                float* __restrict__ q1,
                                                float* __restrict__ s1,
                                                float* __restrict__ out,
                                                const float* __restrict__ ntx,
                                                const float* __restrict__ nty,
                                                const float* __restrict__ ntz,
                                                const float* __restrict__ nt,
                                                int c) {
    int i = blockIdx.x * 256 + threadIdx.x;
    int w = i & (WW - 1);
    int h = (i >> 7) & (HH - 1);
    int d = i >> 14;
    float cx = ntx[c], cy = nty[c], cz = ntz[c], ct = nt[c];

    float pu = p0[i] + cx * (p0[i] - pn[i]);
    float qu = q0[i] + cy * (q0[i] - qn[i]);
    float su = s0[i] + cz * (s0[i] - sn[i]);
    p1[i] = pu;
    q1[i] = qu;
    s1[i] = su;

    float tv = t[i];
    float zl = tv + ct * (tv - zn[i]);

    float acc = zl;
    if (w > 0) {
        float a = p0[i - 1];
        acc += a + cx * (a - pn[i - 1]);
    }
    if (w < WW - 1) acc -= pu;
    if (h > 0) {
        float a = q0[i - WW];
        acc += a + cy * (a - qn[i - WW]);
    }
    if (h < HH - 1) acc -= qu;
    if (d > 0) {
        float a = s0[i - HWC];
        acc += a + cz * (a - sn[i - HWC]);
    }
    if (d < DD - 1) acc -= su;

    t[i] = acc;
    out[i] = acc;
}

// ---------------------------------------------------------------------------
extern "C" void kernel_launch(void* const* d_in, const int* in_sizes, int n_in,
                              void* d_out, int out_size, void* d_ws, size_t ws_size,
                              hipStream_t stream) {
    const float* image = (const float*)d_in[0];
    const float* sino  = (const float*)d_in[1];
    const float* w1    = (const float*)d_in[2];
    const float* b1    = (const float*)d_in[3];
    const float* w2    = (const float*)d_in[4];
    const float* b2    = (const float*)d_in[5];
    const float* w3    = (const float*)d_in[6];
    const float* b3    = (const float*)d_in[7];
    const float* ntx   = (const float*)d_in[8];
    const float* nty   = (const float*)d_in[9];
    const float* ntz   = (const float*)d_in[10];
    const float* nt    = (const float*)d_in[11];

    float* out = (float*)d_out;
    float* ws  = (float*)d_ws;

    // unpadded fp32 state
    float* t     = ws;
    float* pbuf[2] = {ws + (size_t)1 * NN, ws + (size_t)4 * NN};
    float* qbuf[2] = {ws + (size_t)2 * NN, ws + (size_t)5 * NN};
    float* sbuf[2] = {ws + (size_t)3 * NN, ws + (size_t)6 * NN};
    float* pn = ws + (size_t)7 * NN;   // pn,qn,sn,zn contiguous (bi*NN)
    float* r  = ws + (size_t)11 * NN;  // HWC floats

    // padded region (halos zeroed by pad_zero each launch)
    float* padbase = ws + (size_t)12 * NN;
    float* zP  = padbase;                          // bi=3 input
    float* dxP = padbase + (size_t)1 * PN;         // bi=0
    float* dyP = padbase + (size_t)2 * PN;         // bi=1
    float* dzP = padbase + (size_t)3 * PN;         // bi=2

    const size_t HS = (size_t)PN * 16;             // halves per h-buffer
    _Float16* h1  = (_Float16*)(padbase + (size_t)4 * PN);
    _Float16* h2b = h1 + HS;
    _Float16* wBp = h2b + HS;                      // 4*7168 halves
    h2* wCp = (h2*)(wBp + 4 * 7168);               // 4*216 h2
    float* wAp = (float*)(wCp + 4 * 216);          // 4*432 fp32

    const int NB = NN / 256;      // 4096
    const int HB = HWC / 256;     // 64
    const int QB = NN / 4 / 256;  // 1024
    const int OB = NN / 8 / 256;  // 512
    const int PB = (PN + 255) / 256;

    pad_zero<<<PB, 256, 0, stream>>>(zP, dxP, dyP, dzP, h1, h2b);
    prep_all<<<25, 256, 0, stream>>>(w1, w2, w3, wAp, wBp, wCp);
    init_k<<<NB, 256, 0, stream>>>(image, t, out, pbuf[0], qbuf[0], sbuf[0]);

    int cur = 0;
    for (int c = 0; c < 3; ++c) {
        colsum_k<<<HB, 256, 0, stream>>>(t, sino, r);
        zdiff_k<<<NB, 256, 0, stream>>>(t, r, zP, dxP, dyP, dzP);

        const float* xinP[4] = {dxP, dyP, dzP, zP};
        for (int bi = 0; bi < 4; ++bi) {
            conv1_k<<<QB, 256, 0, stream>>>(xinP[bi], wAp + (size_t)bi * 432,
                                            b1 + (size_t)bi * 16, h1);
            conv2_lds<<<NB, 256, 0, stream>>>(h1, wBp + (size_t)bi * 7168,
                                              b2 + (size_t)bi * 16, h2b);
            conv3_k<<<OB, 256, 0, stream>>>(h2b, wCp + (size_t)bi * 216,
                                            b3 + (size_t)bi, xinP[bi],
                                            pn + (size_t)bi * NN);
        }

        update_k<<<NB, 256, 0, stream>>>(pbuf[cur], qbuf[cur], sbuf[cur],
                                         pn, pn + NN, pn + 2 * (size_t)NN,
                                         pn + 3 * (size_t)NN, t,
                                         pbuf[1 - cur], qbuf[1 - cur], sbuf[1 - cur],
                                         out + (size_t)(c + 1) * NN,
                                         ntx, nty, ntz, nt, c);
        cur ^= 1;
    }
}

// Round 12
// 1048.263 us; speedup vs baseline: 22.1248x; 1.0198x over previous
//
#include <hip/hip_runtime.h>
#include <cstddef>

#define DD 64
#define HH 128
#define WW 128
#define HWC (HH * WW)            // 16384
#define NN (DD * HWC)            // 1048576

// padded spatial dims (+1 halo each side)
#define PD 66
#define PH 130
#define PW 130
#define PHW (PH * PW)            // 16900
#define PN (PD * PHW)            // 1115400

typedef __attribute__((ext_vector_type(8))) _Float16 half8;
typedef __attribute__((ext_vector_type(2))) _Float16 h2;
typedef __attribute__((ext_vector_type(4))) float f32x4;
typedef __attribute__((ext_vector_type(2))) float f32x2;

__device__ __forceinline__ int pcidx(int d, int h, int w) {
    return (d + 1) * PHW + (h + 1) * PW + (w + 1);
}

__device__ __forceinline__ float fdot2f(h2 a, h2 b, float c) {
#if __has_builtin(__builtin_amdgcn_fdot2)
    return __builtin_amdgcn_fdot2(a, b, c, false);
#else
    return fmaf((float)a[0], (float)b[0], fmaf((float)a[1], (float)b[1], c));
#endif
}

// ---------------------------------------------------------------------------
// pad_zero: zero ONLY halo cells of the padded buffers.
// ---------------------------------------------------------------------------
__global__ __launch_bounds__(256) void pad_zero(float* __restrict__ zP,
                                                float* __restrict__ dxP,
                                                float* __restrict__ dyP,
                                                float* __restrict__ dzP,
                                                _Float16* __restrict__ h1,
                                                _Float16* __restrict__ h2b) {
    int idx = blockIdx.x * 256 + threadIdx.x;
    if (idx >= PN) return;
    int d = idx / PHW;
    int rem = idx - d * PHW;
    int h = rem / PW;
    int w = rem - h * PW;
    bool pad = (d == 0) | (d == PD - 1) | (h == 0) | (h == PH - 1) |
               (w == 0) | (w == PW - 1);
    if (!pad) return;
    zP[idx] = 0.f;
    dxP[idx] = 0.f;
    dyP[idx] = 0.f;
    dzP[idx] = 0.f;
    half8 z = {};
    *(half8*)(h1 + (size_t)idx * 16) = z;
    *(half8*)(h1 + (size_t)idx * 16 + 8) = z;
    *(half8*)(h2b + (size_t)idx * 16) = z;
    *(half8*)(h2b + (size_t)idx * 16 + 8) = z;
}

// ---------------------------------------------------------------------------
// init: t = image, out[0..NN) = image, p=q=s=0
// ---------------------------------------------------------------------------
__global__ __launch_bounds__(256) void init_k(const float* __restrict__ img,
                                              float* __restrict__ t,
                                              float* __restrict__ out0,
                                              float* __restrict__ p,
                                              float* __restrict__ q,
                                              float* __restrict__ s) {
    int i = blockIdx.x * 256 + threadIdx.x;
    float v = img[i];
    t[i] = v;
    out0[i] = v;
    p[i] = 0.f;
    q[i] = 0.f;
    s[i] = 0.f;
}

// ---------------------------------------------------------------------------
// colsum: r[hw] = (sino[hw] - sum_d t[d,hw]) / DD
// ---------------------------------------------------------------------------
__global__ __launch_bounds__(256) void colsum_k(const float* __restrict__ t,
                                                const float* __restrict__ sino,
                                                float* __restrict__ r) {
    int hw = blockIdx.x * 256 + threadIdx.x;
    float sum = 0.f;
#pragma unroll 8
    for (int d = 0; d < DD; ++d) sum += t[d * HWC + hw];
    r[hw] = (sino[hw] - sum) * (1.0f / DD);
}

// ---------------------------------------------------------------------------
// zdiff: writes PADDED z, dx, dy, dz (fp32). Pads are pre-zeroed.
// ---------------------------------------------------------------------------
__global__ __launch_bounds__(256) void zdiff_k(const float* __restrict__ t,
                                               const float* __restrict__ r,
                                               float* __restrict__ zP,
                                               float* __restrict__ dxP,
                                               float* __restrict__ dyP,
                                               float* __restrict__ dzP) {
    int i = blockIdx.x * 256 + threadIdx.x;
    int w = i & (WW - 1);
    int h = (i >> 7) & (HH - 1);
    int d = i >> 14;
    int hw = i & (HWC - 1);
    int pc = pcidx(d, h, w);
    float tv = t[i];
    float rv = r[hw];
    float zv = tv + rv;
    zP[pc] = zv;
    dxP[pc] = (w < WW - 1) ? (t[i + 1] + r[hw + 1]) - zv : 0.f;
    dyP[pc] = (h < HH - 1) ? (t[i + WW] + r[hw + WW]) - zv : 0.f;
    dzP[pc] = (d < DD - 1) ? (t[i + HWC] - tv) : 0.f;
}

// ---------------------------------------------------------------------------
// prep_all: pack w1 -> [bi][tap][16co] fp32 (idx 0..1727)
//           w2 -> fp16 frag layout (idx 1728..5311)
//           w3 -> half2 pairs (idx 5312..6175)
// ---------------------------------------------------------------------------
__global__ __launch_bounds__(256) void prep_all(const float* __restrict__ w1,
                                                const float* __restrict__ w2,
                                                const float* __restrict__ w3,
                                                float* __restrict__ wA,
                                                _Float16* __restrict__ wB,
                                                h2* __restrict__ wC) {
    int idx = blockIdx.x * 256 + threadIdx.x;
    if (idx < 1728) {
        int bi = idx / 432;
        int rem = idx - bi * 432;
        int tap = rem >> 4;
        int co = rem & 15;
        wA[idx] = w1[bi * 432 + co * 27 + tap];
    } else if (idx < 5312) {
        int k = idx - 1728;
        int bi = k / 896;
        int rem = k - bi * 896;
        int kc = rem >> 4;
        int co = rem & 15;
        int tap = kc >> 1;
        int ci0 = (kc & 1) * 8;
        half8 v;
#pragma unroll
        for (int j = 0; j < 8; ++j) {
            float f = (tap < 27) ? w2[bi * 6912 + (co * 16 + ci0 + j) * 27 + tap]
                                 : 0.f;
            v[j] = (_Float16)f;
        }
        *(half8*)(wB + (size_t)k * 8) = v;
    } else if (idx < 6176) {
        int k = idx - 5312;
        int bi = k / 216;
        int rem = k - bi * 216;
        int tap = rem >> 3;
        int j = rem & 7;
        h2 v;
        v[0] = (_Float16)w3[bi * 432 + (2 * j) * 27 + tap];
        v[1] = (_Float16)w3[bi * 432 + (2 * j + 1) * 27 + tap];
        wC[k] = v;
    }
}

// ---------------------------------------------------------------------------
// conv1: 1 -> 16 ch. 4 outputs/thread along w; row-segment reuse.
// ---------------------------------------------------------------------------
__global__ __launch_bounds__(256) void conv1_k(const float* __restrict__ x,
                                               const float* __restrict__ wA,
                                               const float* __restrict__ bias,
                                               _Float16* __restrict__ out) {
    int i = blockIdx.x * 256 + threadIdx.x;    // NN/4 threads
    int w0 = (i & 31) * 4;
    int h = (i >> 5) & (HH - 1);
    int d = i >> 12;
    int pc = pcidx(d, h, w0);

    float acc[4][16];
#pragma unroll
    for (int o = 0; o < 4; ++o)
#pragma unroll
        for (int co = 0; co < 16; ++co) acc[o][co] = bias[co];

#pragma unroll
    for (int kd = 0; kd < 3; ++kd)
#pragma unroll
        for (int kh = 0; kh < 3; ++kh) {
            const float* base = x + pc + (kd - 1) * PHW + (kh - 1) * PW;
            f32x4 u = *(const f32x4*)(base - 1);
            f32x2 v = *(const f32x2*)(base + 3);
            float c[6] = {u[0], u[1], u[2], u[3], v[0], v[1]};
#pragma unroll
            for (int kw = 0; kw < 3; ++kw) {
                const int tap = (kd * 3 + kh) * 3 + kw;
                const float* wt = wA + tap * 16;
#pragma unroll
                for (int o = 0; o < 4; ++o) {
                    float vv = c[o + kw];
#pragma unroll
                    for (int co = 0; co < 16; ++co)
                        acc[o][co] = fmaf(vv, wt[co], acc[o][co]);
                }
            }
        }

#pragma unroll
    for (int o = 0; o < 4; ++o) {
        half8 lo, hi;
#pragma unroll
        for (int co = 0; co < 8; ++co) {
            lo[co] = (_Float16)fmaxf(acc[o][co], 0.f);
            hi[co] = (_Float16)fmaxf(acc[o][co + 8], 0.f);
        }
        _Float16* po = out + (size_t)(pc + o) * 16;
        *(half8*)po = lo;
        *(half8*)(po + 8) = hi;
    }
}

// ---------------------------------------------------------------------------
// conv2_lds: 16 -> 16 ch MFMA implicit GEMM with LDS-staged A-tile.
// Block = 512 thr = 8 waves = 2 d-planes x 2 h-rows x 128 w outputs.
// Staged region: 4d x 4h x 130w rows of 32B = 2080 granule-rows (66.5KB,
// alloc 72KB incl. over-stage tail). Granule swizzle G' = G ^ ((G>>3)&1)
// on BOTH staging source and read address (linear LDS dest).
// ---------------------------------------------------------------------------
__global__ __launch_bounds__(512) void conv2_lds(const _Float16* __restrict__ x,
                                                 const _Float16* __restrict__ wB,
                                                 const float* __restrict__ bias,
                                                 _Float16* __restrict__ out) {
    __shared__ __align__(16) _Float16 lds[4608 * 8];   // 73,728 B

    const int tid = threadIdx.x;
    const int lane = tid & 63;
    const int wid = tid >> 6;                 // 0..7
    const int bid = blockIdx.x;               // 2048 blocks
    const int h0 = (bid & 63) * 2;            // h-pair
    const int d0 = (bid >> 6) * 2;            // d-pair
    const int origin = d0 * PHW + h0 * PW;    // padded idx of region (0,0,0)

    const int l15 = lane & 15;
    const int lg = lane >> 4;
    const int tapSel = lg >> 1;
    const int hf0 = lg & 1;

    // ---- B-preload: all 14 fragments into registers (independent of LDS)
    half8 bfr[14];
#pragma unroll
    for (int t = 0; t < 14; ++t)
        bfr[t] = *(const half8*)(wB + (size_t)((t * 4 + lg) * 16 + l15) * 8);

    // ---- stage: 9 x global_load_lds(16B) per thread, inverse-swizzled src
    for (int it = 0; it < 9; ++it) {
        int P = it * 512 + tid;               // physical granule (linear dest)
        int G = P ^ ((P >> 3) & 1);           // logical granule
        int lin = G >> 1;                     // region row (32B each)
        int hf = G & 1;                       // 16B half within row
        unsigned seg = (unsigned)lin / 130u;  // 0..15 (+overstage tail)
        int wx = lin - (int)seg * 130;
        int dz = (int)seg >> 2, hy = (int)seg & 3;
        const _Float16* src =
            x + ((size_t)(origin + dz * PHW + hy * PW + wx) * 16 + hf * 8);
        _Float16* dst = lds + ((size_t)(it * 512 + wid * 64) * 8);
        __builtin_amdgcn_global_load_lds(
            (const __attribute__((address_space(1))) void*)src,
            (__attribute__((address_space(3))) void*)dst, 16, 0, 0);
    }
    __syncthreads();

    // wave geometry: dd = wid>>2, hh = (wid>>1)&1, w-half = wid&1
    const int dd = wid >> 2;
    const int hh = (wid >> 1) & 1;
    const int whalf = (wid & 1) * 64;

    // per-lane region row for each packed K-chunk t
    int rowt[14];
#pragma unroll
    for (int t = 0; t < 14; ++t) {
        int tap = 2 * t + tapSel;
        if (tap > 26) tap = 26;               // K-pad: weights are 0 there
        int kd = tap / 9;
        int kh = (tap / 3) % 3;
        int kw = tap % 3;
        rowt[t] = ((dd + kd) * 4 + hh + kh) * 130 + whalf + l15 + kw;
    }

    f32x4 acc0 = {0.f, 0.f, 0.f, 0.f};
    f32x4 acc1 = acc0, acc2 = acc0, acc3 = acc0;

#pragma unroll
    for (int t = 0; t < 14; ++t) {
        int r = rowt[t];
        int g = r * 2 + (hf0 ^ ((r >> 2) & 1));   // swizzled granule
        const _Float16* pa = lds + (size_t)g * 8;
        half8 a0 = *(const half8*)(pa);            // row r
        half8 a1 = *(const half8*)(pa + 32 * 8);   // +16 w
        half8 a2 = *(const half8*)(pa + 64 * 8);   // +32 w
        half8 a3 = *(const half8*)(pa + 96 * 8);   // +48 w
        acc0 = __builtin_amdgcn_mfma_f32_16x16x32_f16(a0, bfr[t], acc0, 0, 0, 0);
        acc1 = __builtin_amdgcn_mfma_f32_16x16x32_f16(a1, bfr[t], acc1, 0, 0, 0);
        acc2 = __builtin_amdgcn_mfma_f32_16x16x32_f16(a2, bfr[t], acc2, 0, 0, 0);
        acc3 = __builtin_amdgcn_mfma_f32_16x16x32_f16(a3, bfr[t], acc3, 0, 0, 0);
    }

    const int pc64 = pcidx(d0 + dd, h0 + hh, whalf);
    float bc = bias[l15];
#pragma unroll
    for (int r = 0; r < 4; ++r) {
        f32x4 a = (r == 0) ? acc0 : (r == 1) ? acc1 : (r == 2) ? acc2 : acc3;
#pragma unroll
        for (int reg = 0; reg < 4; ++reg) {
            int prow = pc64 + r * 16 + lg * 4 + reg;
            float v = fmaxf(a[reg] + bc, 0.f);
            out[(size_t)prow * 16 + l15] = (_Float16)v;
        }
    }
}

// ---------------------------------------------------------------------------
// conv3: 16 -> 1 ch.  8 outputs/thread (4 depth x 2 w); 4-column window
// shared across kw taps and the w-pair; dot2 math, fp32 accum.
// ---------------------------------------------------------------------------
__global__ __launch_bounds__(256) void conv3_k(const _Float16* __restrict__ x,
                                               const h2* __restrict__ wC,
                                               const float* __restrict__ bias,
                                               const float* __restrict__ residP,
                                               float* __restrict__ out) {
    int i = blockIdx.x * 256 + threadIdx.x;    // NN/8 threads
    int w0 = (i & 63) * 2;
    int h = (i >> 6) & (HH - 1);
    int d0 = (i >> 13) * 4;
    int pc = pcidx(d0, h, w0);

    float accA[4][2] = {};
    float accB[4][2] = {};

#pragma unroll
    for (int kh = 0; kh < 3; ++kh) {
#pragma unroll
        for (int p = 0; p < 6; ++p) {         // depth planes d0-1 .. d0+4
            const _Float16* rowp =
                x + (size_t)(pc + (p - 1) * PHW + (kh - 1) * PW - 1) * 16;
            half8 v0[4], v1[4];
#pragma unroll
            for (int c2 = 0; c2 < 4; ++c2) {  // columns w0-1 .. w0+2
                v0[c2] = *(const half8*)(rowp + c2 * 16);
                v1[c2] = *(const half8*)(rowp + c2 * 16 + 8);
            }
#pragma unroll
            for (int kd = 0; kd < 3; ++kd) {
                const int o = p - kd;
                if (o < 0 || o > 3) continue;
#pragma unroll
                for (int kw = 0; kw < 3; ++kw) {
                    const h2* wv = wC + (size_t)(kd * 9 + kh * 3 + kw) * 8;
#pragma unroll
                    for (int ow = 0; ow < 2; ++ow) {
                        const int c2 = kw + ow;
                        float a = accA[o][ow], b = accB[o][ow];
                        h2 t2;
                        t2[0] = v0[c2][0]; t2[1] = v0[c2][1]; a = fdot2f(t2, wv[0], a);
                        t2[0] = v0[c2][2]; t2[1] = v0[c2][3]; b = fdot2f(t2, wv[1], b);
                        t2[0] = v0[c2][4]; t2[1] = v0[c2][5]; a = fdot2f(t2, wv[2], a);
                        t2[0] = v0[c2][6]; t2[1] = v0[c2][7]; b = fdot2f(t2, wv[3], b);
                        t2[0] = v1[c2][0]; t2[1] = v1[c2][1]; a = fdot2f(t2, wv[4], a);
                        t2[0] = v1[c2][2]; t2[1] = v1[c2][3]; b = fdot2f(t2, wv[5], b);
                        t2[0] = v1[c2][4]; t2[1] = v1[c2][5]; a = fdot2f(t2, wv[6], a);
                        t2[0] = v1[c2][6]; t2[1] = v1[c2][7]; b = fdot2f(t2, wv[7], b);
                        accA[o][ow] = a; accB[o][ow] = b;
                    }
                }
            }
        }
    }

    float bc = bias[0];
    int ob = (d0 << 14) + (h << 7) + w0;
#pragma unroll
    for (int o = 0; o < 4; ++o) {
        f32x2 res;
#pragma unroll
        for (int ow = 0; ow < 2; ++ow)
            res[ow] = residP[pc + o * PHW + ow] + bc +
                      (accA[o][ow] + accB[o][ow]);
        *(f32x2*)(out + ob + o * HWC) = res;
    }
}

// ---------------------------------------------------------------------------
// update (unchanged, verified)
// ---------------------------------------------------------------------------
__global__ __launch_bounds__(256) void update_k(const float* __restrict__ p0,
                                                const float* __restrict__ q0,
                                                const float* __restrict__ s0,
                                                const float* __restrict__ pn,
                                                const float* __restrict__ qn,
                                                const float* __restrict__ sn,
                                                const float* __restrict__ zn,
                                                float* __restrict__ t,
                                                float* __restrict__ p1,
                                                float* __restrict__ q1,
                                                float* __restrict__ s1,
                                                float* __restrict__ out,
                                                const float* __restrict__ ntx,
                                                const float* __restrict__ nty,
                                                const float* __restrict__ ntz,
                                                const float* __restrict__ nt,
                                                int c) {
    int i = blockIdx.x * 256 + threadIdx.x;
    int w = i & (WW - 1);
    int h = (i >> 7) & (HH - 1);
    int d = i >> 14;
    float cx = ntx[c], cy = nty[c], cz = ntz[c], ct = nt[c];

    float pu = p0[i] + cx * (p0[i] - pn[i]);
    float qu = q0[i] + cy * (q0[i] - qn[i]);
    float su = s0[i] + cz * (s0[i] - sn[i]);
    p1[i] = pu;
    q1[i] = qu;
    s1[i] = su;

    float tv = t[i];
    float zl = tv + ct * (tv - zn[i]);

    float acc = zl;
    if (w > 0) {
        float a = p0[i - 1];
        acc += a + cx * (a - pn[i - 1]);
    }
    if (w < WW - 1) acc -= pu;
    if (h > 0) {
        float a = q0[i - WW];
        acc += a + cy * (a - qn[i - WW]);
    }
    if (h < HH - 1) acc -= qu;
    if (d > 0) {
        float a = s0[i - HWC];
        acc += a + cz * (a - sn[i - HWC]);
    }
    if (d < DD - 1) acc -= su;

    t[i] = acc;
    out[i] = acc;
}

// ---------------------------------------------------------------------------
extern "C" void kernel_launch(void* const* d_in, const int* in_sizes, int n_in,
                              void* d_out, int out_size, void* d_ws, size_t ws_size,
                              hipStream_t stream) {
    const float* image = (const float*)d_in[0];
    const float* sino  = (const float*)d_in[1];
    const float* w1    = (const float*)d_in[2];
    const float* b1    = (const float*)d_in[3];
    const float* w2    = (const float*)d_in[4];
    const float* b2    = (const float*)d_in[5];
    const float* w3    = (const float*)d_in[6];
    const float* b3    = (const float*)d_in[7];
    const float* ntx   = (const float*)d_in[8];
    const float* nty   = (const float*)d_in[9];
    const float* ntz   = (const float*)d_in[10];
    const float* nt    = (const float*)d_in[11];

    float* out = (float*)d_out;
    float* ws  = (float*)d_ws;

    // unpadded fp32 state
    float* t     = ws;
    float* pbuf[2] = {ws + (size_t)1 * NN, ws + (size_t)4 * NN};
    float* qbuf[2] = {ws + (size_t)2 * NN, ws + (size_t)5 * NN};
    float* sbuf[2] = {ws + (size_t)3 * NN, ws + (size_t)6 * NN};
    float* pn = ws + (size_t)7 * NN;   // pn,qn,sn,zn contiguous (bi*NN)
    float* r  = ws + (size_t)11 * NN;  // HWC floats

    // padded region (halos zeroed by pad_zero each launch)
    float* padbase = ws + (size_t)12 * NN;
    float* zP  = padbase;                          // bi=3 input
    float* dxP = padbase + (size_t)1 * PN;         // bi=0
    float* dyP = padbase + (size_t)2 * PN;         // bi=1
    float* dzP = padbase + (size_t)3 * PN;         // bi=2

    const size_t HS = (size_t)PN * 16;             // halves per h-buffer
    _Float16* h1  = (_Float16*)(padbase + (size_t)4 * PN);
    _Float16* h2b = h1 + HS;
    _Float16* wBp = h2b + HS;                      // 4*7168 halves
    h2* wCp = (h2*)(wBp + 4 * 7168);               // 4*216 h2
    float* wAp = (float*)(wCp + 4 * 216);          // 4*432 fp32

    const int NB = NN / 256;      // 4096
    const int HB = HWC / 256;     // 64
    const int QB = NN / 4 / 256;  // 1024
    const int OB = NN / 8 / 256;  // 512
    const int CB = NN / 512;      // 2048 (conv2: 512-thread blocks)
    const int PB = (PN + 255) / 256;

    pad_zero<<<PB, 256, 0, stream>>>(zP, dxP, dyP, dzP, h1, h2b);
    prep_all<<<25, 256, 0, stream>>>(w1, w2, w3, wAp, wBp, wCp);
    init_k<<<NB, 256, 0, stream>>>(image, t, out, pbuf[0], qbuf[0], sbuf[0]);

    int cur = 0;
    for (int c = 0; c < 3; ++c) {
        colsum_k<<<HB, 256, 0, stream>>>(t, sino, r);
        zdiff_k<<<NB, 256, 0, stream>>>(t, r, zP, dxP, dyP, dzP);

        const float* xinP[4] = {dxP, dyP, dzP, zP};
        for (int bi = 0; bi < 4; ++bi) {
            conv1_k<<<QB, 256, 0, stream>>>(xinP[bi], wAp + (size_t)bi * 432,
                                            b1 + (size_t)bi * 16, h1);
            conv2_lds<<<CB, 512, 0, stream>>>(h1, wBp + (size_t)bi * 7168,
                                              b2 + (size_t)bi * 16, h2b);
            conv3_k<<<OB, 256, 0, stream>>>(h2b, wCp + (size_t)bi * 216,
                                            b3 + (size_t)bi, xinP[bi],
                                            pn + (size_t)bi * NN);
        }

        update_k<<<NB, 256, 0, stream>>>(pbuf[cur], qbuf[cur], sbuf[cur],
                                         pn, pn + NN, pn + 2 * (size_t)NN,
                                         pn + 3 * (size_t)NN, t,
                                         pbuf[1 - cur], qbuf[1 - cur], sbuf[1 - cur],
                                         out + (size_t)(c + 1) * NN,
                                         ntx, nty, ntz, nt, c);
        cur ^= 1;
    }
}

// Round 13
// 997.607 us; speedup vs baseline: 23.2483x; 1.0508x over previous
//
#include <hip/hip_runtime.h>
#include <cstddef>

#define DD 64
#define HH 128
#define WW 128
#define HWC (HH * WW)            // 16384
#define NN (DD * HWC)            // 1048576

// padded spatial dims (+1 halo each side)
#define PD 66
#define PH 130
#define PW 130
#define PHW (PH * PW)            // 16900
#define PN (PD * PHW)            // 1115400

#define NBK 4096                 // init blocks
#define PBK 4358                 // pad_zero blocks
#define QBK 1024                 // conv1 blocks
#define OBK 512                  // conv3 blocks

typedef __attribute__((ext_vector_type(8))) _Float16 half8;
typedef __attribute__((ext_vector_type(2))) _Float16 h2;
typedef __attribute__((ext_vector_type(4))) float f32x4;
typedef __attribute__((ext_vector_type(2))) float f32x2;

__device__ __forceinline__ int pcidx(int d, int h, int w) {
    return (d + 1) * PHW + (h + 1) * PW + (w + 1);
}

__device__ __forceinline__ float fdot2f(h2 a, h2 b, float c) {
#if __has_builtin(__builtin_amdgcn_fdot2)
    return __builtin_amdgcn_fdot2(a, b, c, false);
#else
    return fmaf((float)a[0], (float)b[0], fmaf((float)a[1], (float)b[1], c));
#endif
}

// ---------------------------------------------------------------------------
// device bodies (identical math to round 12)
// ---------------------------------------------------------------------------
__device__ __forceinline__ void conv1_body(int i, const float* __restrict__ x,
                                           const float* __restrict__ wA,
                                           const float* __restrict__ bias,
                                           _Float16* __restrict__ out) {
    int w0 = (i & 31) * 4;
    int h = (i >> 5) & (HH - 1);
    int d = i >> 12;
    int pc = pcidx(d, h, w0);

    float acc[4][16];
#pragma unroll
    for (int o = 0; o < 4; ++o)
#pragma unroll
        for (int co = 0; co < 16; ++co) acc[o][co] = bias[co];

#pragma unroll
    for (int kd = 0; kd < 3; ++kd)
#pragma unroll
        for (int kh = 0; kh < 3; ++kh) {
            const float* base = x + pc + (kd - 1) * PHW + (kh - 1) * PW;
            f32x4 u = *(const f32x4*)(base - 1);
            f32x2 v = *(const f32x2*)(base + 3);
            float c[6] = {u[0], u[1], u[2], u[3], v[0], v[1]};
#pragma unroll
            for (int kw = 0; kw < 3; ++kw) {
                const int tap = (kd * 3 + kh) * 3 + kw;
                const float* wt = wA + tap * 16;
#pragma unroll
                for (int o = 0; o < 4; ++o) {
                    float vv = c[o + kw];
#pragma unroll
                    for (int co = 0; co < 16; ++co)
                        acc[o][co] = fmaf(vv, wt[co], acc[o][co]);
                }
            }
        }

#pragma unroll
    for (int o = 0; o < 4; ++o) {
        half8 lo, hi;
#pragma unroll
        for (int co = 0; co < 8; ++co) {
            lo[co] = (_Float16)fmaxf(acc[o][co], 0.f);
            hi[co] = (_Float16)fmaxf(acc[o][co + 8], 0.f);
        }
        _Float16* po = out + (size_t)(pc + o) * 16;
        *(half8*)po = lo;
        *(half8*)(po + 8) = hi;
    }
}

__device__ __forceinline__ void conv3_body(int i, const _Float16* __restrict__ x,
                                           const h2* __restrict__ wC,
                                           const float* __restrict__ bias,
                                           const float* __restrict__ residP,
                                           float* __restrict__ out) {
    int w0 = (i & 63) * 2;
    int h = (i >> 6) & (HH - 1);
    int d0 = (i >> 13) * 4;
    int pc = pcidx(d0, h, w0);

    float accA[4][2] = {};
    float accB[4][2] = {};

#pragma unroll
    for (int kh = 0; kh < 3; ++kh) {
#pragma unroll
        for (int p = 0; p < 6; ++p) {         // depth planes d0-1 .. d0+4
            const _Float16* rowp =
                x + (size_t)(pc + (p - 1) * PHW + (kh - 1) * PW - 1) * 16;
            half8 v0[4], v1[4];
#pragma unroll
            for (int c2 = 0; c2 < 4; ++c2) {  // columns w0-1 .. w0+2
                v0[c2] = *(const half8*)(rowp + c2 * 16);
                v1[c2] = *(const half8*)(rowp + c2 * 16 + 8);
            }
#pragma unroll
            for (int kd = 0; kd < 3; ++kd) {
                const int o = p - kd;
                if (o < 0 || o > 3) continue;
#pragma unroll
                for (int kw = 0; kw < 3; ++kw) {
                    const h2* wv = wC + (size_t)(kd * 9 + kh * 3 + kw) * 8;
#pragma unroll
                    for (int ow = 0; ow < 2; ++ow) {
                        const int c2 = kw + ow;
                        float a = accA[o][ow], b = accB[o][ow];
                        h2 t2;
                        t2[0] = v0[c2][0]; t2[1] = v0[c2][1]; a = fdot2f(t2, wv[0], a);
                        t2[0] = v0[c2][2]; t2[1] = v0[c2][3]; b = fdot2f(t2, wv[1], b);
                        t2[0] = v0[c2][4]; t2[1] = v0[c2][5]; a = fdot2f(t2, wv[2], a);
                        t2[0] = v0[c2][6]; t2[1] = v0[c2][7]; b = fdot2f(t2, wv[3], b);
                        t2[0] = v1[c2][0]; t2[1] = v1[c2][1]; a = fdot2f(t2, wv[4], a);
                        t2[0] = v1[c2][2]; t2[1] = v1[c2][3]; b = fdot2f(t2, wv[5], b);
                        t2[0] = v1[c2][4]; t2[1] = v1[c2][5]; a = fdot2f(t2, wv[6], a);
                        t2[0] = v1[c2][6]; t2[1] = v1[c2][7]; b = fdot2f(t2, wv[7], b);
                        accA[o][ow] = a; accB[o][ow] = b;
                    }
                }
            }
        }
    }

    float bc = bias[0];
    int ob = (d0 << 14) + (h << 7) + w0;
#pragma unroll
    for (int o = 0; o < 4; ++o) {
        f32x2 res;
#pragma unroll
        for (int ow = 0; ow < 2; ++ow)
            res[ow] = residP[pc + o * PHW + ow] + bc +
                      (accA[o][ow] + accB[o][ow]);
        *(f32x2*)(out + ob + o * HWC) = res;
    }
}

// ---------------------------------------------------------------------------
// prologue_k: fat kernel = pad_zero [0,PBK) + init [PBK,PBK+NBK) + prep (rest)
// ---------------------------------------------------------------------------
__global__ __launch_bounds__(256) void prologue_k(
    const float* __restrict__ img, float* __restrict__ t,
    float* __restrict__ out0, float* __restrict__ p, float* __restrict__ q,
    float* __restrict__ s, float* __restrict__ zP, float* __restrict__ dxP,
    float* __restrict__ dyP, float* __restrict__ dzP,
    _Float16* __restrict__ h1, _Float16* __restrict__ h2b,
    const float* __restrict__ w1, const float* __restrict__ w2,
    const float* __restrict__ w3, float* __restrict__ wA,
    _Float16* __restrict__ wB, h2* __restrict__ wC) {
    int b = blockIdx.x;
    int tid = threadIdx.x;
    if (b < PBK) {
        int idx = b * 256 + tid;
        if (idx >= PN) return;
        int d = idx / PHW;
        int rem = idx - d * PHW;
        int h = rem / PW;
        int w = rem - h * PW;
        bool pad = (d == 0) | (d == PD - 1) | (h == 0) | (h == PH - 1) |
                   (w == 0) | (w == PW - 1);
        if (!pad) return;
        zP[idx] = 0.f;
        dxP[idx] = 0.f;
        dyP[idx] = 0.f;
        dzP[idx] = 0.f;
        half8 z = {};
        *(half8*)(h1 + (size_t)idx * 16) = z;
        *(half8*)(h1 + (size_t)idx * 16 + 8) = z;
        *(half8*)(h2b + (size_t)idx * 16) = z;
        *(half8*)(h2b + (size_t)idx * 16 + 8) = z;
    } else if (b < PBK + NBK) {
        int i = (b - PBK) * 256 + tid;
        float v = img[i];
        t[i] = v;
        out0[i] = v;
        p[i] = 0.f;
        q[i] = 0.f;
        s[i] = 0.f;
    } else {
        int idx = (b - PBK - NBK) * 256 + tid;
        if (idx < 1728) {
            int bi = idx / 432;
            int rem = idx - bi * 432;
            int tap = rem >> 4;
            int co = rem & 15;
            wA[idx] = w1[bi * 432 + co * 27 + tap];
        } else if (idx < 5312) {
            int k = idx - 1728;
            int bi = k / 896;
            int rem = k - bi * 896;
            int kc = rem >> 4;
            int co = rem & 15;
            int tap = kc >> 1;
            int ci0 = (kc & 1) * 8;
            half8 v;
#pragma unroll
            for (int j = 0; j < 8; ++j) {
                float f = (tap < 27)
                              ? w2[bi * 6912 + (co * 16 + ci0 + j) * 27 + tap]
                              : 0.f;
                v[j] = (_Float16)f;
            }
            *(half8*)(wB + (size_t)k * 8) = v;
        } else if (idx < 6176) {
            int k = idx - 5312;
            int bi = k / 216;
            int rem = k - bi * 216;
            int tap = rem >> 3;
            int j = rem & 7;
            h2 v;
            v[0] = (_Float16)w3[bi * 432 + (2 * j) * 27 + tap];
            v[1] = (_Float16)w3[bi * 432 + (2 * j + 1) * 27 + tap];
            wC[k] = v;
        }
    }
}

// ---------------------------------------------------------------------------
// colsum: r[hw] = (sino[hw] - sum_d t[d,hw]) / DD
// ---------------------------------------------------------------------------
__global__ __launch_bounds__(256) void colsum_k(const float* __restrict__ t,
                                                const float* __restrict__ sino,
                                                float* __restrict__ r) {
    int hw = blockIdx.x * 256 + threadIdx.x;
    float sum = 0.f;
#pragma unroll 8
    for (int d = 0; d < DD; ++d) sum += t[d * HWC + hw];
    r[hw] = (sino[hw] - sum) * (1.0f / DD);
}

// ---------------------------------------------------------------------------
// zdiff: writes PADDED z, dx, dy, dz (fp32). Pads are pre-zeroed.
// ---------------------------------------------------------------------------
__global__ __launch_bounds__(256) void zdiff_k(const float* __restrict__ t,
                                               const float* __restrict__ r,
                                               float* __restrict__ zP,
                                               float* __restrict__ dxP,
                                               float* __restrict__ dyP,
                                               float* __restrict__ dzP) {
    int i = blockIdx.x * 256 + threadIdx.x;
    int w = i & (WW - 1);
    int h = (i >> 7) & (HH - 1);
    int d = i >> 14;
    int hw = i & (HWC - 1);
    int pc = pcidx(d, h, w);
    float tv = t[i];
    float rv = r[hw];
    float zv = tv + rv;
    zP[pc] = zv;
    dxP[pc] = (w < WW - 1) ? (t[i + 1] + r[hw + 1]) - zv : 0.f;
    dyP[pc] = (h < HH - 1) ? (t[i + WW] + r[hw + WW]) - zv : 0.f;
    dzP[pc] = (d < DD - 1) ? (t[i + HWC] - tv) : 0.f;
}

// ---------------------------------------------------------------------------
// conv1_k: standalone (branch 0)
// ---------------------------------------------------------------------------
__global__ __launch_bounds__(256) void conv1_k(const float* __restrict__ x,
                                               const float* __restrict__ wA,
                                               const float* __restrict__ bias,
                                               _Float16* __restrict__ out) {
    conv1_body(blockIdx.x * 256 + threadIdx.x, x, wA, bias, out);
}

// ---------------------------------------------------------------------------
// conv2_lds: 16 -> 16 ch MFMA implicit GEMM with LDS-staged A-tile.
// (identical to round 12)
// ---------------------------------------------------------------------------
__global__ __launch_bounds__(512) void conv2_lds(const _Float16* __restrict__ x,
                                                 const _Float16* __restrict__ wB,
                                                 const float* __restrict__ bias,
                                                 _Float16* __restrict__ out) {
    __shared__ __align__(16) _Float16 lds[4608 * 8];   // 73,728 B

    const int tid = threadIdx.x;
    const int lane = tid & 63;
    const int wid = tid >> 6;                 // 0..7
    const int bid = blockIdx.x;               // 2048 blocks
    const int h0 = (bid & 63) * 2;            // h-pair
    const int d0 = (bid >> 6) * 2;            // d-pair
    const int origin = d0 * PHW + h0 * PW;    // padded idx of region (0,0,0)

    const int l15 = lane & 15;
    const int lg = lane >> 4;
    const int tapSel = lg >> 1;
    const int hf0 = lg & 1;

    half8 bfr[14];
#pragma unroll
    for (int t = 0; t < 14; ++t)
        bfr[t] = *(const half8*)(wB + (size_t)((t * 4 + lg) * 16 + l15) * 8);

    for (int it = 0; it < 9; ++it) {
        int P = it * 512 + tid;               // physical granule (linear dest)
        int G = P ^ ((P >> 3) & 1);           // logical granule
        int lin = G >> 1;
        int hf = G & 1;
        unsigned seg = (unsigned)lin / 130u;
        int wx = lin - (int)seg * 130;
        int dz = (int)seg >> 2, hy = (int)seg & 3;
        const _Float16* src =
            x + ((size_t)(origin + dz * PHW + hy * PW + wx) * 16 + hf * 8);
        _Float16* dst = lds + ((size_t)(it * 512 + wid * 64) * 8);
        __builtin_amdgcn_global_load_lds(
            (const __attribute__((address_space(1))) void*)src,
            (__attribute__((address_space(3))) void*)dst, 16, 0, 0);
    }
    __syncthreads();

    const int dd = wid >> 2;
    const int hh = (wid >> 1) & 1;
    const int whalf = (wid & 1) * 64;

    int rowt[14];
#pragma unroll
    for (int t = 0; t < 14; ++t) {
        int tap = 2 * t + tapSel;
        if (tap > 26) tap = 26;
        int kd = tap / 9;
        int kh = (tap / 3) % 3;
        int kw = tap % 3;
        rowt[t] = ((dd + kd) * 4 + hh + kh) * 130 + whalf + l15 + kw;
    }

    f32x4 acc0 = {0.f, 0.f, 0.f, 0.f};
    f32x4 acc1 = acc0, acc2 = acc0, acc3 = acc0;

#pragma unroll
    for (int t = 0; t < 14; ++t) {
        int r = rowt[t];
        int g = r * 2 + (hf0 ^ ((r >> 2) & 1));
        const _Float16* pa = lds + (size_t)g * 8;
        half8 a0 = *(const half8*)(pa);
        half8 a1 = *(const half8*)(pa + 32 * 8);
        half8 a2 = *(const half8*)(pa + 64 * 8);
        half8 a3 = *(const half8*)(pa + 96 * 8);
        acc0 = __builtin_amdgcn_mfma_f32_16x16x32_f16(a0, bfr[t], acc0, 0, 0, 0);
        acc1 = __builtin_amdgcn_mfma_f32_16x16x32_f16(a1, bfr[t], acc1, 0, 0, 0);
        acc2 = __builtin_amdgcn_mfma_f32_16x16x32_f16(a2, bfr[t], acc2, 0, 0, 0);
        acc3 = __builtin_amdgcn_mfma_f32_16x16x32_f16(a3, bfr[t], acc3, 0, 0, 0);
    }

    const int pc64 = pcidx(d0 + dd, h0 + hh, whalf);
    float bc = bias[l15];
#pragma unroll
    for (int r = 0; r < 4; ++r) {
        f32x4 a = (r == 0) ? acc0 : (r == 1) ? acc1 : (r == 2) ? acc2 : acc3;
#pragma unroll
        for (int reg = 0; reg < 4; ++reg) {
            int prow = pc64 + r * 16 + lg * 4 + reg;
            float v = fmaxf(a[reg] + bc, 0.f);
            out[(size_t)prow * 16 + l15] = (_Float16)v;
        }
    }
}

// ---------------------------------------------------------------------------
// conv3_k: standalone (branch 3)
// ---------------------------------------------------------------------------
__global__ __launch_bounds__(256) void conv3_k(const _Float16* __restrict__ x,
                                               const h2* __restrict__ wC,
                                               const float* __restrict__ bias,
                                               const float* __restrict__ residP,
                                               float* __restrict__ out) {
    conv3_body(blockIdx.x * 256 + threadIdx.x, x, wC, bias, residP, out);
}

// ---------------------------------------------------------------------------
// conv31_f: fused conv3(bi) [blocks 0..OBK) + conv1(bi+1) [blocks OBK..OBK+QBK)
// Both depend only on conv2(bi); mutually independent.
// ---------------------------------------------------------------------------
__global__ __launch_bounds__(256) void conv31_f(
    const _Float16* __restrict__ h2b, const h2* __restrict__ wC3,
    const float* __restrict__ b3v, const float* __restrict__ resid3,
    float* __restrict__ out3, const float* __restrict__ x1,
    const float* __restrict__ wA1, const float* __restrict__ b1v,
    _Float16* __restrict__ h1out) {
    int b = blockIdx.x;
    if (b < OBK) {
        conv3_body(b * 256 + threadIdx.x, h2b, wC3, b3v, resid3, out3);
    } else {
        conv1_body((b - OBK) * 256 + threadIdx.x, x1, wA1, b1v, h1out);
    }
}

// ---------------------------------------------------------------------------
// update (unchanged, verified)
// ---------------------------------------------------------------------------
__global__ __launch_bounds__(256) void update_k(const float* __restrict__ p0,
                                                const float* __restrict__ q0,
                                                const float* __restrict__ s0,
                                                const float* __restrict__ pn,
                                                const float* __restrict__ qn,
                                                const float* __restrict__ sn,
                                                const float* __restrict__ zn,
                                                float* __restrict__ t,
                                                float* __restrict__ p1,
                                                float* __restrict__ q1,
                                                float* __restrict__ s1,
                                                float* __restrict__ out,
                                                const float* __restrict__ ntx,
                                                const float* __restrict__ nty,
                                                const float* __restrict__ ntz,
                                                const float* __restrict__ nt,
                                                int c) {
    int i = blockIdx.x * 256 + threadIdx.x;
    int w = i & (WW - 1);
    int h = (i >> 7) & (HH - 1);
    int d = i >> 14;
    float cx = ntx[c], cy = nty[c], cz = ntz[c], ct = nt[c];

    float pu = p0[i] + cx * (p0[i] - pn[i]);
    float qu = q0[i] + cy * (q0[i] - qn[i]);
    float su = s0[i] + cz * (s0[i] - sn[i]);
    p1[i] = pu;
    q1[i] = qu;
    s1[i] = su;

    float tv = t[i];
    float zl = tv + ct * (tv - zn[i]);

    float acc = zl;
    if (w > 0) {
        float a = p0[i - 1];
        acc += a + cx * (a - pn[i - 1]);
    }
    if (w < WW - 1) acc -= pu;
    if (h > 0) {
        float a = q0[i - WW];
        acc += a + cy * (a - qn[i - WW]);
    }
    if (h < HH - 1) acc -= qu;
    if (d > 0) {
        float a = s0[i - HWC];
        acc += a + cz * (a - sn[i - HWC]);
    }
    if (d < DD - 1) acc -= su;

    t[i] = acc;
    out[i] = acc;
}

// ---------------------------------------------------------------------------
extern "C" void kernel_launch(void* const* d_in, const int* in_sizes, int n_in,
                              void* d_out, int out_size, void* d_ws, size_t ws_size,
                              hipStream_t stream) {
    const float* image = (const float*)d_in[0];
    const float* sino  = (const float*)d_in[1];
    const float* w1    = (const float*)d_in[2];
    const float* b1    = (const float*)d_in[3];
    const float* w2    = (const float*)d_in[4];
    const float* b2    = (const float*)d_in[5];
    const float* w3    = (const float*)d_in[6];
    const float* b3    = (const float*)d_in[7];
    const float* ntx   = (const float*)d_in[8];
    const float* nty   = (const float*)d_in[9];
    const float* ntz   = (const float*)d_in[10];
    const float* nt    = (const float*)d_in[11];

    float* out = (float*)d_out;
    float* ws  = (float*)d_ws;

    // unpadded fp32 state
    float* t     = ws;
    float* pbuf[2] = {ws + (size_t)1 * NN, ws + (size_t)4 * NN};
    float* qbuf[2] = {ws + (size_t)2 * NN, ws + (size_t)5 * NN};
    float* sbuf[2] = {ws + (size_t)3 * NN, ws + (size_t)6 * NN};
    float* pn = ws + (size_t)7 * NN;   // pn,qn,sn,zn contiguous (bi*NN)
    float* r  = ws + (size_t)11 * NN;  // HWC floats

    // padded region (halos zeroed by prologue each launch)
    float* padbase = ws + (size_t)12 * NN;
    float* zP  = padbase;                          // bi=3 input
    float* dxP = padbase + (size_t)1 * PN;         // bi=0
    float* dyP = padbase + (size_t)2 * PN;         // bi=1
    float* dzP = padbase + (size_t)3 * PN;         // bi=2

    const size_t HS = (size_t)PN * 16;             // halves per h-buffer
    _Float16* h1  = (_Float16*)(padbase + (size_t)4 * PN);
    _Float16* h2b = h1 + HS;
    _Float16* wBp = h2b + HS;                      // 4*7168 halves
    h2* wCp = (h2*)(wBp + 4 * 7168);               // 4*216 h2
    float* wAp = (float*)(wCp + 4 * 216);          // 4*432 fp32

    const int NB = NN / 256;      // 4096
    const int HB = HWC / 256;     // 64
    const int CB = NN / 512;      // 2048 (conv2: 512-thread blocks)

    prologue_k<<<PBK + NBK + 25, 256, 0, stream>>>(
        image, t, out, pbuf[0], qbuf[0], sbuf[0], zP, dxP, dyP, dzP, h1, h2b,
        w1, w2, w3, wAp, wBp, wCp);

    int cur = 0;
    for (int c = 0; c < 3; ++c) {
        colsum_k<<<HB, 256, 0, stream>>>(t, sino, r);
        zdiff_k<<<NB, 256, 0, stream>>>(t, r, zP, dxP, dyP, dzP);

        const float* xinP[4] = {dxP, dyP, dzP, zP};
        conv1_k<<<QBK, 256, 0, stream>>>(xinP[0], wAp, b1, h1);
        for (int bi = 0; bi < 4; ++bi) {
            conv2_lds<<<CB, 512, 0, stream>>>(h1, wBp + (size_t)bi * 7168,
                                              b2 + (size_t)bi * 16, h2b);
            if (bi < 3) {
                conv31_f<<<OBK + QBK, 256, 0, stream>>>(
                    h2b, wCp + (size_t)bi * 216, b3 + (size_t)bi, xinP[bi],
                    pn + (size_t)bi * NN, xinP[bi + 1],
                    wAp + (size_t)(bi + 1) * 432, b1 + (size_t)(bi + 1) * 16,
                    h1);
            } else {
                conv3_k<<<OBK, 256, 0, stream>>>(h2b, wCp + (size_t)3 * 216,
                                                 b3 + 3, xinP[3],
                                                 pn + (size_t)3 * NN);
            }
        }

        update_k<<<NB, 256, 0, stream>>>(pbuf[cur], qbuf[cur], sbuf[cur],
                                         pn, pn + NN, pn + 2 * (size_t)NN,
                                         pn + 3 * (size_t)NN, t,
                                         pbuf[1 - cur], qbuf[1 - cur], sbuf[1 - cur],
                                         out + (size_t)(c + 1) * NN,
                                         ntx, nty, ntz, nt, c);
        cur ^= 1;
    }
}